// Round 1
// baseline (6229.318 us; speedup 1.0000x reference)
//
#include <hip/hip_runtime.h>
#include <cmath>
#include <cstdint>
#include <cstring>
#include <cstdlib>
#include <vector>
#include <algorithm>
#include <complex>

#define TILE 32

// ------------------------------------------------------------------
// Sparse tensor-product tables (built on host each call, deterministic,
// uploaded with one async H2D memcpy into d_ws).
// cg entry:  packed = iabs | jabs<<8 | s<<16          coeff = cg value
//            S[s] += c * x1[iabs] * sh[jabs]
// out entry: packed = opos | widx<<8 | s<<20          coeff = alpha
//            out[opos] += coef * w[widx] * S[s]
// ------------------------------------------------------------------
struct TPTables {
  int cg1_bnd[9];
  int out1_bnd[9];
  int n_cg1, n_out1, n_cg2, n_out2;
  uint32_t cg1_pk[1024]; float cg1_c[1024];
  uint32_t out1_pk[768]; float out1_c[768];
  uint32_t cg2_pk[192];  float cg2_c[192];
  uint32_t out2_pk[64];  float out2_c[64];
};

// ---------------- host: Clebsch-Gordan (port of reference) ----------------
static double factd(int n){ double r=1; for(int i=2;i<=n;i++) r*=(double)i; return r; }

static double cg_complex(int j1,int m1,int j2,int m2,int j3,int m3){
  if(m1+m2!=m3) return 0.0;
  double pref = std::sqrt((2*j3+1)*factd(j3+j1-j2)*factd(j3-j1+j2)*factd(j1+j2-j3)/factd(j1+j2+j3+1));
  pref *= std::sqrt(factd(j3+m3)*factd(j3-m3)*factd(j1-m1)*factd(j1+m1)*factd(j2-m2)*factd(j2+m2));
  double s=0.0;
  for(int k=0;k<=j1+j2-j3;k++){
    int dd[6] = {k, j1+j2-j3-k, j1-m1-k, j2+m2-k, j3-j2+m1+k, j3-j1-m2+k};
    bool ok=true; double prod=1.0;
    for(int t=0;t<6;t++){ if(dd[t]<0){ok=false;break;} prod*=factd(dd[t]); }
    if(!ok) continue;
    s += ((k&1)?-1.0:1.0)/prod;
  }
  return pref*s;
}

typedef std::complex<double> cd;
static void real_U(int l, cd* U){ // (2l+1)x(2l+1) row-major
  int n = 2*l+1;
  for(int i=0;i<n*n;i++) U[i]=cd(0,0);
  U[l*n+l] = cd(1,0);
  for(int m=1;m<=l;m++){
    double sgn = (m&1)? -1.0 : 1.0;
    double is2 = 1.0/std::sqrt(2.0);
    U[(l+m)*n + (l+m)] = cd(sgn*is2,0);
    U[(l+m)*n + (l-m)] = cd(is2,0);
    U[(l-m)*n + (l+m)] = cd(0,-sgn*is2);
    U[(l-m)*n + (l-m)] = cd(0,is2);
  }
}

static void real_cg_h(int l1,int l2,int l3, double* out){
  int n1=2*l1+1,n2=2*l2+1,n3=2*l3+1;
  std::vector<cd> C(n1*n2*n3);
  for(int a=-l1;a<=l1;a++)for(int b=-l2;b<=l2;b++)for(int c=-l3;c<=l3;c++)
    C[(size_t)((a+l1)*n2+(b+l2))*n3+(c+l3)] = cd(cg_complex(l1,a,l2,b,l3,c),0);
  std::vector<cd> U1(n1*n1),U2(n2*n2),U3(n3*n3);
  real_U(l1,U1.data()); real_U(l2,U2.data()); real_U(l3,U3.data());
  std::vector<cd> T((size_t)n1*n2*n3, cd(0,0));
  for(int i=0;i<n1;i++)for(int j=0;j<n2;j++)for(int k=0;k<n3;k++){
    cd acc(0,0);
    for(int a=0;a<n1;a++){ cd u1=U1[i*n1+a]; if(u1==cd(0,0)) continue;
      for(int b=0;b<n2;b++){ cd u2=U2[j*n2+b]; if(u2==cd(0,0)) continue;
        for(int c=0;c<n3;c++){ cd u3=std::conj(U3[k*n3+c]); if(u3==cd(0,0)) continue;
          acc += u1*u2*u3*C[(size_t)(a*n2+b)*n3+c];
        } } }
    T[(size_t)(i*n2+j)*n3+k]=acc;
  }
  double sr=0, si=0;
  for(auto&z:T){ sr += std::fabs(z.real()); si += std::fabs(z.imag()); }
  int tot=n1*n2*n3;
  std::vector<double> R(tot);
  for(int i=0;i<tot;i++) R[i] = (sr>=si)? T[i].real() : T[i].imag();
  double nrm=0; for(double v:R) nrm += v*v; nrm = std::sqrt(nrm);
  for(int i=0;i<tot;i++) out[i] = R[i]/nrm;
}

// ---------------- host: make_tp port → flat tables ----------------
struct HIrr{int m,l,p;};

static int map_id(int i){return i;}
static int map_gate(int i){return (i<16)? i : i-16;} // compress GATE_OUT used dims {0..15}∪{32..79} → [0,64)

static void build_one(const std::vector<HIrr>& ir1, const std::vector<HIrr>& ir2,
                      const std::vector<HIrr>& ir3, int (*map1)(int), bool sort_out,
                      std::vector<uint32_t>& cg_pk, std::vector<float>& cg_c,
                      std::vector<uint32_t>& out_pk, std::vector<float>& out_c)
{
  int n1=(int)ir1.size(), n2=(int)ir2.size(), n3=(int)ir3.size();
  std::vector<int> s1(n1), s2(n2), s3(n3);
  { int o=0; for(int i=0;i<n1;i++){ s1[i]=o; o+=ir1[i].m*(2*ir1[i].l+1);} }
  { int o=0; for(int i=0;i<n2;i++){ s2[i]=o; o+=ir2[i].m*(2*ir2[i].l+1);} }
  { int o=0; for(int i=0;i<n3;i++){ s3[i]=o; o+=ir3[i].m*(2*ir3[i].l+1);} }
  struct Inst{int i1,i2,i3,w0;};
  std::vector<Inst> insts; int woff=0;
  for(int i1=0;i1<n1;i1++)for(int i2=0;i2<n2;i2++)for(int i3=0;i3<n3;i3++){
    const HIrr&A=ir1[i1];const HIrr&B=ir2[i2];const HIrr&C=ir3[i3];
    int dl = A.l-B.l; if(dl<0) dl=-dl;
    if(A.p*B.p==C.p && dl<=C.l && C.l<=A.l+B.l){
      insts.push_back({i1,i2,i3,woff}); woff += A.m*B.m*C.m;
    }
  }
  std::vector<int> fan(n3,0);
  for(auto&P:insts) fan[P.i3] += ir1[P.i1].m*ir2[P.i2].m;
  struct OE{int opos,widx,s;float coef;};
  std::vector<OE> outs;
  int sbase=0;
  for(auto&P:insts){
    const HIrr&A=ir1[P.i1];const HIrr&B=ir2[P.i2];const HIrr&C=ir3[P.i3];
    int d1=2*A.l+1,d2=2*B.l+1,d3=2*C.l+1;
    double cg[343];
    real_cg_h(A.l,B.l,C.l,cg);
    double alpha = std::sqrt((double)d3/(double)fan[P.i3]);
    for(int u=0;u<A.m;u++)for(int v=0;v<B.m;v++){
      for(int k=0;k<d3;k++)
        for(int i=0;i<d1;i++)for(int j=0;j<d2;j++){
          double c = cg[(i*d2+j)*d3+k];
          if(std::fabs(c)<1e-8) continue;
          int iabs = map1(s1[P.i1]+u*d1+i);
          int jabs = s2[P.i2]+v*d2+j;
          cg_pk.push_back((uint32_t)iabs | ((uint32_t)jabs<<8) | ((uint32_t)(sbase+k)<<16));
          cg_c.push_back((float)c);
        }
      for(int w=0;w<C.m;w++)for(int k=0;k<d3;k++){
        OE o; o.opos=s3[P.i3]+w*d3+k; o.widx=P.w0+(u*B.m+v)*C.m+w; o.s=sbase+k; o.coef=(float)alpha;
        outs.push_back(o);
      }
      sbase += d3;
    }
  }
  if(sort_out) std::stable_sort(outs.begin(), outs.end(),
      [](const OE&a,const OE&b){return a.opos<b.opos;});
  for(auto&o:outs){
    out_pk.push_back((uint32_t)o.opos | ((uint32_t)o.widx<<8) | ((uint32_t)o.s<<20));
    out_c.push_back(o.coef);
  }
}

static void make_chunks(const std::vector<uint32_t>& pk, int shift, uint32_t mask, int* bnd){
  int n=(int)pk.size();
  bnd[0]=0; bnd[8]=n;
  for(int c=1;c<8;c++){
    int p = (int)(((long long)n*c)/8);
    while(p>0 && p<n && ((pk[p]>>shift)&mask)==((pk[p-1]>>shift)&mask)) p++;
    bnd[c] = p>n? n : p;
  }
  for(int c=1;c<=8;c++) if(bnd[c]<bnd[c-1]) bnd[c]=bnd[c-1];
}

static void build_tables(TPTables& T){
  std::vector<HIrr> IR_SH   ={{1,0,1},{1,1,-1},{1,2,1},{1,3,-1}};
  std::vector<HIrr> GATE_IN ={{16,0,1},{16,0,-1},{8,0,1},{8,0,-1},{8,0,1},{8,0,-1},{16,1,-1},{16,1,1}};
  std::vector<HIrr> GATE_OUT={{16,0,1},{16,0,-1},{16,1,-1},{16,1,1}};
  std::vector<HIrr> IR_OUT  ={{1,0,1}};
  std::vector<uint32_t> cg1,o1,cg2,o2; std::vector<float> cg1c,o1c,cg2c,o2c;
  build_one(IR_SH,IR_SH,GATE_IN,map_id,true,cg1,cg1c,o1,o1c);
  build_one(GATE_OUT,IR_SH,IR_OUT,map_gate,false,cg2,cg2c,o2,o2c);
  memset(&T,0,sizeof(T));
  T.n_cg1=(int)cg1.size(); T.n_out1=(int)o1.size();
  T.n_cg2=(int)cg2.size(); T.n_out2=(int)o2.size();
  for(size_t i=0;i<cg1.size()&&i<1024;i++){ T.cg1_pk[i]=cg1[i]; T.cg1_c[i]=cg1c[i]; }
  for(size_t i=0;i<o1.size()&&i<768;i++){ T.out1_pk[i]=o1[i]; T.out1_c[i]=o1c[i]; }
  for(size_t i=0;i<cg2.size()&&i<192;i++){ T.cg2_pk[i]=cg2[i]; T.cg2_c[i]=cg2c[i]; }
  for(size_t i=0;i<o2.size()&&i<64;i++){ T.out2_pk[i]=o2[i]; T.out2_c[i]=o2c[i]; }
  make_chunks(cg1,16,0xFFFFu,T.cg1_bnd);
  make_chunks(o1,0,0xFFu,T.out1_bnd);
}

// ---------------- device helpers ----------------
__device__ __forceinline__ void sph16(float x,float y,float z,float* sh){
  float x2=x*x, y2=y*y, z2=z*z;
  const float SQ3=1.7320508075688772f, SQ5=2.23606797749979f, SQ7=2.6457513110645907f;
  const float SQ15=3.872983346207417f, SQ42=6.48074069840786f, SQ70=8.366600265340756f, SQ105=10.246950765959598f;
  sh[0]=1.f;
  sh[1]=SQ3*y;  sh[2]=SQ3*z;  sh[3]=SQ3*x;
  sh[4]=SQ15*x*y; sh[5]=SQ15*y*z; sh[6]=0.5f*SQ5*(3.f*z2-1.f); sh[7]=SQ15*x*z; sh[8]=0.5f*SQ15*(x2-y2);
  sh[9]=0.25f*SQ70*y*(3.f*x2-y2); sh[10]=SQ105*x*y*z; sh[11]=0.25f*SQ42*y*(5.f*z2-1.f);
  sh[12]=0.5f*SQ7*z*(5.f*z2-3.f); sh[13]=0.25f*SQ42*x*(5.f*z2-1.f);
  sh[14]=0.5f*SQ105*z*(x2-y2);    sh[15]=0.25f*SQ70*x*(x2-3.f*y2);
}

__device__ __forceinline__ void radial10(float d, float* emb){
  const float step = 0.2909090909090909f; // 3.2/11
  #pragma unroll
  for(int b=0;b<10;b++){
    float c = step*(float)(b+1);
    float u = (d-c)/step;
    float u2 = u*u;
    float f = 0.f;
    if(u2<1.f) f = 1.14136f*__expf(-u2/fmaxf(1.f-u2,1e-6f));
    emb[b] = f*3.1622776601683795f; // *sqrt(10)
  }
}

// ---------------- kernels ----------------
__global__ void k_zero(float* a, int na, float* b, int nb, float* c, int nc){
  int total = na+nb+nc;
  for(int i = blockIdx.x*blockDim.x+threadIdx.x; i<total; i += gridDim.x*blockDim.x){
    if(i<na) a[i]=0.f;
    else if(i<na+nb) b[i-na]=0.f;
    else c[i-na-nb]=0.f;
  }
}

// per-edge: sh, scatter into node features x (segment_sum(sh, edge_dst))
__global__ void k_edge_pre(const float* __restrict__ pos, const int* __restrict__ esrc,
                           const int* __restrict__ edst, float* __restrict__ x, int E){
  int e = blockIdx.x*256 + threadIdx.x;
  if(e>=E) return;
  int s=esrc[e], d=edst[e];
  float ex=pos[3*d]-pos[3*s], ey=pos[3*d+1]-pos[3*s+1], ez=pos[3*d+2]-pos[3*s+2];
  float dd = sqrtf(ex*ex+ey*ey+ez*ez+1e-12f);
  float sh[16];
  sph16(ex/dd, ey/dd, ez/dd, sh);
  #pragma unroll
  for(int j=0;j<16;j++) atomicAdd(&x[(size_t)d*16+j], sh[j]);
}

// fused: radial MLP fc1 (10->256->272) + TP1 apply + scatter into ef1
__global__ __launch_bounds__(256) void k_fc1_tp1(
    const float* __restrict__ pos, const int* __restrict__ esrc, const int* __restrict__ edst,
    const float* __restrict__ W1, const float* __restrict__ W2,
    const float* __restrict__ xnode, float* __restrict__ ef1,
    const TPTables* __restrict__ T, int E, float inv_nn)
{
  __shared__ float sm[19360];
  __shared__ int src_t[TILE], dst_t[TILE];
  float* sh_t  = sm;           // [32][17]
  float* x1_t  = sm + 544;     // [32][17]
  float* Wt    = sm + 1088;    // [32][272]
  float* emb_t = sm + 9792;    // [32][11]
  float* Hc    = sm + 10144;   // [256][36]
  float* S_l   = sm + 9792;    // alias over emb/Hc (dead by TP phase): [32][40]
  int t = threadIdx.x;
  int e0 = blockIdx.x*TILE;
  int nE = min(TILE, E-e0);

  if(t<TILE){
    float embr[10];
    if(t<nE){
      int s=esrc[e0+t], d=edst[e0+t];
      src_t[t]=s; dst_t[t]=d;
      float ex=pos[3*d]-pos[3*s], ey=pos[3*d+1]-pos[3*s+1], ez=pos[3*d+2]-pos[3*s+2];
      float dd=sqrtf(ex*ex+ey*ey+ez*ez+1e-12f);
      sph16(ex/dd,ey/dd,ez/dd, &sh_t[t*17]);
      radial10(dd, embr);
    } else {
      src_t[t]=0; dst_t[t]=-1;
      #pragma unroll
      for(int j=0;j<16;j++) sh_t[t*17+j]=0.f;
      #pragma unroll
      for(int b=0;b<10;b++) embr[b]=0.f;
    }
    #pragma unroll
    for(int b=0;b<10;b++) emb_t[t*11+b]=embr[b];
  }
  __syncthreads();
  for(int i=t;i<TILE*16;i+=256){ int e=i>>4, j=i&15; x1_t[e*17+j] = xnode[(size_t)src_t[e]*16+j]*inv_nn; }
  // H = relu(emb @ W1/sqrt(10)) * sqrt(2)   -> Hc[k][e]
  {
    int e = t&31, kg = t>>5;
    float er[10];
    #pragma unroll
    for(int b=0;b<10;b++) er[b]=emb_t[e*11+b];
    for(int j=0;j<32;j++){
      int k = kg*32+j;
      float a=0.f;
      #pragma unroll
      for(int b=0;b<10;b++) a += er[b]*W1[b*256+k];
      Hc[k*36+e] = fmaxf(a*0.31622776601683794f, 0.f)*1.4142135623730951f;
    }
  }
  __syncthreads();
  // W = (H @ W2) / 16
  for(int pass=0; pass<2; pass++){
    int c = t + pass*256;
    if(c<272){
      float acc[TILE];
      #pragma unroll
      for(int e=0;e<TILE;e++) acc[e]=0.f;
      for(int k=0;k<256;k++){
        float wv = W2[k*272+c];
        const float4* hr = (const float4*)(Hc + k*36);
        #pragma unroll
        for(int q=0;q<8;q++){
          float4 h4 = hr[q];
          acc[4*q+0]+=h4.x*wv; acc[4*q+1]+=h4.y*wv; acc[4*q+2]+=h4.z*wv; acc[4*q+3]+=h4.w*wv;
        }
      }
      #pragma unroll
      for(int e=0;e<TILE;e++) Wt[e*272+c] = acc[e]*0.0625f;
    }
  }
  __syncthreads();
  // TP1: 8 threads per edge
  int e = t>>3, g = t&7;
  {
    int beg=T->cg1_bnd[g], end=T->cg1_bnd[g+1];
    float acc=0.f; int cur=-1;
    for(int idx=beg; idx<end; idx++){
      uint32_t pk = T->cg1_pk[idx]; float c = T->cg1_c[idx];
      int i = pk&0xff, j=(pk>>8)&0xff, s=(int)(pk>>16);
      if(s!=cur){ if(cur>=0) S_l[e*40+cur]=acc; cur=s; acc=0.f; }
      acc += c * x1_t[e*17+i] * sh_t[e*17+j];
    }
    if(cur>=0) S_l[e*40+cur]=acc;
  }
  __syncthreads();
  if(e<nE){
    int dst = dst_t[e];
    int beg=T->out1_bnd[g], end=T->out1_bnd[g+1];
    float acc=0.f; int cur=-1;
    for(int idx=beg; idx<end; idx++){
      uint32_t pk=T->out1_pk[idx]; float cf=T->out1_c[idx];
      int opos=(int)(pk&0xff), widx=(int)((pk>>8)&0xfff), s=(int)(pk>>20);
      if(opos!=cur){ if(cur>=0) atomicAdd(&ef1[(size_t)dst*160+cur], acc); cur=opos; acc=0.f; }
      acc += cf * Wt[e*272+widx] * S_l[e*40+s];
    }
    if(cur>=0) atomicAdd(&ef1[(size_t)dst*160+cur], acc);
  }
}

// gate activation on node features
__global__ void k_gate(const float* __restrict__ ef1, float* __restrict__ xg, int N, float inv_nn){
  int n = blockIdx.x*256+threadIdx.x;
  if(n>=N) return;
  const float* v = ef1 + (size_t)n*160;
  float* o = xg + (size_t)n*128;
  float g[32];
  #pragma unroll
  for(int i=0;i<16;i++) o[i] = fmaxf(v[i]*inv_nn, 0.f);
  #pragma unroll
  for(int i=0;i<16;i++) o[16+i] = tanhf(v[16+i]*inv_nn);
  #pragma unroll
  for(int i=0;i<8;i++) g[i]    = fmaxf(v[32+i]*inv_nn,0.f);
  #pragma unroll
  for(int i=0;i<8;i++) g[8+i]  = tanhf(v[40+i]*inv_nn);
  #pragma unroll
  for(int i=0;i<8;i++) g[16+i] = fmaxf(v[48+i]*inv_nn,0.f);
  #pragma unroll
  for(int i=0;i<8;i++) g[24+i] = tanhf(v[56+i]*inv_nn);
  #pragma unroll
  for(int u=0;u<32;u++){
    float gu = g[u];
    #pragma unroll
    for(int k=0;k<3;k++) o[32+u*3+k] = v[64+u*3+k]*inv_nn*gu;
  }
}

// fused: radial MLP fc2 (10->256->32) + TP2 + per-graph reduction
__global__ __launch_bounds__(256) void k_fc2_tp2(
    const float* __restrict__ pos, const int* __restrict__ esrc, const int* __restrict__ edst,
    const int* __restrict__ batch,
    const float* __restrict__ W1, const float* __restrict__ W2,
    const float* __restrict__ xg, float* __restrict__ out,
    const TPTables* __restrict__ T, int E, float out_scale, int G)
{
  __shared__ float sm[13216];
  __shared__ int src_t[TILE], dst_t[TILE], g_t[TILE];
  float* sh_t  = sm;              // [32][17] : 544
  float* xg_t  = sm + 544;        // [32][65] : 2080
  float* Wt    = sm + 2624;       // [32][32] : 1024
  float* emb_t = sm + 3648;       // [32][11] : 352
  float* Hc    = sm + 4000;       // [256][36]: 9216
  float* S_l   = sm + 3648;       // alias: [32][33] : 1056
  float* bins  = sm + 3648+1056;  // alias: [64]
  int t = threadIdx.x;
  int e0 = blockIdx.x*TILE;
  int nE = min(TILE, E-e0);

  if(t<TILE){
    float embr[10];
    if(t<nE){
      int s=esrc[e0+t], d=edst[e0+t];
      src_t[t]=s; dst_t[t]=d; g_t[t]=batch[d];
      float ex=pos[3*d]-pos[3*s], ey=pos[3*d+1]-pos[3*s+1], ez=pos[3*d+2]-pos[3*s+2];
      float dd=sqrtf(ex*ex+ey*ey+ez*ez+1e-12f);
      sph16(ex/dd,ey/dd,ez/dd, &sh_t[t*17]);
      radial10(dd, embr);
    } else {
      src_t[t]=0; dst_t[t]=-1; g_t[t]=0;
      #pragma unroll
      for(int j=0;j<16;j++) sh_t[t*17+j]=0.f;
      #pragma unroll
      for(int b=0;b<10;b++) embr[b]=0.f;
    }
    #pragma unroll
    for(int b=0;b<10;b++) emb_t[t*11+b]=embr[b];
  }
  __syncthreads();
  // gather used gate dims: {0..15} and {32..79} -> compressed [0,64)
  for(int i=t;i<TILE*64;i+=256){
    int e=i>>6, j=i&63;
    xg_t[e*65+j] = xg[(size_t)src_t[e]*128 + (j<16? j : j+16)];
  }
  {
    int e = t&31, kg = t>>5;
    float er[10];
    #pragma unroll
    for(int b=0;b<10;b++) er[b]=emb_t[e*11+b];
    for(int j=0;j<32;j++){
      int k = kg*32+j;
      float a=0.f;
      #pragma unroll
      for(int b=0;b<10;b++) a += er[b]*W1[b*256+k];
      Hc[k*36+e] = fmaxf(a*0.31622776601683794f, 0.f)*1.4142135623730951f;
    }
  }
  __syncthreads();
  {
    int c = t&31, eb = (t>>5)*4;
    float acc0=0.f, acc1=0.f, acc2=0.f, acc3=0.f;
    for(int k=0;k<256;k++){
      float wv = W2[k*32+c];
      float4 h4 = *(const float4*)(Hc + k*36 + eb);
      acc0+=h4.x*wv; acc1+=h4.y*wv; acc2+=h4.z*wv; acc3+=h4.w*wv;
    }
    Wt[(eb+0)*32+c]=acc0*0.0625f; Wt[(eb+1)*32+c]=acc1*0.0625f;
    Wt[(eb+2)*32+c]=acc2*0.0625f; Wt[(eb+3)*32+c]=acc3*0.0625f;
  }
  __syncthreads();
  if(t<64) bins[t]=0.f;
  __syncthreads();
  if(t<nE){
    int e=t;
    {
      float acc=0.f; int cur=-1;
      int n=T->n_cg2;
      for(int idx=0;idx<n;idx++){
        uint32_t pk=T->cg2_pk[idx]; float c=T->cg2_c[idx];
        int i=pk&0xff, j=(pk>>8)&0xff, s=(int)(pk>>16);
        if(s!=cur){ if(cur>=0) S_l[e*33+cur]=acc; cur=s; acc=0.f; }
        acc += c*xg_t[e*65+i]*sh_t[e*17+j];
      }
      if(cur>=0) S_l[e*33+cur]=acc;
    }
    float v=0.f;
    int n=T->n_out2;
    for(int idx=0;idx<n;idx++){
      uint32_t pk=T->out2_pk[idx]; float cf=T->out2_c[idx];
      int widx=(int)((pk>>8)&0xfff), s=(int)(pk>>20);
      v += cf * Wt[e*32+widx] * S_l[e*33+s];
    }
    atomicAdd(&bins[g_t[e]], v);
  }
  __syncthreads();
  if(t<G) atomicAdd(&out[t], bins[t]*out_scale);
}

// ---------------- launch ----------------
extern "C" void kernel_launch(void* const* d_in, const int* in_sizes, int n_in,
                              void* d_out, int out_size, void* d_ws, size_t ws_size,
                              hipStream_t stream) {
  const float* pos  = (const float*)d_in[0];
  const float* w11  = (const float*)d_in[1];
  const float* w12  = (const float*)d_in[2];
  const float* w21  = (const float*)d_in[3];
  const float* w22  = (const float*)d_in[4];
  const int*   esrc = (const int*)d_in[5];
  const int*   edst = (const int*)d_in[6];
  const int*   batch= (const int*)d_in[7];
  int E = in_sizes[5];
  int N = in_sizes[0]/3;
  int G = out_size;

  double nn = std::sqrt((double)E/(double)N);
  float inv_nn    = (float)(1.0/nn);
  float out_scale = (float)(1.0/(nn*std::sqrt((double)N)));

  float* ws = (float*)d_ws;
  float* x   = ws;                          // N*16
  float* ef1 = x   + (size_t)N*16;          // N*160
  float* xg  = ef1 + (size_t)N*160;         // N*128
  TPTables* dT = (TPTables*)(xg + (size_t)N*128);

  static TPTables hT;
  build_tables(hT);   // deterministic; same contents every call
  hipMemcpyAsync(dT, &hT, sizeof(TPTables), hipMemcpyHostToDevice, stream);

  int nz = N*16 + N*160 + G;
  int zgrid = (nz+255)/256; if(zgrid>2048) zgrid=2048;
  k_zero<<<zgrid,256,0,stream>>>(x, N*16, ef1, N*160, (float*)d_out, G);
  k_edge_pre<<<(E+255)/256,256,0,stream>>>(pos, esrc, edst, x, E);
  k_fc1_tp1<<<(E+TILE-1)/TILE,256,0,stream>>>(pos, esrc, edst, w11, w12, x, ef1, dT, E, inv_nn);
  k_gate<<<(N+255)/256,256,0,stream>>>(ef1, xg, N, inv_nn);
  k_fc2_tp2<<<(E+TILE-1)/TILE,256,0,stream>>>(pos, esrc, edst, batch, w21, w22, xg,
                                              (float*)d_out, dT, E, out_scale, G);
}

// Round 2
// 5016.703 us; speedup vs baseline: 1.2417x; 1.2417x over previous
//
#include <hip/hip_runtime.h>
#include <cmath>
#include <cstdint>
#include <cstring>
#include <cstdlib>
#include <vector>
#include <algorithm>
#include <complex>

#define TILE 32

typedef __attribute__((ext_vector_type(8))) short bf16x8;
typedef __attribute__((ext_vector_type(4))) float f32x4;

// ------------------------------------------------------------------
// Sparse tensor-product tables (host-built, deterministic, one async H2D).
// ------------------------------------------------------------------
struct TPTables {
  int cg1_bnd[9];
  int out1_bnd[9];
  int n_cg1, n_out1, n_cg2, n_out2;
  uint32_t cg1_pk[1024]; float cg1_c[1024];
  uint32_t out1_pk[768]; float out1_c[768];
  uint32_t cg2_pk[192];  float cg2_c[192];
  uint32_t out2_pk[64];  float out2_c[64];
};

static double factd(int n){ double r=1; for(int i=2;i<=n;i++) r*=(double)i; return r; }

static double cg_complex(int j1,int m1,int j2,int m2,int j3,int m3){
  if(m1+m2!=m3) return 0.0;
  double pref = std::sqrt((2*j3+1)*factd(j3+j1-j2)*factd(j3-j1+j2)*factd(j1+j2-j3)/factd(j1+j2+j3+1));
  pref *= std::sqrt(factd(j3+m3)*factd(j3-m3)*factd(j1-m1)*factd(j1+m1)*factd(j2-m2)*factd(j2+m2));
  double s=0.0;
  for(int k=0;k<=j1+j2-j3;k++){
    int dd[6] = {k, j1+j2-j3-k, j1-m1-k, j2+m2-k, j3-j2+m1+k, j3-j1-m2+k};
    bool ok=true; double prod=1.0;
    for(int t=0;t<6;t++){ if(dd[t]<0){ok=false;break;} prod*=factd(dd[t]); }
    if(!ok) continue;
    s += ((k&1)?-1.0:1.0)/prod;
  }
  return pref*s;
}

typedef std::complex<double> cd;
static void real_U(int l, cd* U){
  int n = 2*l+1;
  for(int i=0;i<n*n;i++) U[i]=cd(0,0);
  U[l*n+l] = cd(1,0);
  for(int m=1;m<=l;m++){
    double sgn = (m&1)? -1.0 : 1.0;
    double is2 = 1.0/std::sqrt(2.0);
    U[(l+m)*n + (l+m)] = cd(sgn*is2,0);
    U[(l+m)*n + (l-m)] = cd(is2,0);
    U[(l-m)*n + (l+m)] = cd(0,-sgn*is2);
    U[(l-m)*n + (l-m)] = cd(0,is2);
  }
}

static void real_cg_h(int l1,int l2,int l3, double* out){
  int n1=2*l1+1,n2=2*l2+1,n3=2*l3+1;
  std::vector<cd> C(n1*n2*n3);
  for(int a=-l1;a<=l1;a++)for(int b=-l2;b<=l2;b++)for(int c=-l3;c<=l3;c++)
    C[(size_t)((a+l1)*n2+(b+l2))*n3+(c+l3)] = cd(cg_complex(l1,a,l2,b,l3,c),0);
  std::vector<cd> U1(n1*n1),U2(n2*n2),U3(n3*n3);
  real_U(l1,U1.data()); real_U(l2,U2.data()); real_U(l3,U3.data());
  std::vector<cd> T((size_t)n1*n2*n3, cd(0,0));
  for(int i=0;i<n1;i++)for(int j=0;j<n2;j++)for(int k=0;k<n3;k++){
    cd acc(0,0);
    for(int a=0;a<n1;a++){ cd u1=U1[i*n1+a]; if(u1==cd(0,0)) continue;
      for(int b=0;b<n2;b++){ cd u2=U2[j*n2+b]; if(u2==cd(0,0)) continue;
        for(int c=0;c<n3;c++){ cd u3=std::conj(U3[k*n3+c]); if(u3==cd(0,0)) continue;
          acc += u1*u2*u3*C[(size_t)(a*n2+b)*n3+c];
        } } }
    T[(size_t)(i*n2+j)*n3+k]=acc;
  }
  double sr=0, si=0;
  for(auto&z:T){ sr += std::fabs(z.real()); si += std::fabs(z.imag()); }
  int tot=n1*n2*n3;
  std::vector<double> R(tot);
  for(int i=0;i<tot;i++) R[i] = (sr>=si)? T[i].real() : T[i].imag();
  double nrm=0; for(double v:R) nrm += v*v; nrm = std::sqrt(nrm);
  for(int i=0;i<tot;i++) out[i] = R[i]/nrm;
}

struct HIrr{int m,l,p;};
static int map_id(int i){return i;}
static int map_gate(int i){return (i<16)? i : i-16;}

static void build_one(const std::vector<HIrr>& ir1, const std::vector<HIrr>& ir2,
                      const std::vector<HIrr>& ir3, int (*map1)(int), bool sort_out,
                      std::vector<uint32_t>& cg_pk, std::vector<float>& cg_c,
                      std::vector<uint32_t>& out_pk, std::vector<float>& out_c)
{
  int n1=(int)ir1.size(), n2=(int)ir2.size(), n3=(int)ir3.size();
  std::vector<int> s1(n1), s2(n2), s3(n3);
  { int o=0; for(int i=0;i<n1;i++){ s1[i]=o; o+=ir1[i].m*(2*ir1[i].l+1);} }
  { int o=0; for(int i=0;i<n2;i++){ s2[i]=o; o+=ir2[i].m*(2*ir2[i].l+1);} }
  { int o=0; for(int i=0;i<n3;i++){ s3[i]=o; o+=ir3[i].m*(2*ir3[i].l+1);} }
  struct Inst{int i1,i2,i3,w0;};
  std::vector<Inst> insts; int woff=0;
  for(int i1=0;i1<n1;i1++)for(int i2=0;i2<n2;i2++)for(int i3=0;i3<n3;i3++){
    const HIrr&A=ir1[i1];const HIrr&B=ir2[i2];const HIrr&C=ir3[i3];
    int dl = A.l-B.l; if(dl<0) dl=-dl;
    if(A.p*B.p==C.p && dl<=C.l && C.l<=A.l+B.l){
      insts.push_back({i1,i2,i3,woff}); woff += A.m*B.m*C.m;
    }
  }
  std::vector<int> fan(n3,0);
  for(auto&P:insts) fan[P.i3] += ir1[P.i1].m*ir2[P.i2].m;
  struct OE{int opos,widx,s;float coef;};
  std::vector<OE> outs;
  int sbase=0;
  for(auto&P:insts){
    const HIrr&A=ir1[P.i1];const HIrr&B=ir2[P.i2];const HIrr&C=ir3[P.i3];
    int d1=2*A.l+1,d2=2*B.l+1,d3=2*C.l+1;
    double cg[343];
    real_cg_h(A.l,B.l,C.l,cg);
    double alpha = std::sqrt((double)d3/(double)fan[P.i3]);
    for(int u=0;u<A.m;u++)for(int v=0;v<B.m;v++){
      for(int k=0;k<d3;k++)
        for(int i=0;i<d1;i++)for(int j=0;j<d2;j++){
          double c = cg[(i*d2+j)*d3+k];
          if(std::fabs(c)<1e-8) continue;
          int iabs = map1(s1[P.i1]+u*d1+i);
          int jabs = s2[P.i2]+v*d2+j;
          cg_pk.push_back((uint32_t)iabs | ((uint32_t)jabs<<8) | ((uint32_t)(sbase+k)<<16));
          cg_c.push_back((float)c);
        }
      for(int w=0;w<C.m;w++)for(int k=0;k<d3;k++){
        OE o; o.opos=s3[P.i3]+w*d3+k; o.widx=P.w0+(u*B.m+v)*C.m+w; o.s=sbase+k; o.coef=(float)alpha;
        outs.push_back(o);
      }
      sbase += d3;
    }
  }
  if(sort_out) std::stable_sort(outs.begin(), outs.end(),
      [](const OE&a,const OE&b){return a.opos<b.opos;});
  for(auto&o:outs){
    out_pk.push_back((uint32_t)o.opos | ((uint32_t)o.widx<<8) | ((uint32_t)o.s<<20));
    out_c.push_back(o.coef);
  }
}

static void make_chunks(const std::vector<uint32_t>& pk, int shift, uint32_t mask, int* bnd){
  int n=(int)pk.size();
  bnd[0]=0; bnd[8]=n;
  for(int c=1;c<8;c++){
    int p = (int)(((long long)n*c)/8);
    while(p>0 && p<n && ((pk[p]>>shift)&mask)==((pk[p-1]>>shift)&mask)) p++;
    bnd[c] = p>n? n : p;
  }
  for(int c=1;c<=8;c++) if(bnd[c]<bnd[c-1]) bnd[c]=bnd[c-1];
}

static void build_tables(TPTables& T){
  std::vector<HIrr> IR_SH   ={{1,0,1},{1,1,-1},{1,2,1},{1,3,-1}};
  std::vector<HIrr> GATE_IN ={{16,0,1},{16,0,-1},{8,0,1},{8,0,-1},{8,0,1},{8,0,-1},{16,1,-1},{16,1,1}};
  std::vector<HIrr> GATE_OUT={{16,0,1},{16,0,-1},{16,1,-1},{16,1,1}};
  std::vector<HIrr> IR_OUT  ={{1,0,1}};
  std::vector<uint32_t> cg1,o1,cg2,o2; std::vector<float> cg1c,o1c,cg2c,o2c;
  build_one(IR_SH,IR_SH,GATE_IN,map_id,true,cg1,cg1c,o1,o1c);
  build_one(GATE_OUT,IR_SH,IR_OUT,map_gate,false,cg2,cg2c,o2,o2c);
  memset(&T,0,sizeof(T));
  T.n_cg1=(int)cg1.size(); T.n_out1=(int)o1.size();
  T.n_cg2=(int)cg2.size(); T.n_out2=(int)o2.size();
  for(size_t i=0;i<cg1.size()&&i<1024;i++){ T.cg1_pk[i]=cg1[i]; T.cg1_c[i]=cg1c[i]; }
  for(size_t i=0;i<o1.size()&&i<768;i++){ T.out1_pk[i]=o1[i]; T.out1_c[i]=o1c[i]; }
  for(size_t i=0;i<cg2.size()&&i<192;i++){ T.cg2_pk[i]=cg2[i]; T.cg2_c[i]=cg2c[i]; }
  for(size_t i=0;i<o2.size()&&i<64;i++){ T.out2_pk[i]=o2[i]; T.out2_c[i]=o2c[i]; }
  make_chunks(cg1,16,0xFFFFu,T.cg1_bnd);
  make_chunks(o1,0,0xFFu,T.out1_bnd);
}

// ---------------- device helpers ----------------
__device__ __forceinline__ unsigned short f2bf(float f){
  uint32_t u = __float_as_uint(f);
  uint32_t r = (u + 0x7FFFu + ((u>>16)&1u)) >> 16;
  return (unsigned short)r;
}

__device__ __forceinline__ void sph16(float x,float y,float z,float* sh){
  float x2=x*x, y2=y*y, z2=z*z;
  const float SQ3=1.7320508075688772f, SQ5=2.23606797749979f, SQ7=2.6457513110645907f;
  const float SQ15=3.872983346207417f, SQ42=6.48074069840786f, SQ70=8.366600265340756f, SQ105=10.246950765959598f;
  sh[0]=1.f;
  sh[1]=SQ3*y;  sh[2]=SQ3*z;  sh[3]=SQ3*x;
  sh[4]=SQ15*x*y; sh[5]=SQ15*y*z; sh[6]=0.5f*SQ5*(3.f*z2-1.f); sh[7]=SQ15*x*z; sh[8]=0.5f*SQ15*(x2-y2);
  sh[9]=0.25f*SQ70*y*(3.f*x2-y2); sh[10]=SQ105*x*y*z; sh[11]=0.25f*SQ42*y*(5.f*z2-1.f);
  sh[12]=0.5f*SQ7*z*(5.f*z2-3.f); sh[13]=0.25f*SQ42*x*(5.f*z2-1.f);
  sh[14]=0.5f*SQ105*z*(x2-y2);    sh[15]=0.25f*SQ70*x*(x2-3.f*y2);
}

__device__ __forceinline__ void radial10(float d, float* emb){
  const float step = 0.2909090909090909f;
  #pragma unroll
  for(int b=0;b<10;b++){
    float c = step*(float)(b+1);
    float u = (d-c)/step;
    float u2 = u*u;
    float f = 0.f;
    if(u2<1.f) f = 1.14136f*__expf(-u2/fmaxf(1.f-u2,1e-6f));
    emb[b] = f*3.1622776601683795f;
  }
}

// ---------------- kernels ----------------
__global__ void k_zero(float* a, int na, float* b, int nb, float* c, int nc){
  int total = na+nb+nc;
  for(int i = blockIdx.x*blockDim.x+threadIdx.x; i<total; i += gridDim.x*blockDim.x){
    if(i<na) a[i]=0.f;
    else if(i<na+nb) b[i-na]=0.f;
    else c[i-na-nb]=0.f;
  }
}

// Pre-pack W2 matrices into bf16 MFMA B-fragments.
// Slot mapping (shared with A-side reads; only A/B consistency matters):
//   k = ks*32 + g*4 + (s&3) + ((s>>2)<<4),  g = lane>>4, c = ct*16 + (lane&15)
__global__ void k_prep(const float* __restrict__ W2a, const float* __restrict__ W2b,
                       unsigned short* __restrict__ B1, unsigned short* __restrict__ B2){
  int i = blockIdx.x*256 + threadIdx.x;
  if(i < 17*8*64*8){
    int s = i&7, lane = (i>>3)&63, ks = (i>>9)&7, ct = i>>12;
    int g = lane>>4;
    int k = ks*32 + g*4 + (s&3) + ((s>>2)<<4);
    int c = ct*16 + (lane&15);
    B1[i] = f2bf(W2a[k*272+c]);
  } else if(i < 17*8*64*8 + 2*8*64*8){
    int j = i - 17*8*64*8;
    int s = j&7, lane = (j>>3)&63, ks = (j>>9)&7, ct = j>>12;
    int g = lane>>4;
    int k = ks*32 + g*4 + (s&3) + ((s>>2)<<4);
    int c = ct*16 + (lane&15);
    B2[j] = f2bf(W2b[k*32+c]);
  }
}

__global__ void k_edge_pre(const float* __restrict__ pos, const int* __restrict__ esrc,
                           const int* __restrict__ edst, float* __restrict__ x, int E){
  int e = blockIdx.x*256 + threadIdx.x;
  if(e>=E) return;
  int s=esrc[e], d=edst[e];
  float ex=pos[3*d]-pos[3*s], ey=pos[3*d+1]-pos[3*s+1], ez=pos[3*d+2]-pos[3*s+2];
  float dd = sqrtf(ex*ex+ey*ey+ez*ez+1e-12f);
  float sh[16];
  sph16(ex/dd, ey/dd, ez/dd, sh);
  #pragma unroll
  for(int j=0;j<16;j++) atomicAdd(&x[(size_t)d*16+j], sh[j]);
}

// LDS layout (floats) for k_fc1_tp1:
//   sh_t   @0      [32][17]  (544)
//   x1_t   @544    [32][17]  (544)
//   emb_t  @1088   [32][11]  (352)
//   Wt     @1440   [32][276] (8832)   fp32 W per edge
//   Hbf    @10272  [32][284] ushort (4544 floats); S_l aliases @10272 [32][40]
#define F1_SH   0
#define F1_X1   544
#define F1_EMB  1088
#define F1_WT   1440
#define F1_H    10272
#define F1_TOT  14816
#define HSTRIDE 284
#define WSTRIDE 276

__global__ __launch_bounds__(256) void k_fc1_tp1(
    const float* __restrict__ pos, const int* __restrict__ esrc, const int* __restrict__ edst,
    const float* __restrict__ W1, const unsigned short* __restrict__ B1,
    const float* __restrict__ xnode, float* __restrict__ ef1,
    const TPTables* __restrict__ T, int E, float inv_nn)
{
  __shared__ __align__(16) float sm[F1_TOT];
  __shared__ int src_t[TILE], dst_t[TILE];
  float* sh_t  = sm + F1_SH;
  float* x1_t  = sm + F1_X1;
  float* emb_t = sm + F1_EMB;
  float* Wt    = sm + F1_WT;
  unsigned short* Hbf = (unsigned short*)(sm + F1_H);
  float* S_l   = sm + F1_H;
  int t = threadIdx.x;
  int e0 = blockIdx.x*TILE;
  int nE = min(TILE, E-e0);

  if(t<TILE){
    float embr[10];
    if(t<nE){
      int s=esrc[e0+t], d=edst[e0+t];
      src_t[t]=s; dst_t[t]=d;
      float ex=pos[3*d]-pos[3*s], ey=pos[3*d+1]-pos[3*s+1], ez=pos[3*d+2]-pos[3*s+2];
      float dd=sqrtf(ex*ex+ey*ey+ez*ez+1e-12f);
      sph16(ex/dd,ey/dd,ez/dd, &sh_t[t*17]);
      radial10(dd, embr);
    } else {
      src_t[t]=0; dst_t[t]=-1;
      #pragma unroll
      for(int j=0;j<16;j++) sh_t[t*17+j]=0.f;
      #pragma unroll
      for(int b=0;b<10;b++) embr[b]=0.f;
    }
    #pragma unroll
    for(int b=0;b<10;b++) emb_t[t*11+b]=embr[b];
  }
  __syncthreads();
  for(int i=t;i<TILE*16;i+=256){ int e=i>>4, j=i&15; x1_t[e*17+j] = xnode[(size_t)src_t[e]*16+j]*inv_nn; }
  // H = relu(emb @ W1/sqrt(10)) * sqrt(2) -> bf16 Hbf[e][k]
  {
    int e = t&31, kg = t>>5;
    float er[10];
    #pragma unroll
    for(int b=0;b<10;b++) er[b]=emb_t[e*11+b];
    for(int j=0;j<32;j++){
      int k = kg*32+j;
      float a=0.f;
      #pragma unroll
      for(int b=0;b<10;b++) a += er[b]*W1[b*256+k];
      Hbf[e*HSTRIDE + k] = f2bf(fmaxf(a*0.31622776601683794f, 0.f)*1.4142135623730951f);
    }
  }
  __syncthreads();
  // W = (H @ W2)/16 via bf16 MFMA 16x16x32. 17 col-tiles over 4 waves, 2 row-tiles.
  {
    int wv = t>>6, lane = t&63, g = lane>>4, lr = lane&15;
    for(int ct = wv; ct < 17; ct += 4){
      f32x4 acc0 = {0.f,0.f,0.f,0.f}, acc1 = {0.f,0.f,0.f,0.f};
      for(int ks=0; ks<8; ks++){
        bf16x8 b = *(const bf16x8*)(B1 + ((size_t)(ct*8+ks)*64 + lane)*8);
        union { bf16x8 v; uint32_t w[4]; } a0, a1;
        const uint32_t* p0 = (const uint32_t*)(Hbf + lr*HSTRIDE + ks*32 + g*4);
        const uint32_t* p1 = (const uint32_t*)(Hbf + (16+lr)*HSTRIDE + ks*32 + g*4);
        a0.w[0]=p0[0]; a0.w[1]=p0[1]; a0.w[2]=p0[8]; a0.w[3]=p0[9];   // +16 ushorts = +8 u32
        a1.w[0]=p1[0]; a1.w[1]=p1[1]; a1.w[2]=p1[8]; a1.w[3]=p1[9];
        acc0 = __builtin_amdgcn_mfma_f32_16x16x32_bf16(a0.v, b, acc0, 0,0,0);
        acc1 = __builtin_amdgcn_mfma_f32_16x16x32_bf16(a1.v, b, acc1, 0,0,0);
      }
      #pragma unroll
      for(int r=0;r<4;r++){
        Wt[(g*4+r)*WSTRIDE + ct*16+lr]    = acc0[r]*0.0625f;
        Wt[(16+g*4+r)*WSTRIDE + ct*16+lr] = acc1[r]*0.0625f;
      }
    }
  }
  __syncthreads();
  // TP1: 8 threads per edge. S_l aliases the (now dead) Hbf region.
  int e = t>>3, g = t&7;
  {
    int beg=T->cg1_bnd[g], end=T->cg1_bnd[g+1];
    float acc=0.f; int cur=-1;
    for(int idx=beg; idx<end; idx++){
      uint32_t pk = T->cg1_pk[idx]; float c = T->cg1_c[idx];
      int i = pk&0xff, j=(pk>>8)&0xff, s=(int)(pk>>16);
      if(s!=cur){ if(cur>=0) S_l[e*40+cur]=acc; cur=s; acc=0.f; }
      acc += c * x1_t[e*17+i] * sh_t[e*17+j];
    }
    if(cur>=0) S_l[e*40+cur]=acc;
  }
  __syncthreads();
  if(e<nE){
    int dst = dst_t[e];
    int beg=T->out1_bnd[g], end=T->out1_bnd[g+1];
    float acc=0.f; int cur=-1;
    for(int idx=beg; idx<end; idx++){
      uint32_t pk=T->out1_pk[idx]; float cf=T->out1_c[idx];
      int opos=(int)(pk&0xff), widx=(int)((pk>>8)&0xfff), s=(int)(pk>>20);
      if(opos!=cur){ if(cur>=0) atomicAdd(&ef1[(size_t)dst*160+cur], acc); cur=opos; acc=0.f; }
      acc += cf * Wt[e*WSTRIDE+widx] * S_l[e*40+s];
    }
    if(cur>=0) atomicAdd(&ef1[(size_t)dst*160+cur], acc);
  }
}

__global__ void k_gate(const float* __restrict__ ef1, float* __restrict__ xg, int N, float inv_nn){
  int n = blockIdx.x*256+threadIdx.x;
  if(n>=N) return;
  const float* v = ef1 + (size_t)n*160;
  float* o = xg + (size_t)n*128;
  float g[32];
  #pragma unroll
  for(int i=0;i<16;i++) o[i] = fmaxf(v[i]*inv_nn, 0.f);
  #pragma unroll
  for(int i=0;i<16;i++) o[16+i] = tanhf(v[16+i]*inv_nn);
  #pragma unroll
  for(int i=0;i<8;i++) g[i]    = fmaxf(v[32+i]*inv_nn,0.f);
  #pragma unroll
  for(int i=0;i<8;i++) g[8+i]  = tanhf(v[40+i]*inv_nn);
  #pragma unroll
  for(int i=0;i<8;i++) g[16+i] = fmaxf(v[48+i]*inv_nn,0.f);
  #pragma unroll
  for(int i=0;i<8;i++) g[24+i] = tanhf(v[56+i]*inv_nn);
  #pragma unroll
  for(int u=0;u<32;u++){
    float gu = g[u];
    #pragma unroll
    for(int k=0;k<3;k++) o[32+u*3+k] = v[64+u*3+k]*inv_nn*gu;
  }
}

// LDS layout (floats) for k_fc2_tp2:
//   sh_t @0 [32][17](544) | xg_t @544 [32][65](2080) | emb_t @2624 (352)
//   Wt2 @2976 [32][36](1152) | Hbf2 @4128 [32][284]us (4544 f, S_l alias [32][33])
//   bins @8672 (64)
#define F2_SH   0
#define F2_XG   544
#define F2_EMB  2624
#define F2_WT   2976
#define F2_H    4128
#define F2_BINS 8672
#define F2_TOT  8736

__global__ __launch_bounds__(256) void k_fc2_tp2(
    const float* __restrict__ pos, const int* __restrict__ esrc, const int* __restrict__ edst,
    const int* __restrict__ batch,
    const float* __restrict__ W1, const unsigned short* __restrict__ B2,
    const float* __restrict__ xg, float* __restrict__ out,
    const TPTables* __restrict__ T, int E, float out_scale, int G)
{
  __shared__ __align__(16) float sm[F2_TOT];
  __shared__ int src_t[TILE], dst_t[TILE], g_t[TILE];
  float* sh_t  = sm + F2_SH;
  float* xg_t  = sm + F2_XG;
  float* emb_t = sm + F2_EMB;
  float* Wt    = sm + F2_WT;
  unsigned short* Hbf = (unsigned short*)(sm + F2_H);
  float* S_l   = sm + F2_H;
  float* bins  = sm + F2_BINS;
  int t = threadIdx.x;
  int e0 = blockIdx.x*TILE;
  int nE = min(TILE, E-e0);

  if(t<TILE){
    float embr[10];
    if(t<nE){
      int s=esrc[e0+t], d=edst[e0+t];
      src_t[t]=s; dst_t[t]=d; g_t[t]=batch[d];
      float ex=pos[3*d]-pos[3*s], ey=pos[3*d+1]-pos[3*s+1], ez=pos[3*d+2]-pos[3*s+2];
      float dd=sqrtf(ex*ex+ey*ey+ez*ez+1e-12f);
      sph16(ex/dd,ey/dd,ez/dd, &sh_t[t*17]);
      radial10(dd, embr);
    } else {
      src_t[t]=0; dst_t[t]=-1; g_t[t]=0;
      #pragma unroll
      for(int j=0;j<16;j++) sh_t[t*17+j]=0.f;
      #pragma unroll
      for(int b=0;b<10;b++) embr[b]=0.f;
    }
    #pragma unroll
    for(int b=0;b<10;b++) emb_t[t*11+b]=embr[b];
  }
  __syncthreads();
  for(int i=t;i<TILE*64;i+=256){
    int e=i>>6, j=i&63;
    xg_t[e*65+j] = xg[(size_t)src_t[e]*128 + (j<16? j : j+16)];
  }
  {
    int e = t&31, kg = t>>5;
    float er[10];
    #pragma unroll
    for(int b=0;b<10;b++) er[b]=emb_t[e*11+b];
    for(int j=0;j<32;j++){
      int k = kg*32+j;
      float a=0.f;
      #pragma unroll
      for(int b=0;b<10;b++) a += er[b]*W1[b*256+k];
      Hbf[e*HSTRIDE + k] = f2bf(fmaxf(a*0.31622776601683794f, 0.f)*1.4142135623730951f);
    }
  }
  __syncthreads();
  {
    int wv = t>>6, lane = t&63, g = lane>>4, lr = lane&15;
    if(wv<2){
      int ct = wv;
      f32x4 acc0 = {0.f,0.f,0.f,0.f}, acc1 = {0.f,0.f,0.f,0.f};
      for(int ks=0; ks<8; ks++){
        bf16x8 b = *(const bf16x8*)(B2 + ((size_t)(ct*8+ks)*64 + lane)*8);
        union { bf16x8 v; uint32_t w[4]; } a0, a1;
        const uint32_t* p0 = (const uint32_t*)(Hbf + lr*HSTRIDE + ks*32 + g*4);
        const uint32_t* p1 = (const uint32_t*)(Hbf + (16+lr)*HSTRIDE + ks*32 + g*4);
        a0.w[0]=p0[0]; a0.w[1]=p0[1]; a0.w[2]=p0[8]; a0.w[3]=p0[9];
        a1.w[0]=p1[0]; a1.w[1]=p1[1]; a1.w[2]=p1[8]; a1.w[3]=p1[9];
        acc0 = __builtin_amdgcn_mfma_f32_16x16x32_bf16(a0.v, b, acc0, 0,0,0);
        acc1 = __builtin_amdgcn_mfma_f32_16x16x32_bf16(a1.v, b, acc1, 0,0,0);
      }
      #pragma unroll
      for(int r=0;r<4;r++){
        Wt[(g*4+r)*36 + ct*16+lr]    = acc0[r]*0.0625f;
        Wt[(16+g*4+r)*36 + ct*16+lr] = acc1[r]*0.0625f;
      }
    }
  }
  __syncthreads();
  if(t<64) bins[t]=0.f;
  __syncthreads();
  if(t<nE){
    int e=t;
    {
      float acc=0.f; int cur=-1;
      int n=T->n_cg2;
      for(int idx=0;idx<n;idx++){
        uint32_t pk=T->cg2_pk[idx]; float c=T->cg2_c[idx];
        int i=pk&0xff, j=(pk>>8)&0xff, s=(int)(pk>>16);
        if(s!=cur){ if(cur>=0) S_l[e*33+cur]=acc; cur=s; acc=0.f; }
        acc += c*xg_t[e*65+i]*sh_t[e*17+j];
      }
      if(cur>=0) S_l[e*33+cur]=acc;
    }
    float v=0.f;
    int n=T->n_out2;
    for(int idx=0;idx<n;idx++){
      uint32_t pk=T->out2_pk[idx]; float cf=T->out2_c[idx];
      int widx=(int)((pk>>8)&0xfff), s=(int)(pk>>20);
      v += cf * Wt[e*36+widx] * S_l[e*33+s];
    }
    atomicAdd(&bins[g_t[e]], v);
  }
  __syncthreads();
  if(t<G) atomicAdd(&out[t], bins[t]*out_scale);
}

// ---------------- launch ----------------
extern "C" void kernel_launch(void* const* d_in, const int* in_sizes, int n_in,
                              void* d_out, int out_size, void* d_ws, size_t ws_size,
                              hipStream_t stream) {
  const float* pos  = (const float*)d_in[0];
  const float* w11  = (const float*)d_in[1];
  const float* w12  = (const float*)d_in[2];
  const float* w21  = (const float*)d_in[3];
  const float* w22  = (const float*)d_in[4];
  const int*   esrc = (const int*)d_in[5];
  const int*   edst = (const int*)d_in[6];
  const int*   batch= (const int*)d_in[7];
  int E = in_sizes[5];
  int N = in_sizes[0]/3;
  int G = out_size;

  double nn = std::sqrt((double)E/(double)N);
  float inv_nn    = (float)(1.0/nn);
  float out_scale = (float)(1.0/(nn*std::sqrt((double)N)));

  float* ws = (float*)d_ws;
  float* x   = ws;
  float* ef1 = x   + (size_t)N*16;
  float* xg  = ef1 + (size_t)N*160;
  TPTables* dT = (TPTables*)(xg + (size_t)N*128);
  unsigned short* B1 = (unsigned short*)(((char*)dT) + ((sizeof(TPTables)+255)&~(size_t)255));
  unsigned short* B2 = B1 + 17*8*64*8;

  static TPTables hT;
  build_tables(hT);
  hipMemcpyAsync(dT, &hT, sizeof(TPTables), hipMemcpyHostToDevice, stream);

  int nz = N*16 + N*160 + G;
  int zgrid = (nz+255)/256; if(zgrid>2048) zgrid=2048;
  k_zero<<<zgrid,256,0,stream>>>(x, N*16, ef1, N*160, (float*)d_out, G);
  k_prep<<<(17*8*64*8 + 2*8*64*8 + 255)/256,256,0,stream>>>(w12, w22, B1, B2);
  k_edge_pre<<<(E+255)/256,256,0,stream>>>(pos, esrc, edst, x, E);
  k_fc1_tp1<<<(E+TILE-1)/TILE,256,0,stream>>>(pos, esrc, edst, w11, B1, x, ef1, dT, E, inv_nn);
  k_gate<<<(N+255)/256,256,0,stream>>>(ef1, xg, N, inv_nn);
  k_fc2_tp2<<<(E+TILE-1)/TILE,256,0,stream>>>(pos, esrc, edst, batch, w21, B2, xg,
                                              (float*)d_out, dT, E, out_scale, G);
}

// Round 3
// 1777.820 us; speedup vs baseline: 3.5039x; 2.8218x over previous
//
#include <hip/hip_runtime.h>
#include <cmath>
#include <cstdint>
#include <cstring>
#include <cstdlib>
#include <vector>
#include <algorithm>
#include <complex>

#define TILE 32

typedef __attribute__((ext_vector_type(8))) _Float16 f16x8;
typedef __attribute__((ext_vector_type(4))) float f32x4;

// ------------------------------------------------------------------
// Sparse tensor-product tables (host-built, deterministic, one async H2D).
// ------------------------------------------------------------------
struct TPTables {
  int cg1_bnd[9];
  int out1_bnd[9];
  int n_cg1, n_out1, n_cg2, n_out2;
  uint32_t cg1_pk[1024]; float cg1_c[1024];
  uint32_t out1_pk[768]; float out1_c[768];
  uint32_t cg2_pk[192];  float cg2_c[192];
  uint32_t out2_pk[64];  float out2_c[64];
};

static double factd(int n){ double r=1; for(int i=2;i<=n;i++) r*=(double)i; return r; }

static double cg_complex(int j1,int m1,int j2,int m2,int j3,int m3){
  if(m1+m2!=m3) return 0.0;
  double pref = std::sqrt((2*j3+1)*factd(j3+j1-j2)*factd(j3-j1+j2)*factd(j1+j2-j3)/factd(j1+j2+j3+1));
  pref *= std::sqrt(factd(j3+m3)*factd(j3-m3)*factd(j1-m1)*factd(j1+m1)*factd(j2-m2)*factd(j2+m2));
  double s=0.0;
  for(int k=0;k<=j1+j2-j3;k++){
    int dd[6] = {k, j1+j2-j3-k, j1-m1-k, j2+m2-k, j3-j2+m1+k, j3-j1-m2+k};
    bool ok=true; double prod=1.0;
    for(int t=0;t<6;t++){ if(dd[t]<0){ok=false;break;} prod*=factd(dd[t]); }
    if(!ok) continue;
    s += ((k&1)?-1.0:1.0)/prod;
  }
  return pref*s;
}

typedef std::complex<double> cd;
static void real_U(int l, cd* U){
  int n = 2*l+1;
  for(int i=0;i<n*n;i++) U[i]=cd(0,0);
  U[l*n+l] = cd(1,0);
  for(int m=1;m<=l;m++){
    double sgn = (m&1)? -1.0 : 1.0;
    double is2 = 1.0/std::sqrt(2.0);
    U[(l+m)*n + (l+m)] = cd(sgn*is2,0);
    U[(l+m)*n + (l-m)] = cd(is2,0);
    U[(l-m)*n + (l+m)] = cd(0,-sgn*is2);
    U[(l-m)*n + (l-m)] = cd(0,is2);
  }
}

static void real_cg_h(int l1,int l2,int l3, double* out){
  int n1=2*l1+1,n2=2*l2+1,n3=2*l3+1;
  std::vector<cd> C(n1*n2*n3);
  for(int a=-l1;a<=l1;a++)for(int b=-l2;b<=l2;b++)for(int c=-l3;c<=l3;c++)
    C[(size_t)((a+l1)*n2+(b+l2))*n3+(c+l3)] = cd(cg_complex(l1,a,l2,b,l3,c),0);
  std::vector<cd> U1(n1*n1),U2(n2*n2),U3(n3*n3);
  real_U(l1,U1.data()); real_U(l2,U2.data()); real_U(l3,U3.data());
  std::vector<cd> T((size_t)n1*n2*n3, cd(0,0));
  for(int i=0;i<n1;i++)for(int j=0;j<n2;j++)for(int k=0;k<n3;k++){
    cd acc(0,0);
    for(int a=0;a<n1;a++){ cd u1=U1[i*n1+a]; if(u1==cd(0,0)) continue;
      for(int b=0;b<n2;b++){ cd u2=U2[j*n2+b]; if(u2==cd(0,0)) continue;
        for(int c=0;c<n3;c++){ cd u3=std::conj(U3[k*n3+c]); if(u3==cd(0,0)) continue;
          acc += u1*u2*u3*C[(size_t)(a*n2+b)*n3+c];
        } } }
    T[(size_t)(i*n2+j)*n3+k]=acc;
  }
  double sr=0, si=0;
  for(auto&z:T){ sr += std::fabs(z.real()); si += std::fabs(z.imag()); }
  int tot=n1*n2*n3;
  std::vector<double> R(tot);
  for(int i=0;i<tot;i++) R[i] = (sr>=si)? T[i].real() : T[i].imag();
  double nrm=0; for(double v:R) nrm += v*v; nrm = std::sqrt(nrm);
  for(int i=0;i<tot;i++) out[i] = R[i]/nrm;
}

struct HIrr{int m,l,p;};
static int map_id(int i){return i;}
static int map_gate(int i){return (i<16)? i : i-16;}

static void build_one(const std::vector<HIrr>& ir1, const std::vector<HIrr>& ir2,
                      const std::vector<HIrr>& ir3, int (*map1)(int), bool sort_out,
                      std::vector<uint32_t>& cg_pk, std::vector<float>& cg_c,
                      std::vector<uint32_t>& out_pk, std::vector<float>& out_c)
{
  int n1=(int)ir1.size(), n2=(int)ir2.size(), n3=(int)ir3.size();
  std::vector<int> s1(n1), s2(n2), s3(n3);
  { int o=0; for(int i=0;i<n1;i++){ s1[i]=o; o+=ir1[i].m*(2*ir1[i].l+1);} }
  { int o=0; for(int i=0;i<n2;i++){ s2[i]=o; o+=ir2[i].m*(2*ir2[i].l+1);} }
  { int o=0; for(int i=0;i<n3;i++){ s3[i]=o; o+=ir3[i].m*(2*ir3[i].l+1);} }
  struct Inst{int i1,i2,i3,w0;};
  std::vector<Inst> insts; int woff=0;
  for(int i1=0;i1<n1;i1++)for(int i2=0;i2<n2;i2++)for(int i3=0;i3<n3;i3++){
    const HIrr&A=ir1[i1];const HIrr&B=ir2[i2];const HIrr&C=ir3[i3];
    int dl = A.l-B.l; if(dl<0) dl=-dl;
    if(A.p*B.p==C.p && dl<=C.l && C.l<=A.l+B.l){
      insts.push_back({i1,i2,i3,woff}); woff += A.m*B.m*C.m;
    }
  }
  std::vector<int> fan(n3,0);
  for(auto&P:insts) fan[P.i3] += ir1[P.i1].m*ir2[P.i2].m;
  struct OE{int opos,widx,s;float coef;};
  std::vector<OE> outs;
  int sbase=0;
  for(auto&P:insts){
    const HIrr&A=ir1[P.i1];const HIrr&B=ir2[P.i2];const HIrr&C=ir3[P.i3];
    int d1=2*A.l+1,d2=2*B.l+1,d3=2*C.l+1;
    double cg[343];
    real_cg_h(A.l,B.l,C.l,cg);
    double alpha = std::sqrt((double)d3/(double)fan[P.i3]);
    for(int u=0;u<A.m;u++)for(int v=0;v<B.m;v++){
      for(int k=0;k<d3;k++)
        for(int i=0;i<d1;i++)for(int j=0;j<d2;j++){
          double c = cg[(i*d2+j)*d3+k];
          if(std::fabs(c)<1e-8) continue;
          int iabs = map1(s1[P.i1]+u*d1+i);
          int jabs = s2[P.i2]+v*d2+j;
          cg_pk.push_back((uint32_t)iabs | ((uint32_t)jabs<<8) | ((uint32_t)(sbase+k)<<16));
          cg_c.push_back((float)c);
        }
      for(int w=0;w<C.m;w++)for(int k=0;k<d3;k++){
        OE o; o.opos=s3[P.i3]+w*d3+k; o.widx=P.w0+(u*B.m+v)*C.m+w; o.s=sbase+k; o.coef=(float)alpha;
        outs.push_back(o);
      }
      sbase += d3;
    }
  }
  if(sort_out) std::stable_sort(outs.begin(), outs.end(),
      [](const OE&a,const OE&b){return a.opos<b.opos;});
  for(auto&o:outs){
    out_pk.push_back((uint32_t)o.opos | ((uint32_t)o.widx<<8) | ((uint32_t)o.s<<20));
    out_c.push_back(o.coef);
  }
}

static void make_chunks(const std::vector<uint32_t>& pk, int shift, uint32_t mask, int* bnd){
  int n=(int)pk.size();
  bnd[0]=0; bnd[8]=n;
  for(int c=1;c<8;c++){
    int p = (int)(((long long)n*c)/8);
    while(p>0 && p<n && ((pk[p]>>shift)&mask)==((pk[p-1]>>shift)&mask)) p++;
    bnd[c] = p>n? n : p;
  }
  for(int c=1;c<=8;c++) if(bnd[c]<bnd[c-1]) bnd[c]=bnd[c-1];
}

static void build_tables(TPTables& T){
  std::vector<HIrr> IR_SH   ={{1,0,1},{1,1,-1},{1,2,1},{1,3,-1}};
  std::vector<HIrr> GATE_IN ={{16,0,1},{16,0,-1},{8,0,1},{8,0,-1},{8,0,1},{8,0,-1},{16,1,-1},{16,1,1}};
  std::vector<HIrr> GATE_OUT={{16,0,1},{16,0,-1},{16,1,-1},{16,1,1}};
  std::vector<HIrr> IR_OUT  ={{1,0,1}};
  std::vector<uint32_t> cg1,o1,cg2,o2; std::vector<float> cg1c,o1c,cg2c,o2c;
  build_one(IR_SH,IR_SH,GATE_IN,map_id,true,cg1,cg1c,o1,o1c);
  build_one(GATE_OUT,IR_SH,IR_OUT,map_gate,false,cg2,cg2c,o2,o2c);
  memset(&T,0,sizeof(T));
  T.n_cg1=(int)cg1.size(); T.n_out1=(int)o1.size();
  T.n_cg2=(int)cg2.size(); T.n_out2=(int)o2.size();
  for(size_t i=0;i<cg1.size()&&i<1024;i++){ T.cg1_pk[i]=cg1[i]; T.cg1_c[i]=cg1c[i]; }
  for(size_t i=0;i<o1.size()&&i<768;i++){ T.out1_pk[i]=o1[i]; T.out1_c[i]=o1c[i]; }
  for(size_t i=0;i<cg2.size()&&i<192;i++){ T.cg2_pk[i]=cg2[i]; T.cg2_c[i]=cg2c[i]; }
  for(size_t i=0;i<o2.size()&&i<64;i++){ T.out2_pk[i]=o2[i]; T.out2_c[i]=o2c[i]; }
  make_chunks(cg1,16,0xFFFFu,T.cg1_bnd);
  make_chunks(o1,0,0xFFu,T.out1_bnd);
}

// ---------------- device helpers ----------------
__device__ __forceinline__ unsigned short f2h(float f){
  _Float16 h = (_Float16)f;
  unsigned short u; __builtin_memcpy(&u, &h, 2); return u;
}
__device__ __forceinline__ float h2f(unsigned short u){
  _Float16 h; __builtin_memcpy(&h, &u, 2); return (float)h;
}

__device__ __forceinline__ void sph16(float x,float y,float z,float* sh){
  float x2=x*x, y2=y*y, z2=z*z;
  const float SQ3=1.7320508075688772f, SQ5=2.23606797749979f, SQ7=2.6457513110645907f;
  const float SQ15=3.872983346207417f, SQ42=6.48074069840786f, SQ70=8.366600265340756f, SQ105=10.246950765959598f;
  sh[0]=1.f;
  sh[1]=SQ3*y;  sh[2]=SQ3*z;  sh[3]=SQ3*x;
  sh[4]=SQ15*x*y; sh[5]=SQ15*y*z; sh[6]=0.5f*SQ5*(3.f*z2-1.f); sh[7]=SQ15*x*z; sh[8]=0.5f*SQ15*(x2-y2);
  sh[9]=0.25f*SQ70*y*(3.f*x2-y2); sh[10]=SQ105*x*y*z; sh[11]=0.25f*SQ42*y*(5.f*z2-1.f);
  sh[12]=0.5f*SQ7*z*(5.f*z2-3.f); sh[13]=0.25f*SQ42*x*(5.f*z2-1.f);
  sh[14]=0.5f*SQ105*z*(x2-y2);    sh[15]=0.25f*SQ70*x*(x2-3.f*y2);
}

__device__ __forceinline__ void radial10(float d, float* emb){
  const float step = 0.2909090909090909f;
  #pragma unroll
  for(int b=0;b<10;b++){
    float c = step*(float)(b+1);
    float u = (d-c)/step;
    float u2 = u*u;
    float f = 0.f;
    if(u2<1.f) f = 1.14136f*__expf(-u2/fmaxf(1.f-u2,1e-6f));
    emb[b] = f*3.1622776601683795f;
  }
}

// ---------------- kernels ----------------
__global__ void k_zero(float* a, size_t na, float* b, size_t nb, float* c, size_t nc,
                       int* d, size_t nd){
  size_t total = na+nb+nc+nd;
  for(size_t i = (size_t)blockIdx.x*blockDim.x+threadIdx.x; i<total; i += (size_t)gridDim.x*blockDim.x){
    if(i<na) a[i]=0.f;
    else if(i<na+nb) b[i-na]=0.f;
    else if(i<na+nb+nc) c[i-na-nb]=0.f;
    else d[i-na-nb-nc]=0;
  }
}

__global__ void k_deg(const int* __restrict__ edst, int* __restrict__ deg, int E){
  int e = blockIdx.x*256 + threadIdx.x;
  if(e<E) atomicAdd(&deg[edst[e]], 1);
}

// single-block exclusive scan over deg[N] -> row[N+1]; zeroes cursor[N]
__global__ __launch_bounds__(1024) void k_scan(const int* __restrict__ deg, int* __restrict__ row,
                                               int* __restrict__ cursor, int N){
  __shared__ int buf[2][1024];
  __shared__ int carry;
  int t = threadIdx.x;
  if(t==0) carry=0;
  __syncthreads();
  for(int base=0; base<N; base+=1024){
    int i = base+t;
    int v = (i<N)? deg[i] : 0;
    int cur=0;
    buf[0][t]=v; __syncthreads();
    for(int off=1; off<1024; off<<=1){
      int val = buf[cur][t];
      if(t>=off) val += buf[cur][t-off];
      buf[cur^1][t]=val; __syncthreads();
      cur^=1;
    }
    if(i<N) row[i] = carry + buf[cur][t] - v;
    int tot = buf[cur][1023];
    __syncthreads();
    if(t==0) carry += tot;
    __syncthreads();
  }
  if(t==0) row[N]=carry;
  for(int i=t;i<N;i+=1024) cursor[i]=0;
}

__global__ void k_fill(const int* __restrict__ edst, const int* __restrict__ row,
                       int* __restrict__ cursor, int* __restrict__ perm, int E){
  int e = blockIdx.x*256 + threadIdx.x;
  if(e<E){
    int d = edst[e];
    int p = atomicAdd(&cursor[d], 1);
    perm[row[d]+p] = e;
  }
}

// Pre-pack W2 matrices into fp16 MFMA B-fragments.
// Slot mapping (shared with A-side reads; only A/B consistency matters):
//   k = ks*32 + g*4 + (s&3) + ((s>>2)<<4),  g = lane>>4, c = ct*16 + (lane&15)
__global__ void k_prep(const float* __restrict__ W2a, const float* __restrict__ W2b,
                       unsigned short* __restrict__ B1, unsigned short* __restrict__ B2){
  int i = blockIdx.x*256 + threadIdx.x;
  if(i < 17*8*64*8){
    int s = i&7, lane = (i>>3)&63, ks = (i>>9)&7, ct = i>>12;
    int g = lane>>4;
    int k = ks*32 + g*4 + (s&3) + ((s>>2)<<4);
    int c = ct*16 + (lane&15);
    B1[i] = f2h(W2a[k*272+c]);
  } else if(i < 17*8*64*8 + 2*8*64*8){
    int j = i - 17*8*64*8;
    int s = j&7, lane = (j>>3)&63, ks = (j>>9)&7, ct = j>>12;
    int g = lane>>4;
    int k = ks*32 + g*4 + (s&3) + ((s>>2)<<4);
    int c = ct*16 + (lane&15);
    B2[j] = f2h(W2b[k*32+c]);
  }
}

// sorted edges: per-dst-run reduced scatter of sh into x
__global__ __launch_bounds__(256) void k_edge_pre(
    const float* __restrict__ pos, const int* __restrict__ esrc, const int* __restrict__ edst,
    const int* __restrict__ perm, float* __restrict__ x, int E){
  __shared__ float shs[256*17];
  __shared__ int dsts[256];
  int t = threadIdx.x;
  int idx = blockIdx.x*256 + t;
  int d = -1;
  if(idx<E){
    int e = perm[idx];
    int s = esrc[e]; d = edst[e];
    float ex=pos[3*d]-pos[3*s], ey=pos[3*d+1]-pos[3*s+1], ez=pos[3*d+2]-pos[3*s+2];
    float dd = sqrtf(ex*ex+ey*ey+ez*ez+1e-12f);
    sph16(ex/dd, ey/dd, ez/dd, &shs[t*17]);
  }
  dsts[t] = d;
  __syncthreads();
  bool leader = (d>=0) && (t==0 || dsts[t-1]!=d);
  if(leader){
    int len=1;
    while(t+len<256 && dsts[t+len]==d) len++;
    #pragma unroll
    for(int j=0;j<16;j++){
      float a=0.f;
      for(int k=0;k<len;k++) a += shs[(t+k)*17+j];
      atomicAdd(&x[(size_t)d*16+j], a);
    }
  }
}

// LDS layout (floats) for k_fc1_tp1:
//   sh_t @0 [32][17](544) | x1_t @544 (544) | emb_t @1088 (352)
//   Hbf @1440: [32][284] ushort = 4544 f  (S_l aliases @1440 [32][40])
//   Wt_h @5984: [32][276] ushort = 4416 f
//   ef_t @10400: [32][161] = 5152 f
#define F1_H    1440
#define F1_WT   5984
#define F1_EF   10400
#define F1_TOT  15552
#define HSTRIDE 284
#define WSTRIDE 276

__global__ __launch_bounds__(256) void k_fc1_tp1(
    const float* __restrict__ pos, const int* __restrict__ esrc, const int* __restrict__ edst,
    const int* __restrict__ perm,
    const float* __restrict__ W1, const unsigned short* __restrict__ B1,
    const float* __restrict__ xnode, float* __restrict__ ef1,
    const TPTables* __restrict__ T, int E, float inv_nn)
{
  __shared__ __align__(16) float sm[F1_TOT];
  __shared__ int src_t[TILE], dst_t[TILE];
  float* sh_t  = sm;
  float* x1_t  = sm + 544;
  float* emb_t = sm + 1088;
  unsigned short* Hbf  = (unsigned short*)(sm + F1_H);
  float* S_l   = sm + F1_H;
  unsigned short* Wt_h = (unsigned short*)(sm + F1_WT);
  float* ef_t  = sm + F1_EF;
  int t = threadIdx.x;
  int e0 = blockIdx.x*TILE;
  int nE = min(TILE, E-e0);

  if(t<TILE){
    float embr[10];
    if(t<nE){
      int e = perm[e0+t];
      int s=esrc[e], d=edst[e];
      src_t[t]=s; dst_t[t]=d;
      float ex=pos[3*d]-pos[3*s], ey=pos[3*d+1]-pos[3*s+1], ez=pos[3*d+2]-pos[3*s+2];
      float dd=sqrtf(ex*ex+ey*ey+ez*ez+1e-12f);
      sph16(ex/dd,ey/dd,ez/dd, &sh_t[t*17]);
      radial10(dd, embr);
    } else {
      src_t[t]=0; dst_t[t]=-1;
      #pragma unroll
      for(int j=0;j<16;j++) sh_t[t*17+j]=0.f;
      #pragma unroll
      for(int b=0;b<10;b++) embr[b]=0.f;
    }
    #pragma unroll
    for(int b=0;b<10;b++) emb_t[t*11+b]=embr[b];
  } else {
    for(int i=t-32;i<TILE*161;i+=224) ef_t[i]=0.f;
  }
  __syncthreads();
  for(int i=t;i<TILE*16;i+=256){ int e=i>>4, j=i&15; x1_t[e*17+j] = xnode[(size_t)src_t[e]*16+j]*inv_nn; }
  // H = relu(emb @ W1/sqrt(10)) * sqrt(2) -> f16 Hbf[e][k]
  {
    int e = t&31, kg = t>>5;
    float er[10];
    #pragma unroll
    for(int b=0;b<10;b++) er[b]=emb_t[e*11+b];
    for(int j=0;j<32;j++){
      int k = kg*32+j;
      float a=0.f;
      #pragma unroll
      for(int b=0;b<10;b++) a += er[b]*W1[b*256+k];
      Hbf[e*HSTRIDE + k] = f2h(fmaxf(a*0.31622776601683794f, 0.f)*1.4142135623730951f);
    }
  }
  __syncthreads();
  // W = (H @ W2)/16 via fp16 MFMA 16x16x32; Wt stored f16.
  {
    int wv = t>>6, lane = t&63, g = lane>>4, lr = lane&15;
    for(int ct = wv; ct < 17; ct += 4){
      f32x4 acc0 = {0.f,0.f,0.f,0.f}, acc1 = {0.f,0.f,0.f,0.f};
      for(int ks=0; ks<8; ks++){
        f16x8 b = *(const f16x8*)(B1 + ((size_t)(ct*8+ks)*64 + lane)*8);
        union { f16x8 v; uint32_t w[4]; } a0, a1;
        const uint32_t* p0 = (const uint32_t*)(Hbf + lr*HSTRIDE + ks*32 + g*4);
        const uint32_t* p1 = (const uint32_t*)(Hbf + (16+lr)*HSTRIDE + ks*32 + g*4);
        a0.w[0]=p0[0]; a0.w[1]=p0[1]; a0.w[2]=p0[8]; a0.w[3]=p0[9];
        a1.w[0]=p1[0]; a1.w[1]=p1[1]; a1.w[2]=p1[8]; a1.w[3]=p1[9];
        acc0 = __builtin_amdgcn_mfma_f32_16x16x32_f16(a0.v, b, acc0, 0,0,0);
        acc1 = __builtin_amdgcn_mfma_f32_16x16x32_f16(a1.v, b, acc1, 0,0,0);
      }
      #pragma unroll
      for(int r=0;r<4;r++){
        Wt_h[(g*4+r)*WSTRIDE + ct*16+lr]    = f2h(acc0[r]*0.0625f);
        Wt_h[(16+g*4+r)*WSTRIDE + ct*16+lr] = f2h(acc1[r]*0.0625f);
      }
    }
  }
  __syncthreads();
  // TP1 cg phase: 8 threads per edge (S_l aliases dead Hbf)
  int e = t>>3, g = t&7;
  {
    int beg=T->cg1_bnd[g], end=T->cg1_bnd[g+1];
    float acc=0.f; int cur=-1;
    for(int idx=beg; idx<end; idx++){
      uint32_t pk = T->cg1_pk[idx]; float c = T->cg1_c[idx];
      int i = pk&0xff, j=(pk>>8)&0xff, s=(int)(pk>>16);
      if(s!=cur){ if(cur>=0) S_l[e*40+cur]=acc; cur=s; acc=0.f; }
      acc += c * x1_t[e*17+i] * sh_t[e*17+j];
    }
    if(cur>=0) S_l[e*40+cur]=acc;
  }
  __syncthreads();
  // TP1 out phase: plain LDS stores into ef_t (exclusive (e,opos) ownership)
  if(e<nE){
    int beg=T->out1_bnd[g], end=T->out1_bnd[g+1];
    float acc=0.f; int cur=-1;
    for(int idx=beg; idx<end; idx++){
      uint32_t pk=T->out1_pk[idx]; float cf=T->out1_c[idx];
      int opos=(int)(pk&0xff), widx=(int)((pk>>8)&0xfff), s=(int)(pk>>20);
      if(opos!=cur){ if(cur>=0) ef_t[e*161+cur]=acc; cur=opos; acc=0.f; }
      acc += cf * h2f(Wt_h[e*WSTRIDE+widx]) * S_l[e*40+s];
    }
    if(cur>=0) ef_t[e*161+cur]=acc;
  }
  __syncthreads();
  // segmented flush: one atomic per (dst-run, opos)
  if(t<160){
    float acc=0.f;
    for(int e2=0;e2<TILE;e2++){
      acc += ef_t[e2*161+t];
      int d = dst_t[e2];
      bool bnd = (e2==TILE-1) || (dst_t[e2+1]!=d);
      if(bnd){
        if(d>=0 && acc!=0.f) atomicAdd(&ef1[(size_t)d*160+t], acc);
        acc=0.f;
      }
    }
  }
}

__global__ void k_gate(const float* __restrict__ ef1, float* __restrict__ xg, int N, float inv_nn){
  int n = blockIdx.x*256+threadIdx.x;
  if(n>=N) return;
  const float* v = ef1 + (size_t)n*160;
  float* o = xg + (size_t)n*128;
  float g[32];
  #pragma unroll
  for(int i=0;i<16;i++) o[i] = fmaxf(v[i]*inv_nn, 0.f);
  #pragma unroll
  for(int i=0;i<16;i++) o[16+i] = tanhf(v[16+i]*inv_nn);
  #pragma unroll
  for(int i=0;i<8;i++) g[i]    = fmaxf(v[32+i]*inv_nn,0.f);
  #pragma unroll
  for(int i=0;i<8;i++) g[8+i]  = tanhf(v[40+i]*inv_nn);
  #pragma unroll
  for(int i=0;i<8;i++) g[16+i] = fmaxf(v[48+i]*inv_nn,0.f);
  #pragma unroll
  for(int i=0;i<8;i++) g[24+i] = tanhf(v[56+i]*inv_nn);
  #pragma unroll
  for(int u=0;u<32;u++){
    float gu = g[u];
    #pragma unroll
    for(int k=0;k<3;k++) o[32+u*3+k] = v[64+u*3+k]*inv_nn*gu;
  }
}

// LDS layout (floats) for k_fc2_tp2:
//   sh_t @0 [32][17](544) | xg_t @544 [32][65](2080) | emb_t @2624 (352)
//   Wt2 @2976 [32][36](1152) | Hbf2 @4128 [32][284]us (4544 f, S_l alias [32][33])
//   bins @8672 (64)
#define F2_SH   0
#define F2_XG   544
#define F2_EMB  2624
#define F2_WT   2976
#define F2_H    4128
#define F2_BINS 8672
#define F2_TOT  8736

__global__ __launch_bounds__(256) void k_fc2_tp2(
    const float* __restrict__ pos, const int* __restrict__ esrc, const int* __restrict__ edst,
    const int* __restrict__ batch,
    const float* __restrict__ W1, const unsigned short* __restrict__ B2,
    const float* __restrict__ xg, float* __restrict__ out,
    const TPTables* __restrict__ T, int E, float out_scale, int G)
{
  __shared__ __align__(16) float sm[F2_TOT];
  __shared__ int src_t[TILE], dst_t[TILE], g_t[TILE];
  float* sh_t  = sm + F2_SH;
  float* xg_t  = sm + F2_XG;
  float* emb_t = sm + F2_EMB;
  float* Wt    = sm + F2_WT;
  unsigned short* Hbf = (unsigned short*)(sm + F2_H);
  float* S_l   = sm + F2_H;
  float* bins  = sm + F2_BINS;
  int t = threadIdx.x;
  int e0 = blockIdx.x*TILE;
  int nE = min(TILE, E-e0);

  if(t<TILE){
    float embr[10];
    if(t<nE){
      int s=esrc[e0+t], d=edst[e0+t];
      src_t[t]=s; dst_t[t]=d; g_t[t]=batch[d];
      float ex=pos[3*d]-pos[3*s], ey=pos[3*d+1]-pos[3*s+1], ez=pos[3*d+2]-pos[3*s+2];
      float dd=sqrtf(ex*ex+ey*ey+ez*ez+1e-12f);
      sph16(ex/dd,ey/dd,ez/dd, &sh_t[t*17]);
      radial10(dd, embr);
    } else {
      src_t[t]=0; dst_t[t]=-1; g_t[t]=0;
      #pragma unroll
      for(int j=0;j<16;j++) sh_t[t*17+j]=0.f;
      #pragma unroll
      for(int b=0;b<10;b++) embr[b]=0.f;
    }
    #pragma unroll
    for(int b=0;b<10;b++) emb_t[t*11+b]=embr[b];
  }
  __syncthreads();
  for(int i=t;i<TILE*64;i+=256){
    int e=i>>6, j=i&63;
    xg_t[e*65+j] = xg[(size_t)src_t[e]*128 + (j<16? j : j+16)];
  }
  {
    int e = t&31, kg = t>>5;
    float er[10];
    #pragma unroll
    for(int b=0;b<10;b++) er[b]=emb_t[e*11+b];
    for(int j=0;j<32;j++){
      int k = kg*32+j;
      float a=0.f;
      #pragma unroll
      for(int b=0;b<10;b++) a += er[b]*W1[b*256+k];
      Hbf[e*HSTRIDE + k] = f2h(fmaxf(a*0.31622776601683794f, 0.f)*1.4142135623730951f);
    }
  }
  __syncthreads();
  {
    int wv = t>>6, lane = t&63, g = lane>>4, lr = lane&15;
    if(wv<2){
      int ct = wv;
      f32x4 acc0 = {0.f,0.f,0.f,0.f}, acc1 = {0.f,0.f,0.f,0.f};
      for(int ks=0; ks<8; ks++){
        f16x8 b = *(const f16x8*)(B2 + ((size_t)(ct*8+ks)*64 + lane)*8);
        union { f16x8 v; uint32_t w[4]; } a0, a1;
        const uint32_t* p0 = (const uint32_t*)(Hbf + lr*HSTRIDE + ks*32 + g*4);
        const uint32_t* p1 = (const uint32_t*)(Hbf + (16+lr)*HSTRIDE + ks*32 + g*4);
        a0.w[0]=p0[0]; a0.w[1]=p0[1]; a0.w[2]=p0[8]; a0.w[3]=p0[9];
        a1.w[0]=p1[0]; a1.w[1]=p1[1]; a1.w[2]=p1[8]; a1.w[3]=p1[9];
        acc0 = __builtin_amdgcn_mfma_f32_16x16x32_f16(a0.v, b, acc0, 0,0,0);
        acc1 = __builtin_amdgcn_mfma_f32_16x16x32_f16(a1.v, b, acc1, 0,0,0);
      }
      #pragma unroll
      for(int r=0;r<4;r++){
        Wt[(g*4+r)*36 + ct*16+lr]    = acc0[r]*0.0625f;
        Wt[(16+g*4+r)*36 + ct*16+lr] = acc1[r]*0.0625f;
      }
    }
  }
  __syncthreads();
  if(t<64) bins[t]=0.f;
  __syncthreads();
  if(t<nE){
    int e=t;
    {
      float acc=0.f; int cur=-1;
      int n=T->n_cg2;
      for(int idx=0;idx<n;idx++){
        uint32_t pk=T->cg2_pk[idx]; float c=T->cg2_c[idx];
        int i=pk&0xff, j=(pk>>8)&0xff, s=(int)(pk>>16);
        if(s!=cur){ if(cur>=0) S_l[e*33+cur]=acc; cur=s; acc=0.f; }
        acc += c*xg_t[e*65+i]*sh_t[e*17+j];
      }
      if(cur>=0) S_l[e*33+cur]=acc;
    }
    float v=0.f;
    int n=T->n_out2;
    for(int idx=0;idx<n;idx++){
      uint32_t pk=T->out2_pk[idx]; float cf=T->out2_c[idx];
      int widx=(int)((pk>>8)&0xfff), s=(int)(pk>>20);
      v += cf * Wt[e*36+widx] * S_l[e*33+s];
    }
    atomicAdd(&bins[g_t[e]], v);
  }
  __syncthreads();
  if(t<G) atomicAdd(&out[t], bins[t]*out_scale);
}

// ---------------- launch ----------------
extern "C" void kernel_launch(void* const* d_in, const int* in_sizes, int n_in,
                              void* d_out, int out_size, void* d_ws, size_t ws_size,
                              hipStream_t stream) {
  const float* pos  = (const float*)d_in[0];
  const float* w11  = (const float*)d_in[1];
  const float* w12  = (const float*)d_in[2];
  const float* w21  = (const float*)d_in[3];
  const float* w22  = (const float*)d_in[4];
  const int*   esrc = (const int*)d_in[5];
  const int*   edst = (const int*)d_in[6];
  const int*   batch= (const int*)d_in[7];
  int E = in_sizes[5];
  int N = in_sizes[0]/3;
  int G = out_size;

  double nn = std::sqrt((double)E/(double)N);
  float inv_nn    = (float)(1.0/nn);
  float out_scale = (float)(1.0/(nn*std::sqrt((double)N)));

  float* ws = (float*)d_ws;
  float* x   = ws;
  float* ef1 = x   + (size_t)N*16;
  float* xg  = ef1 + (size_t)N*160;
  TPTables* dT = (TPTables*)(xg + (size_t)N*128);
  unsigned short* B1 = (unsigned short*)(((char*)dT) + ((sizeof(TPTables)+255)&~(size_t)255));
  unsigned short* B2 = B1 + 17*8*64*8;
  int* deg    = (int*)(B2 + 2*8*64*8);
  int* row    = deg + N;
  int* cursor = row + (N+1);
  int* perm   = cursor + N;

  static TPTables hT;
  build_tables(hT);
  hipMemcpyAsync(dT, &hT, sizeof(TPTables), hipMemcpyHostToDevice, stream);

  size_t nz = (size_t)N*16 + (size_t)N*160 + G + N;
  int zgrid = (int)((nz+255)/256); if(zgrid>2048) zgrid=2048;
  k_zero<<<zgrid,256,0,stream>>>(x, (size_t)N*16, ef1, (size_t)N*160, (float*)d_out, (size_t)G, deg, (size_t)N);
  k_deg<<<(E+255)/256,256,0,stream>>>(edst, deg, E);
  k_scan<<<1,1024,0,stream>>>(deg, row, cursor, N);
  k_fill<<<(E+255)/256,256,0,stream>>>(edst, row, cursor, perm, E);
  k_prep<<<(17*8*64*8 + 2*8*64*8 + 255)/256,256,0,stream>>>(w12, w22, B1, B2);
  k_edge_pre<<<(E+255)/256,256,0,stream>>>(pos, esrc, edst, perm, x, E);
  k_fc1_tp1<<<(E+TILE-1)/TILE,256,0,stream>>>(pos, esrc, edst, perm, w11, B1, x, ef1, dT, E, inv_nn);
  k_gate<<<(N+255)/256,256,0,stream>>>(ef1, xg, N, inv_nn);
  k_fc2_tp2<<<(E+TILE-1)/TILE,256,0,stream>>>(pos, esrc, edst, batch, w21, B2, xg,
                                              (float*)d_out, dT, E, out_scale, G);
}

// Round 4
// 1444.555 us; speedup vs baseline: 4.3123x; 1.2307x over previous
//
#include <hip/hip_runtime.h>
#include <cmath>
#include <cstdint>
#include <cstring>
#include <cstdlib>
#include <vector>
#include <algorithm>
#include <complex>

#define TILE 32
#define HSTRIDE 268   // ushort stride of H rows in LDS
#define WSTRIDE 276   // ushort stride of W rows in LDS

typedef __attribute__((ext_vector_type(8))) _Float16 f16x8;
typedef __attribute__((ext_vector_type(4))) float f32x4;

// ------------------------------------------------------------------
// Sparse tensor-product tables (host-built, deterministic, one async H2D).
// entries interleaved (pk, f32bits) -> device loads uint2.
// ------------------------------------------------------------------
struct TPTables {
  int cg1_bnd[17];
  int out1_bnd[2][17];   // [half][chunk]
  int cg2_bnd[17];
  int n_cg1, n_out1, n_cg2, n_out2;
  uint32_t cg1[2048];
  uint32_t out1[1536];
  uint32_t cg2[384];
  uint32_t out2[128];
};

static double factd(int n){ double r=1; for(int i=2;i<=n;i++) r*=(double)i; return r; }

static double cg_complex(int j1,int m1,int j2,int m2,int j3,int m3){
  if(m1+m2!=m3) return 0.0;
  double pref = std::sqrt((2*j3+1)*factd(j3+j1-j2)*factd(j3-j1+j2)*factd(j1+j2-j3)/factd(j1+j2+j3+1));
  pref *= std::sqrt(factd(j3+m3)*factd(j3-m3)*factd(j1-m1)*factd(j1+m1)*factd(j2-m2)*factd(j2+m2));
  double s=0.0;
  for(int k=0;k<=j1+j2-j3;k++){
    int dd[6] = {k, j1+j2-j3-k, j1-m1-k, j2+m2-k, j3-j2+m1+k, j3-j1-m2+k};
    bool ok=true; double prod=1.0;
    for(int t=0;t<6;t++){ if(dd[t]<0){ok=false;break;} prod*=factd(dd[t]); }
    if(!ok) continue;
    s += ((k&1)?-1.0:1.0)/prod;
  }
  return pref*s;
}

typedef std::complex<double> cd;
static void real_U(int l, cd* U){
  int n = 2*l+1;
  for(int i=0;i<n*n;i++) U[i]=cd(0,0);
  U[l*n+l] = cd(1,0);
  for(int m=1;m<=l;m++){
    double sgn = (m&1)? -1.0 : 1.0;
    double is2 = 1.0/std::sqrt(2.0);
    U[(l+m)*n + (l+m)] = cd(sgn*is2,0);
    U[(l+m)*n + (l-m)] = cd(is2,0);
    U[(l-m)*n + (l+m)] = cd(0,-sgn*is2);
    U[(l-m)*n + (l-m)] = cd(0,is2);
  }
}

static void real_cg_h(int l1,int l2,int l3, double* out){
  int n1=2*l1+1,n2=2*l2+1,n3=2*l3+1;
  std::vector<cd> C(n1*n2*n3);
  for(int a=-l1;a<=l1;a++)for(int b=-l2;b<=l2;b++)for(int c=-l3;c<=l3;c++)
    C[(size_t)((a+l1)*n2+(b+l2))*n3+(c+l3)] = cd(cg_complex(l1,a,l2,b,l3,c),0);
  std::vector<cd> U1(n1*n1),U2(n2*n2),U3(n3*n3);
  real_U(l1,U1.data()); real_U(l2,U2.data()); real_U(l3,U3.data());
  std::vector<cd> T((size_t)n1*n2*n3, cd(0,0));
  for(int i=0;i<n1;i++)for(int j=0;j<n2;j++)for(int k=0;k<n3;k++){
    cd acc(0,0);
    for(int a=0;a<n1;a++){ cd u1=U1[i*n1+a]; if(u1==cd(0,0)) continue;
      for(int b=0;b<n2;b++){ cd u2=U2[j*n2+b]; if(u2==cd(0,0)) continue;
        for(int c=0;c<n3;c++){ cd u3=std::conj(U3[k*n3+c]); if(u3==cd(0,0)) continue;
          acc += u1*u2*u3*C[(size_t)(a*n2+b)*n3+c];
        } } }
    T[(size_t)(i*n2+j)*n3+k]=acc;
  }
  double sr=0, si=0;
  for(auto&z:T){ sr += std::fabs(z.real()); si += std::fabs(z.imag()); }
  int tot=n1*n2*n3;
  std::vector<double> R(tot);
  for(int i=0;i<tot;i++) R[i] = (sr>=si)? T[i].real() : T[i].imag();
  double nrm=0; for(double v:R) nrm += v*v; nrm = std::sqrt(nrm);
  for(int i=0;i<tot;i++) out[i] = R[i]/nrm;
}

struct HIrr{int m,l,p;};
static int map_id(int i){return i;}
static int map_gate(int i){return (i<16)? i : i-16;}

static void build_one(const std::vector<HIrr>& ir1, const std::vector<HIrr>& ir2,
                      const std::vector<HIrr>& ir3, int (*map1)(int), bool sort_out,
                      std::vector<uint32_t>& cg_pk, std::vector<float>& cg_c,
                      std::vector<uint32_t>& out_pk, std::vector<float>& out_c)
{
  int n1=(int)ir1.size(), n2=(int)ir2.size(), n3=(int)ir3.size();
  std::vector<int> s1(n1), s2(n2), s3(n3);
  { int o=0; for(int i=0;i<n1;i++){ s1[i]=o; o+=ir1[i].m*(2*ir1[i].l+1);} }
  { int o=0; for(int i=0;i<n2;i++){ s2[i]=o; o+=ir2[i].m*(2*ir2[i].l+1);} }
  { int o=0; for(int i=0;i<n3;i++){ s3[i]=o; o+=ir3[i].m*(2*ir3[i].l+1);} }
  struct Inst{int i1,i2,i3,w0;};
  std::vector<Inst> insts; int woff=0;
  for(int i1=0;i1<n1;i1++)for(int i2=0;i2<n2;i2++)for(int i3=0;i3<n3;i3++){
    const HIrr&A=ir1[i1];const HIrr&B=ir2[i2];const HIrr&C=ir3[i3];
    int dl = A.l-B.l; if(dl<0) dl=-dl;
    if(A.p*B.p==C.p && dl<=C.l && C.l<=A.l+B.l){
      insts.push_back({i1,i2,i3,woff}); woff += A.m*B.m*C.m;
    }
  }
  std::vector<int> fan(n3,0);
  for(auto&P:insts) fan[P.i3] += ir1[P.i1].m*ir2[P.i2].m;
  struct OE{int opos,widx,s;float coef;};
  std::vector<OE> outs;
  int sbase=0;
  for(auto&P:insts){
    const HIrr&A=ir1[P.i1];const HIrr&B=ir2[P.i2];const HIrr&C=ir3[P.i3];
    int d1=2*A.l+1,d2=2*B.l+1,d3=2*C.l+1;
    double cg[343];
    real_cg_h(A.l,B.l,C.l,cg);
    double alpha = std::sqrt((double)d3/(double)fan[P.i3]);
    for(int u=0;u<A.m;u++)for(int v=0;v<B.m;v++){
      for(int k=0;k<d3;k++)
        for(int i=0;i<d1;i++)for(int j=0;j<d2;j++){
          double c = cg[(i*d2+j)*d3+k];
          if(std::fabs(c)<1e-8) continue;
          int iabs = map1(s1[P.i1]+u*d1+i);
          int jabs = s2[P.i2]+v*d2+j;
          cg_pk.push_back((uint32_t)iabs | ((uint32_t)jabs<<8) | ((uint32_t)(sbase+k)<<16));
          cg_c.push_back((float)c);
        }
      for(int w=0;w<C.m;w++)for(int k=0;k<d3;k++){
        OE o; o.opos=s3[P.i3]+w*d3+k; o.widx=P.w0+(u*B.m+v)*C.m+w; o.s=sbase+k; o.coef=(float)alpha;
        outs.push_back(o);
      }
      sbase += d3;
    }
  }
  if(sort_out) std::stable_sort(outs.begin(), outs.end(),
      [](const OE&a,const OE&b){return a.opos<b.opos;});
  for(auto&o:outs){
    out_pk.push_back((uint32_t)o.opos | ((uint32_t)o.widx<<8) | ((uint32_t)o.s<<20));
    out_c.push_back(o.coef);
  }
}

static void make_chunks_r(const std::vector<uint32_t>& pk, int lo, int hi,
                          int shift, uint32_t mask, int nc, int* bnd){
  int n = hi-lo;
  bnd[0]=lo; bnd[nc]=hi;
  for(int c=1;c<nc;c++){
    int p = lo + (int)(((long long)n*c)/nc);
    while(p>lo && p<hi && ((pk[p]>>shift)&mask)==((pk[p-1]>>shift)&mask)) p++;
    bnd[c] = p>hi? hi : p;
  }
  for(int c=1;c<=nc;c++) if(bnd[c]<bnd[c-1]) bnd[c]=bnd[c-1];
}

static void build_tables(TPTables& T){
  std::vector<HIrr> IR_SH   ={{1,0,1},{1,1,-1},{1,2,1},{1,3,-1}};
  std::vector<HIrr> GATE_IN ={{16,0,1},{16,0,-1},{8,0,1},{8,0,-1},{8,0,1},{8,0,-1},{16,1,-1},{16,1,1}};
  std::vector<HIrr> GATE_OUT={{16,0,1},{16,0,-1},{16,1,-1},{16,1,1}};
  std::vector<HIrr> IR_OUT  ={{1,0,1}};
  std::vector<uint32_t> cg1,o1,cg2,o2; std::vector<float> cg1c,o1c,cg2c,o2c;
  build_one(IR_SH,IR_SH,GATE_IN,map_id,true,cg1,cg1c,o1,o1c);
  build_one(GATE_OUT,IR_SH,IR_OUT,map_gate,false,cg2,cg2c,o2,o2c);
  memset(&T,0,sizeof(T));
  T.n_cg1=(int)cg1.size(); T.n_out1=(int)o1.size();
  T.n_cg2=(int)cg2.size(); T.n_out2=(int)o2.size();
  for(size_t i=0;i<cg1.size()&&i<1024;i++){ T.cg1[2*i]=cg1[i]; T.cg1[2*i+1]=*(uint32_t*)&cg1c[i]; }
  for(size_t i=0;i<o1.size()&&i<768;i++){ T.out1[2*i]=o1[i]; T.out1[2*i+1]=*(uint32_t*)&o1c[i]; }
  for(size_t i=0;i<cg2.size()&&i<192;i++){ T.cg2[2*i]=cg2[i]; T.cg2[2*i+1]=*(uint32_t*)&cg2c[i]; }
  for(size_t i=0;i<o2.size()&&i<64;i++){ T.out2[2*i]=o2[i]; T.out2[2*i+1]=*(uint32_t*)&o2c[i]; }
  make_chunks_r(cg1, 0, (int)cg1.size(), 16, 0xFFFFu, 16, T.cg1_bnd);
  // split out1 by opos<80 / >=80, chunk each half by opos
  int h1 = 0;
  while(h1 < (int)o1.size() && (o1[h1]&0xFF) < 80) h1++;
  make_chunks_r(o1, 0, h1, 0, 0xFFu, 16, T.out1_bnd[0]);
  make_chunks_r(o1, h1, (int)o1.size(), 0, 0xFFu, 16, T.out1_bnd[1]);
  make_chunks_r(cg2, 0, (int)cg2.size(), 16, 0xFFFFu, 16, T.cg2_bnd);
}

// ---------------- device helpers ----------------
__device__ __forceinline__ unsigned short f2h(float f){
  _Float16 h = (_Float16)f;
  unsigned short u; __builtin_memcpy(&u, &h, 2); return u;
}
__device__ __forceinline__ float h2f(unsigned short u){
  _Float16 h; __builtin_memcpy(&h, &u, 2); return (float)h;
}

__device__ __forceinline__ void sph16(float x,float y,float z,float* sh){
  float x2=x*x, y2=y*y, z2=z*z;
  const float SQ3=1.7320508075688772f, SQ5=2.23606797749979f, SQ7=2.6457513110645907f;
  const float SQ15=3.872983346207417f, SQ42=6.48074069840786f, SQ70=8.366600265340756f, SQ105=10.246950765959598f;
  sh[0]=1.f;
  sh[1]=SQ3*y;  sh[2]=SQ3*z;  sh[3]=SQ3*x;
  sh[4]=SQ15*x*y; sh[5]=SQ15*y*z; sh[6]=0.5f*SQ5*(3.f*z2-1.f); sh[7]=SQ15*x*z; sh[8]=0.5f*SQ15*(x2-y2);
  sh[9]=0.25f*SQ70*y*(3.f*x2-y2); sh[10]=SQ105*x*y*z; sh[11]=0.25f*SQ42*y*(5.f*z2-1.f);
  sh[12]=0.5f*SQ7*z*(5.f*z2-3.f); sh[13]=0.25f*SQ42*x*(5.f*z2-1.f);
  sh[14]=0.5f*SQ105*z*(x2-y2);    sh[15]=0.25f*SQ70*x*(x2-3.f*y2);
}

__device__ __forceinline__ void radial10(float d, float* emb){
  const float step = 0.2909090909090909f;
  #pragma unroll
  for(int b=0;b<10;b++){
    float c = step*(float)(b+1);
    float u = (d-c)/step;
    float u2 = u*u;
    float f = 0.f;
    if(u2<1.f) f = 1.14136f*__expf(-u2/fmaxf(1.f-u2,1e-6f));
    emb[b] = f*3.1622776601683795f;
  }
}

// ---------------- kernels ----------------
__global__ void k_zero(float* a, size_t na, float* b, size_t nb, float* c, size_t nc,
                       int* d, size_t nd){
  size_t total = na+nb+nc+nd;
  for(size_t i = (size_t)blockIdx.x*blockDim.x+threadIdx.x; i<total; i += (size_t)gridDim.x*blockDim.x){
    if(i<na) a[i]=0.f;
    else if(i<na+nb) b[i-na]=0.f;
    else if(i<na+nb+nc) c[i-na-nb]=0.f;
    else d[i-na-nb-nc]=0;
  }
}

__global__ void k_deg(const int* __restrict__ edst, int* __restrict__ deg, int E){
  int e = blockIdx.x*256 + threadIdx.x;
  if(e<E) atomicAdd(&deg[edst[e]], 1);
}

__global__ __launch_bounds__(1024) void k_scan(const int* __restrict__ deg, int* __restrict__ row,
                                               int* __restrict__ cursor, int N){
  __shared__ int buf[2][1024];
  __shared__ int carry;
  int t = threadIdx.x;
  if(t==0) carry=0;
  __syncthreads();
  for(int base=0; base<N; base+=1024){
    int i = base+t;
    int v = (i<N)? deg[i] : 0;
    int cur=0;
    buf[0][t]=v; __syncthreads();
    for(int off=1; off<1024; off<<=1){
      int val = buf[cur][t];
      if(t>=off) val += buf[cur][t-off];
      buf[cur^1][t]=val; __syncthreads();
      cur^=1;
    }
    if(i<N) row[i] = carry + buf[cur][t] - v;
    int tot = buf[cur][1023];
    __syncthreads();
    if(t==0) carry += tot;
    __syncthreads();
  }
  if(t==0) row[N]=carry;
  for(int i=t;i<N;i+=1024) cursor[i]=0;
}

__global__ void k_fill(const int* __restrict__ edst, const int* __restrict__ row,
                       int* __restrict__ cursor, int* __restrict__ perm, int E){
  int e = blockIdx.x*256 + threadIdx.x;
  if(e<E){
    int d = edst[e];
    int p = atomicAdd(&cursor[d], 1);
    perm[row[d]+p] = e;
  }
}

// Pack W2 (scaled by 1/16) and W1 (scaled by 1/sqrt(10)*sqrt(2)) into fp16 MFMA
// B-fragments with the slot mapping k = g*4 + (s&3) + ((s>>2)<<4).
#define NB1 (17*8*64*8)
#define NB2 (2*8*64*8)
#define NW1 (16*64*8)
__global__ void k_prep(const float* __restrict__ W2a, const float* __restrict__ W2b,
                       const float* __restrict__ W1a, const float* __restrict__ W1b,
                       unsigned short* __restrict__ B1, unsigned short* __restrict__ B2,
                       unsigned short* __restrict__ W1p1, unsigned short* __restrict__ W1p2){
  int i = blockIdx.x*256 + threadIdx.x;
  if(i < NB1){
    int s = i&7, lane = (i>>3)&63, ks = (i>>9)&7, ct = i>>12;
    int g = lane>>4;
    int k = ks*32 + g*4 + (s&3) + ((s>>2)<<4);
    int c = ct*16 + (lane&15);
    B1[i] = f2h(W2a[k*272+c]*0.0625f);
  } else if(i < NB1+NB2){
    int j = i - NB1;
    int s = j&7, lane = (j>>3)&63, ks = (j>>9)&7, ct = j>>12;
    int g = lane>>4;
    int k = ks*32 + g*4 + (s&3) + ((s>>2)<<4);
    int c = ct*16 + (lane&15);
    B2[j] = f2h(W2b[k*32+c]*0.0625f);
  } else if(i < NB1+NB2+NW1){
    int j = i - NB1 - NB2;
    int s = j&7, lane = (j>>3)&63, ct = j>>9;
    int g = lane>>4;
    int k = g*4 + (s&3) + ((s>>2)<<4);
    int c = ct*16 + (lane&15);
    W1p1[j] = (k<10)? f2h(W1a[k*256+c]*0.4472135954999579f) : (unsigned short)0;
  } else if(i < NB1+NB2+2*NW1){
    int j = i - NB1 - NB2 - NW1;
    int s = j&7, lane = (j>>3)&63, ct = j>>9;
    int g = lane>>4;
    int k = g*4 + (s&3) + ((s>>2)<<4);
    int c = ct*16 + (lane&15);
    W1p2[j] = (k<10)? f2h(W1b[k*256+c]*0.4472135954999579f) : (unsigned short)0;
  }
}

// sorted edges: per-dst-run reduced scatter of sh into x
__global__ __launch_bounds__(256) void k_edge_pre(
    const float* __restrict__ pos, const int* __restrict__ esrc, const int* __restrict__ edst,
    const int* __restrict__ perm, float* __restrict__ x, int E){
  __shared__ float shs[256*17];
  __shared__ int dsts[256];
  int t = threadIdx.x;
  int idx = blockIdx.x*256 + t;
  int d = -1;
  if(idx<E){
    int e = perm[idx];
    int s = esrc[e]; d = edst[e];
    float ex=pos[3*d]-pos[3*s], ey=pos[3*d+1]-pos[3*s+1], ez=pos[3*d+2]-pos[3*s+2];
    float dd = sqrtf(ex*ex+ey*ey+ez*ez+1e-12f);
    sph16(ex/dd, ey/dd, ez/dd, &shs[t*17]);
  }
  dsts[t] = d;
  __syncthreads();
  bool leader = (d>=0) && (t==0 || dsts[t-1]!=d);
  if(leader){
    int len=1;
    while(t+len<256 && dsts[t+len]==d) len++;
    #pragma unroll
    for(int j=0;j<16;j++){
      float a=0.f;
      for(int k=0;k<len;k++) a += shs[(t+k)*17+j];
      atomicAdd(&x[(size_t)d*16+j], a);
    }
  }
}

// LDS layout (floats) for k_fc1_tp1 (512 threads):
//   sh_t @0 [32][17] | x1_t @544 [32][17] | emb_t @1088 [32][17]
//   Hbf @1632: us[32][268] = 4288 f  (S_l aliases: [32][40])
//   Wt_h @5920: us[32][276] = 4416 f
//   ef_h @10336: [32][81] = 2592 f
#define F1_H    1632
#define F1_WT   5920
#define F1_EF   10336
#define F1_TOT  12928

__global__ __launch_bounds__(512) void k_fc1_tp1(
    const float* __restrict__ pos, const int* __restrict__ esrc, const int* __restrict__ edst,
    const int* __restrict__ perm,
    const unsigned short* __restrict__ W1p, const unsigned short* __restrict__ B1,
    const float* __restrict__ xnode, float* __restrict__ ef1,
    const TPTables* __restrict__ T, int E, float inv_nn)
{
  __shared__ __align__(16) float sm[F1_TOT];
  __shared__ int src_t[TILE], dst_t[TILE];
  float* sh_t  = sm;
  float* x1_t  = sm + 544;
  float* emb_t = sm + 1088;
  unsigned short* Hbf  = (unsigned short*)(sm + F1_H);
  float* S_l   = sm + F1_H;
  unsigned short* Wt_h = (unsigned short*)(sm + F1_WT);
  float* ef_h  = sm + F1_EF;
  int t = threadIdx.x;
  int e0 = blockIdx.x*TILE;
  int nE = min(TILE, E-e0);

  // P1: per-edge geometry (threads 0..31)
  if(t<TILE){
    float embr[10];
    if(t<nE){
      int e = perm[e0+t];
      int s=esrc[e], d=edst[e];
      src_t[t]=s; dst_t[t]=d;
      float ex=pos[3*d]-pos[3*s], ey=pos[3*d+1]-pos[3*s+1], ez=pos[3*d+2]-pos[3*s+2];
      float dd=sqrtf(ex*ex+ey*ey+ez*ez+1e-12f);
      sph16(ex/dd,ey/dd,ez/dd, &sh_t[t*17]);
      radial10(dd, embr);
    } else {
      src_t[t]=0; dst_t[t]=-1;
      #pragma unroll
      for(int j=0;j<16;j++) sh_t[t*17+j]=0.f;
      #pragma unroll
      for(int b=0;b<10;b++) embr[b]=0.f;
    }
    #pragma unroll
    for(int b=0;b<10;b++) emb_t[t*17+b]=embr[b];
  }
  __syncthreads();
  // P2: x1 gather (1 elem/thread) + H-GEMM via MFMA (emb @ W1p)
  { int e=t>>4, j=t&15; x1_t[e*17+j] = xnode[(size_t)src_t[e]*16+j]*inv_nn; }
  {
    int w = t>>6, lane = t&63, g2 = lane>>4, lr = lane&15;
    float af0[8], af1[8];
    #pragma unroll
    for(int s=0;s<8;s++){
      int k = g2*4 + (s&3) + ((s>>2)<<4);
      af0[s] = (k<10)? emb_t[lr*17+k] : 0.f;
      af1[s] = (k<10)? emb_t[(16+lr)*17+k] : 0.f;
    }
    union { f16x8 v; uint32_t w4[4]; } a0, a1;
    #pragma unroll
    for(int i=0;i<4;i++){
      a0.w4[i] = (uint32_t)f2h(af0[2*i]) | ((uint32_t)f2h(af0[2*i+1])<<16);
      a1.w4[i] = (uint32_t)f2h(af1[2*i]) | ((uint32_t)f2h(af1[2*i+1])<<16);
    }
    #pragma unroll
    for(int q=0;q<2;q++){
      int ct = w*2+q;
      f16x8 b = *(const f16x8*)(W1p + ((size_t)(ct*64+lane))*8);
      f32x4 z = {0.f,0.f,0.f,0.f};
      f32x4 c0 = __builtin_amdgcn_mfma_f32_16x16x32_f16(a0.v, b, z, 0,0,0);
      f32x4 c1 = __builtin_amdgcn_mfma_f32_16x16x32_f16(a1.v, b, z, 0,0,0);
      #pragma unroll
      for(int r=0;r<4;r++){
        Hbf[(g2*4+r)*HSTRIDE + ct*16+lr]    = f2h(fmaxf(c0[r],0.f));
        Hbf[(16+g2*4+r)*HSTRIDE + ct*16+lr] = f2h(fmaxf(c1[r],0.f));
      }
    }
  }
  __syncthreads();
  // P3: W = H @ B1 (272 cols, 17 col-tiles over 8 waves)
  {
    int w = t>>6, lane = t&63, g2 = lane>>4, lr = lane&15;
    for(int ct = w; ct < 17; ct += 8){
      f32x4 acc0 = {0.f,0.f,0.f,0.f}, acc1 = {0.f,0.f,0.f,0.f};
      for(int ks=0; ks<8; ks++){
        f16x8 b = *(const f16x8*)(B1 + ((size_t)(ct*8+ks)*64 + lane)*8);
        union { f16x8 v; uint32_t w4[4]; } a0, a1;
        const uint32_t* p0 = (const uint32_t*)(Hbf + lr*HSTRIDE + ks*32 + g2*4);
        const uint32_t* p1 = (const uint32_t*)(Hbf + (16+lr)*HSTRIDE + ks*32 + g2*4);
        a0.w4[0]=p0[0]; a0.w4[1]=p0[1]; a0.w4[2]=p0[8]; a0.w4[3]=p0[9];
        a1.w4[0]=p1[0]; a1.w4[1]=p1[1]; a1.w4[2]=p1[8]; a1.w4[3]=p1[9];
        acc0 = __builtin_amdgcn_mfma_f32_16x16x32_f16(a0.v, b, acc0, 0,0,0);
        acc1 = __builtin_amdgcn_mfma_f32_16x16x32_f16(a1.v, b, acc1, 0,0,0);
      }
      #pragma unroll
      for(int r=0;r<4;r++){
        Wt_h[(g2*4+r)*WSTRIDE + ct*16+lr]    = f2h(acc0[r]);
        Wt_h[(16+g2*4+r)*WSTRIDE + ct*16+lr] = f2h(acc1[r]);
      }
    }
  }
  __syncthreads();
  // P4: cg contraction, 16 threads/edge (S_l aliases dead Hbf)
  int e = t>>4, g = t&15;
  {
    const uint2* cgt = (const uint2*)T->cg1;
    int beg=T->cg1_bnd[g], end=T->cg1_bnd[g+1];
    float acc=0.f; int cur=-1;
    for(int idx=beg; idx<end; idx++){
      uint2 v = cgt[idx];
      uint32_t pk = v.x; float c = __uint_as_float(v.y);
      int i = pk&0xff, j=(pk>>8)&0xff, s=(int)(pk>>16);
      if(s!=cur){ if(cur>=0) S_l[e*40+cur]=acc; cur=s; acc=0.f; }
      acc += c * x1_t[e*17+i] * sh_t[e*17+j];
    }
    if(cur>=0) S_l[e*40+cur]=acc;
  }
  __syncthreads();
  // P5: two output passes (opos halves), staged in f32 ef_h then run-flushed
  const uint2* ot = (const uint2*)T->out1;
  #pragma unroll
  for(int h=0; h<2; h++){
    for(int i=t;i<TILE*81;i+=512) ef_h[i]=0.f;
    __syncthreads();
    if(e<nE){
      int beg=T->out1_bnd[h][g], end=T->out1_bnd[h][g+1];
      float acc=0.f; int cur=-1;
      for(int idx=beg; idx<end; idx++){
        uint2 v = ot[idx];
        uint32_t pk = v.x; float cf = __uint_as_float(v.y);
        int opos=(int)(pk&0xff), widx=(int)((pk>>8)&0xfff), s=(int)(pk>>20);
        if(opos!=cur){ if(cur>=0) ef_h[e*81 + (cur-80*h)]=acc; cur=opos; acc=0.f; }
        acc += cf * h2f(Wt_h[e*WSTRIDE+widx]) * S_l[e*40+s];
      }
      if(cur>=0) ef_h[e*81 + (cur-80*h)]=acc;
    }
    __syncthreads();
    if(t<80){
      float acc=0.f;
      for(int e2=0;e2<TILE;e2++){
        int d = dst_t[e2];
        if(d>=0) acc += ef_h[e2*81+t];
        bool bnd = (e2==TILE-1) || (dst_t[e2+1]!=d);
        if(bnd){
          if(d>=0 && acc!=0.f) atomicAdd(&ef1[(size_t)d*160 + 80*h + t], acc);
          acc=0.f;
        }
      }
    }
    __syncthreads();
  }
}

__global__ void k_gate(const float* __restrict__ ef1, float* __restrict__ xg, int N, float inv_nn){
  int n = blockIdx.x*256+threadIdx.x;
  if(n>=N) return;
  const float* v = ef1 + (size_t)n*160;
  float* o = xg + (size_t)n*128;
  float g[32];
  #pragma unroll
  for(int i=0;i<16;i++) o[i] = fmaxf(v[i]*inv_nn, 0.f);
  #pragma unroll
  for(int i=0;i<16;i++) o[16+i] = tanhf(v[16+i]*inv_nn);
  #pragma unroll
  for(int i=0;i<8;i++) g[i]    = fmaxf(v[32+i]*inv_nn,0.f);
  #pragma unroll
  for(int i=0;i<8;i++) g[8+i]  = tanhf(v[40+i]*inv_nn);
  #pragma unroll
  for(int i=0;i<8;i++) g[16+i] = fmaxf(v[48+i]*inv_nn,0.f);
  #pragma unroll
  for(int i=0;i<8;i++) g[24+i] = tanhf(v[56+i]*inv_nn);
  #pragma unroll
  for(int u=0;u<32;u++){
    float gu = g[u];
    #pragma unroll
    for(int k=0;k<3;k++) o[32+u*3+k] = v[64+u*3+k]*inv_nn*gu;
  }
}

// LDS layout (floats) for k_fc2_tp2 (512 threads):
//   sh_t @0 [32][17] | xg_t @544 [32][65] | emb_t @2624 [32][17]
//   Hbf @3168: us[32][268] = 4288 f (S_l aliases [32][33])
//   Wt2 @7456: f32 [32][36] = 1152 | bins @8608 (16)
#define F2_H    3168
#define F2_WT   7456
#define F2_BINS 8608
#define F2_TOT  8624

__global__ __launch_bounds__(512) void k_fc2_tp2(
    const float* __restrict__ pos, const int* __restrict__ esrc, const int* __restrict__ edst,
    const int* __restrict__ batch,
    const unsigned short* __restrict__ W1p, const unsigned short* __restrict__ B2,
    const float* __restrict__ xg, float* __restrict__ out,
    const TPTables* __restrict__ T, int E, float out_scale, int G)
{
  __shared__ __align__(16) float sm[F2_TOT];
  __shared__ int src_t[TILE], dst_t[TILE], g_t[TILE];
  float* sh_t  = sm;
  float* xg_t  = sm + 544;
  float* emb_t = sm + 2624;
  unsigned short* Hbf = (unsigned short*)(sm + F2_H);
  float* S_l   = sm + F2_H;
  float* Wt    = sm + F2_WT;
  float* bins  = sm + F2_BINS;
  int t = threadIdx.x;
  int e0 = blockIdx.x*TILE;
  int nE = min(TILE, E-e0);

  if(t<TILE){
    float embr[10];
    if(t<nE){
      int s=esrc[e0+t], d=edst[e0+t];
      src_t[t]=s; dst_t[t]=d; g_t[t]=batch[d];
      float ex=pos[3*d]-pos[3*s], ey=pos[3*d+1]-pos[3*s+1], ez=pos[3*d+2]-pos[3*s+2];
      float dd=sqrtf(ex*ex+ey*ey+ez*ez+1e-12f);
      sph16(ex/dd,ey/dd,ez/dd, &sh_t[t*17]);
      radial10(dd, embr);
    } else {
      src_t[t]=0; dst_t[t]=-1; g_t[t]=0;
      #pragma unroll
      for(int j=0;j<16;j++) sh_t[t*17+j]=0.f;
      #pragma unroll
      for(int b=0;b<10;b++) embr[b]=0.f;
    }
    #pragma unroll
    for(int b=0;b<10;b++) emb_t[t*17+b]=embr[b];
  } else if(t<TILE+16){
    bins[t-TILE]=0.f;
  }
  __syncthreads();
  for(int i=t;i<TILE*64;i+=512){
    int e=i>>6, j=i&63;
    xg_t[e*65+j] = xg[(size_t)src_t[e]*128 + (j<16? j : j+16)];
  }
  {
    int w = t>>6, lane = t&63, g2 = lane>>4, lr = lane&15;
    float af0[8], af1[8];
    #pragma unroll
    for(int s=0;s<8;s++){
      int k = g2*4 + (s&3) + ((s>>2)<<4);
      af0[s] = (k<10)? emb_t[lr*17+k] : 0.f;
      af1[s] = (k<10)? emb_t[(16+lr)*17+k] : 0.f;
    }
    union { f16x8 v; uint32_t w4[4]; } a0, a1;
    #pragma unroll
    for(int i=0;i<4;i++){
      a0.w4[i] = (uint32_t)f2h(af0[2*i]) | ((uint32_t)f2h(af0[2*i+1])<<16);
      a1.w4[i] = (uint32_t)f2h(af1[2*i]) | ((uint32_t)f2h(af1[2*i+1])<<16);
    }
    #pragma unroll
    for(int q=0;q<2;q++){
      int ct = w*2+q;
      f16x8 b = *(const f16x8*)(W1p + ((size_t)(ct*64+lane))*8);
      f32x4 z = {0.f,0.f,0.f,0.f};
      f32x4 c0 = __builtin_amdgcn_mfma_f32_16x16x32_f16(a0.v, b, z, 0,0,0);
      f32x4 c1 = __builtin_amdgcn_mfma_f32_16x16x32_f16(a1.v, b, z, 0,0,0);
      #pragma unroll
      for(int r=0;r<4;r++){
        Hbf[(g2*4+r)*HSTRIDE + ct*16+lr]    = f2h(fmaxf(c0[r],0.f));
        Hbf[(16+g2*4+r)*HSTRIDE + ct*16+lr] = f2h(fmaxf(c1[r],0.f));
      }
    }
  }
  __syncthreads();
  {
    int w = t>>6, lane = t&63, g2 = lane>>4, lr = lane&15;
    if(w<2){
      int ct = w;
      f32x4 acc0 = {0.f,0.f,0.f,0.f}, acc1 = {0.f,0.f,0.f,0.f};
      for(int ks=0; ks<8; ks++){
        f16x8 b = *(const f16x8*)(B2 + ((size_t)(ct*8+ks)*64 + lane)*8);
        union { f16x8 v; uint32_t w4[4]; } a0, a1;
        const uint32_t* p0 = (const uint32_t*)(Hbf + lr*HSTRIDE + ks*32 + g2*4);
        const uint32_t* p1 = (const uint32_t*)(Hbf + (16+lr)*HSTRIDE + ks*32 + g2*4);
        a0.w4[0]=p0[0]; a0.w4[1]=p0[1]; a0.w4[2]=p0[8]; a0.w4[3]=p0[9];
        a1.w4[0]=p1[0]; a1.w4[1]=p1[1]; a1.w4[2]=p1[8]; a1.w4[3]=p1[9];
        acc0 = __builtin_amdgcn_mfma_f32_16x16x32_f16(a0.v, b, acc0, 0,0,0);
        acc1 = __builtin_amdgcn_mfma_f32_16x16x32_f16(a1.v, b, acc1, 0,0,0);
      }
      #pragma unroll
      for(int r=0;r<4;r++){
        Wt[(g2*4+r)*36 + ct*16+lr]    = acc0[r];
        Wt[(16+g2*4+r)*36 + ct*16+lr] = acc1[r];
      }
    }
  }
  __syncthreads();
  int e = t>>4, g = t&15;
  {
    const uint2* cgt = (const uint2*)T->cg2;
    int beg=T->cg2_bnd[g], end=T->cg2_bnd[g+1];
    float acc=0.f; int cur=-1;
    for(int idx=beg; idx<end; idx++){
      uint2 v = cgt[idx];
      uint32_t pk = v.x; float c = __uint_as_float(v.y);
      int i=pk&0xff, j=(pk>>8)&0xff, s=(int)(pk>>16);
      if(s!=cur){ if(cur>=0) S_l[e*33+cur]=acc; cur=s; acc=0.f; }
      acc += c*xg_t[e*65+i]*sh_t[e*17+j];
    }
    if(cur>=0) S_l[e*33+cur]=acc;
  }
  __syncthreads();
  {
    const uint2* ot = (const uint2*)T->out2;
    int n = T->n_out2;
    int per = (n+15)>>4;
    int beg = g*per, end = min(beg+per, n);
    float v=0.f;
    for(int idx=beg; idx<end; idx++){
      uint2 u = ot[idx];
      uint32_t pk = u.x; float cf = __uint_as_float(u.y);
      int widx=(int)((pk>>8)&0xfff), s=(int)(pk>>20);
      v += cf * Wt[e*36+widx] * S_l[e*33+s];
    }
    #pragma unroll
    for(int m=1;m<16;m<<=1) v += __shfl_xor(v, m, 64);
    if(g==0 && e<nE) atomicAdd(&bins[g_t[e]], v);
  }
  __syncthreads();
  if(t<G) atomicAdd(&out[t], bins[t]*out_scale);
}

// ---------------- launch ----------------
extern "C" void kernel_launch(void* const* d_in, const int* in_sizes, int n_in,
                              void* d_out, int out_size, void* d_ws, size_t ws_size,
                              hipStream_t stream) {
  const float* pos  = (const float*)d_in[0];
  const float* w11  = (const float*)d_in[1];
  const float* w12  = (const float*)d_in[2];
  const float* w21  = (const float*)d_in[3];
  const float* w22  = (const float*)d_in[4];
  const int*   esrc = (const int*)d_in[5];
  const int*   edst = (const int*)d_in[6];
  const int*   batch= (const int*)d_in[7];
  int E = in_sizes[5];
  int N = in_sizes[0]/3;
  int G = out_size;

  double nn = std::sqrt((double)E/(double)N);
  float inv_nn    = (float)(1.0/nn);
  float out_scale = (float)(1.0/(nn*std::sqrt((double)N)));

  float* ws = (float*)d_ws;
  float* x   = ws;
  float* ef1 = x   + (size_t)N*16;
  float* xg  = ef1 + (size_t)N*160;
  TPTables* dT = (TPTables*)(xg + (size_t)N*128);
  unsigned short* B1   = (unsigned short*)(((char*)dT) + ((sizeof(TPTables)+255)&~(size_t)255));
  unsigned short* B2   = B1 + NB1;
  unsigned short* W1p1 = B2 + NB2;
  unsigned short* W1p2 = W1p1 + NW1;
  int* deg    = (int*)(W1p2 + NW1);
  int* row    = deg + N;
  int* cursor = row + (N+1);
  int* perm   = cursor + N;

  static TPTables hT;
  build_tables(hT);
  hipMemcpyAsync(dT, &hT, sizeof(TPTables), hipMemcpyHostToDevice, stream);

  size_t nz = (size_t)N*16 + (size_t)N*160 + G + N;
  int zgrid = (int)((nz+255)/256); if(zgrid>2048) zgrid=2048;
  k_zero<<<zgrid,256,0,stream>>>(x, (size_t)N*16, ef1, (size_t)N*160, (float*)d_out, (size_t)G, deg, (size_t)N);
  k_deg<<<(E+255)/256,256,0,stream>>>(edst, deg, E);
  k_scan<<<1,1024,0,stream>>>(deg, row, cursor, N);
  k_fill<<<(E+255)/256,256,0,stream>>>(edst, row, cursor, perm, E);
  k_prep<<<(NB1+NB2+2*NW1+255)/256,256,0,stream>>>(w12, w22, w11, w21, B1, B2, W1p1, W1p2);
  k_edge_pre<<<(E+255)/256,256,0,stream>>>(pos, esrc, edst, perm, x, E);
  k_fc1_tp1<<<(E+TILE-1)/TILE,512,0,stream>>>(pos, esrc, edst, perm, W1p1, B1, x, ef1, dT, E, inv_nn);
  k_gate<<<(N+255)/256,256,0,stream>>>(ef1, xg, N, inv_nn);
  k_fc2_tp2<<<(E+TILE-1)/TILE,512,0,stream>>>(pos, esrc, edst, batch, W1p2, B2, xg,
                                              (float*)d_out, dT, E, out_scale, G);
}

// Round 5
// 1300.307 us; speedup vs baseline: 4.7907x; 1.1109x over previous
//
#include <hip/hip_runtime.h>
#include <cmath>
#include <cstdint>
#include <cstring>
#include <cstdlib>
#include <vector>
#include <algorithm>
#include <complex>

#define TILE 32
#define HSTRIDE 268   // ushort stride of H rows in LDS
#define WSTRIDE 276   // ushort stride of W rows in LDS

typedef __attribute__((ext_vector_type(8))) _Float16 f16x8;
typedef __attribute__((ext_vector_type(4))) float f32x4;

// ------------------------------------------------------------------
// Padded, branch-free TP tables (host-built, deterministic, one H2D).
//   cg1p:  [40 slots][16] entries {i|j<<8, coef}   S[slot] += c*x1[i]*sh[j]
//   out1p: [128 active][6] entries {widx|s<<16, coef}
//   cg2p:  [32 slots][4]
//   out2p: [32] entries {widx|s<<16, coef} (single output)
//   aop:   active->real opos map for TP1 outputs
// ------------------------------------------------------------------
struct TPTables {
  uint32_t cg1p[40*16*2];
  uint32_t out1p[128*6*2];
  uint32_t cg2p[32*4*2];
  uint32_t out2p[32*2];
  int aop[128];
};

static double factd(int n){ double r=1; for(int i=2;i<=n;i++) r*=(double)i; return r; }

static double cg_complex(int j1,int m1,int j2,int m2,int j3,int m3){
  if(m1+m2!=m3) return 0.0;
  double pref = std::sqrt((2*j3+1)*factd(j3+j1-j2)*factd(j3-j1+j2)*factd(j1+j2-j3)/factd(j1+j2+j3+1));
  pref *= std::sqrt(factd(j3+m3)*factd(j3-m3)*factd(j1-m1)*factd(j1+m1)*factd(j2-m2)*factd(j2+m2));
  double s=0.0;
  for(int k=0;k<=j1+j2-j3;k++){
    int dd[6] = {k, j1+j2-j3-k, j1-m1-k, j2+m2-k, j3-j2+m1+k, j3-j1-m2+k};
    bool ok=true; double prod=1.0;
    for(int t=0;t<6;t++){ if(dd[t]<0){ok=false;break;} prod*=factd(dd[t]); }
    if(!ok) continue;
    s += ((k&1)?-1.0:1.0)/prod;
  }
  return pref*s;
}

typedef std::complex<double> cd;
static void real_U(int l, cd* U){
  int n = 2*l+1;
  for(int i=0;i<n*n;i++) U[i]=cd(0,0);
  U[l*n+l] = cd(1,0);
  for(int m=1;m<=l;m++){
    double sgn = (m&1)? -1.0 : 1.0;
    double is2 = 1.0/std::sqrt(2.0);
    U[(l+m)*n + (l+m)] = cd(sgn*is2,0);
    U[(l+m)*n + (l-m)] = cd(is2,0);
    U[(l-m)*n + (l+m)] = cd(0,-sgn*is2);
    U[(l-m)*n + (l-m)] = cd(0,is2);
  }
}

static void real_cg_h(int l1,int l2,int l3, double* out){
  int n1=2*l1+1,n2=2*l2+1,n3=2*l3+1;
  std::vector<cd> C(n1*n2*n3);
  for(int a=-l1;a<=l1;a++)for(int b=-l2;b<=l2;b++)for(int c=-l3;c<=l3;c++)
    C[(size_t)((a+l1)*n2+(b+l2))*n3+(c+l3)] = cd(cg_complex(l1,a,l2,b,l3,c),0);
  std::vector<cd> U1(n1*n1),U2(n2*n2),U3(n3*n3);
  real_U(l1,U1.data()); real_U(l2,U2.data()); real_U(l3,U3.data());
  std::vector<cd> T((size_t)n1*n2*n3, cd(0,0));
  for(int i=0;i<n1;i++)for(int j=0;j<n2;j++)for(int k=0;k<n3;k++){
    cd acc(0,0);
    for(int a=0;a<n1;a++){ cd u1=U1[i*n1+a]; if(u1==cd(0,0)) continue;
      for(int b=0;b<n2;b++){ cd u2=U2[j*n2+b]; if(u2==cd(0,0)) continue;
        for(int c=0;c<n3;c++){ cd u3=std::conj(U3[k*n3+c]); if(u3==cd(0,0)) continue;
          acc += u1*u2*u3*C[(size_t)(a*n2+b)*n3+c];
        } } }
    T[(size_t)(i*n2+j)*n3+k]=acc;
  }
  double sr=0, si=0;
  for(auto&z:T){ sr += std::fabs(z.real()); si += std::fabs(z.imag()); }
  int tot=n1*n2*n3;
  std::vector<double> R(tot);
  for(int i=0;i<tot;i++) R[i] = (sr>=si)? T[i].real() : T[i].imag();
  double nrm=0; for(double v:R) nrm += v*v; nrm = std::sqrt(nrm);
  for(int i=0;i<tot;i++) out[i] = R[i]/nrm;
}

struct HIrr{int m,l,p;};
static int map_id(int i){return i;}
static int map_gate(int i){return (i<16)? i : i-16;}

static void build_one(const std::vector<HIrr>& ir1, const std::vector<HIrr>& ir2,
                      const std::vector<HIrr>& ir3, int (*map1)(int), bool sort_out,
                      std::vector<uint32_t>& cg_pk, std::vector<float>& cg_c,
                      std::vector<uint32_t>& out_pk, std::vector<float>& out_c)
{
  int n1=(int)ir1.size(), n2=(int)ir2.size(), n3=(int)ir3.size();
  std::vector<int> s1(n1), s2(n2), s3(n3);
  { int o=0; for(int i=0;i<n1;i++){ s1[i]=o; o+=ir1[i].m*(2*ir1[i].l+1);} }
  { int o=0; for(int i=0;i<n2;i++){ s2[i]=o; o+=ir2[i].m*(2*ir2[i].l+1);} }
  { int o=0; for(int i=0;i<n3;i++){ s3[i]=o; o+=ir3[i].m*(2*ir3[i].l+1);} }
  struct Inst{int i1,i2,i3,w0;};
  std::vector<Inst> insts; int woff=0;
  for(int i1=0;i1<n1;i1++)for(int i2=0;i2<n2;i2++)for(int i3=0;i3<n3;i3++){
    const HIrr&A=ir1[i1];const HIrr&B=ir2[i2];const HIrr&C=ir3[i3];
    int dl = A.l-B.l; if(dl<0) dl=-dl;
    if(A.p*B.p==C.p && dl<=C.l && C.l<=A.l+B.l){
      insts.push_back({i1,i2,i3,woff}); woff += A.m*B.m*C.m;
    }
  }
  std::vector<int> fan(n3,0);
  for(auto&P:insts) fan[P.i3] += ir1[P.i1].m*ir2[P.i2].m;
  struct OE{int opos,widx,s;float coef;};
  std::vector<OE> outs;
  int sbase=0;
  for(auto&P:insts){
    const HIrr&A=ir1[P.i1];const HIrr&B=ir2[P.i2];const HIrr&C=ir3[P.i3];
    int d1=2*A.l+1,d2=2*B.l+1,d3=2*C.l+1;
    double cg[343];
    real_cg_h(A.l,B.l,C.l,cg);
    double alpha = std::sqrt((double)d3/(double)fan[P.i3]);
    for(int u=0;u<A.m;u++)for(int v=0;v<B.m;v++){
      for(int k=0;k<d3;k++)
        for(int i=0;i<d1;i++)for(int j=0;j<d2;j++){
          double c = cg[(i*d2+j)*d3+k];
          if(std::fabs(c)<1e-8) continue;
          int iabs = map1(s1[P.i1]+u*d1+i);
          int jabs = s2[P.i2]+v*d2+j;
          cg_pk.push_back((uint32_t)iabs | ((uint32_t)jabs<<8) | ((uint32_t)(sbase+k)<<16));
          cg_c.push_back((float)c);
        }
      for(int w=0;w<C.m;w++)for(int k=0;k<d3;k++){
        OE o; o.opos=s3[P.i3]+w*d3+k; o.widx=P.w0+(u*B.m+v)*C.m+w; o.s=sbase+k; o.coef=(float)alpha;
        outs.push_back(o);
      }
      sbase += d3;
    }
  }
  if(sort_out) std::stable_sort(outs.begin(), outs.end(),
      [](const OE&a,const OE&b){return a.opos<b.opos;});
  for(auto&o:outs){
    out_pk.push_back((uint32_t)o.opos | ((uint32_t)o.widx<<8) | ((uint32_t)o.s<<20));
    out_c.push_back(o.coef);
  }
}

static uint32_t fbits(float f){ uint32_t u; memcpy(&u,&f,4); return u; }

static void build_tables(TPTables& T){
  std::vector<HIrr> IR_SH   ={{1,0,1},{1,1,-1},{1,2,1},{1,3,-1}};
  std::vector<HIrr> GATE_IN ={{16,0,1},{16,0,-1},{8,0,1},{8,0,-1},{8,0,1},{8,0,-1},{16,1,-1},{16,1,1}};
  std::vector<HIrr> GATE_OUT={{16,0,1},{16,0,-1},{16,1,-1},{16,1,1}};
  std::vector<HIrr> IR_OUT  ={{1,0,1}};
  std::vector<uint32_t> cg1,o1,cg2,o2; std::vector<float> cg1c,o1c,cg2c,o2c;
  build_one(IR_SH,IR_SH,GATE_IN,map_id,true,cg1,cg1c,o1,o1c);
  build_one(GATE_OUT,IR_SH,IR_OUT,map_gate,false,cg2,cg2c,o2,o2c);
  memset(&T,0,sizeof(T));
  // cg1p [40][16]
  {
    int cnt[64]; memset(cnt,0,sizeof(cnt));
    for(size_t idx=0; idx<cg1.size(); ++idx){
      int s = (int)(cg1[idx]>>16);
      int i = cg1[idx]&0xff, j=(cg1[idx]>>8)&0xff;
      if(s<40 && cnt[s]<16){
        T.cg1p[(s*16+cnt[s])*2]   = (uint32_t)i | ((uint32_t)j<<8);
        T.cg1p[(s*16+cnt[s])*2+1] = fbits(cg1c[idx]);
        cnt[s]++;
      }
    }
  }
  // out1p [128][6] + aop
  {
    int actof[256]; for(int i=0;i<256;i++) actof[i]=-1;
    int cnt[128]; memset(cnt,0,sizeof(cnt));
    int nact=0;
    for(size_t idx=0; idx<o1.size(); ++idx){
      int opos = o1[idx]&0xff;
      int widx = (o1[idx]>>8)&0xfff;
      int s    = (int)(o1[idx]>>20);
      if(actof[opos]<0){ if(nact>=128) continue; actof[opos]=nact; T.aop[nact]=opos; nact++; }
      int a = actof[opos];
      if(cnt[a]<6){
        T.out1p[(a*6+cnt[a])*2]   = (uint32_t)widx | ((uint32_t)s<<16);
        T.out1p[(a*6+cnt[a])*2+1] = fbits(o1c[idx]);
        cnt[a]++;
      }
    }
  }
  // cg2p [32][4]
  {
    int cnt[32]; memset(cnt,0,sizeof(cnt));
    for(size_t idx=0; idx<cg2.size(); ++idx){
      int s = (int)(cg2[idx]>>16);
      int i = cg2[idx]&0xff, j=(cg2[idx]>>8)&0xff;
      if(s<32 && cnt[s]<4){
        T.cg2p[(s*4+cnt[s])*2]   = (uint32_t)i | ((uint32_t)j<<8);
        T.cg2p[(s*4+cnt[s])*2+1] = fbits(cg2c[idx]);
        cnt[s]++;
      }
    }
  }
  // out2p [32]
  for(size_t idx=0; idx<o2.size() && idx<32; ++idx){
    int widx = (o2[idx]>>8)&0xfff;
    int s    = (int)(o2[idx]>>20);
    T.out2p[idx*2]   = (uint32_t)widx | ((uint32_t)s<<16);
    T.out2p[idx*2+1] = fbits(o2c[idx]);
  }
}

// ---------------- device helpers ----------------
__device__ __forceinline__ unsigned short f2h(float f){
  _Float16 h = (_Float16)f;
  unsigned short u; __builtin_memcpy(&u, &h, 2); return u;
}
__device__ __forceinline__ float h2f(unsigned short u){
  _Float16 h; __builtin_memcpy(&h, &u, 2); return (float)h;
}

__device__ __forceinline__ void sph16(float x,float y,float z,float* sh){
  float x2=x*x, y2=y*y, z2=z*z;
  const float SQ3=1.7320508075688772f, SQ5=2.23606797749979f, SQ7=2.6457513110645907f;
  const float SQ15=3.872983346207417f, SQ42=6.48074069840786f, SQ70=8.366600265340756f, SQ105=10.246950765959598f;
  sh[0]=1.f;
  sh[1]=SQ3*y;  sh[2]=SQ3*z;  sh[3]=SQ3*x;
  sh[4]=SQ15*x*y; sh[5]=SQ15*y*z; sh[6]=0.5f*SQ5*(3.f*z2-1.f); sh[7]=SQ15*x*z; sh[8]=0.5f*SQ15*(x2-y2);
  sh[9]=0.25f*SQ70*y*(3.f*x2-y2); sh[10]=SQ105*x*y*z; sh[11]=0.25f*SQ42*y*(5.f*z2-1.f);
  sh[12]=0.5f*SQ7*z*(5.f*z2-3.f); sh[13]=0.25f*SQ42*x*(5.f*z2-1.f);
  sh[14]=0.5f*SQ105*z*(x2-y2);    sh[15]=0.25f*SQ70*x*(x2-3.f*y2);
}

__device__ __forceinline__ void radial10(float d, float* emb){
  const float step = 0.2909090909090909f;
  #pragma unroll
  for(int b=0;b<10;b++){
    float c = step*(float)(b+1);
    float u = (d-c)/step;
    float u2 = u*u;
    float f = 0.f;
    if(u2<1.f) f = 1.14136f*__expf(-u2/fmaxf(1.f-u2,1e-6f));
    emb[b] = f*3.1622776601683795f;
  }
}

// ---------------- kernels ----------------
__global__ void k_zero(float* a, size_t na, float* b, size_t nb, float* c, size_t nc,
                       int* d, size_t nd){
  size_t total = na+nb+nc+nd;
  for(size_t i = (size_t)blockIdx.x*blockDim.x+threadIdx.x; i<total; i += (size_t)gridDim.x*blockDim.x){
    if(i<na) a[i]=0.f;
    else if(i<na+nb) b[i-na]=0.f;
    else if(i<na+nb+nc) c[i-na-nb]=0.f;
    else d[i-na-nb-nc]=0;
  }
}

__global__ void k_deg(const int* __restrict__ edst, int* __restrict__ deg, int E){
  int e = blockIdx.x*256 + threadIdx.x;
  if(e<E) atomicAdd(&deg[edst[e]], 1);
}

__global__ __launch_bounds__(1024) void k_scan(const int* __restrict__ deg, int* __restrict__ row,
                                               int* __restrict__ cursor, int N){
  __shared__ int buf[2][1024];
  __shared__ int carry;
  int t = threadIdx.x;
  if(t==0) carry=0;
  __syncthreads();
  for(int base=0; base<N; base+=1024){
    int i = base+t;
    int v = (i<N)? deg[i] : 0;
    int cur=0;
    buf[0][t]=v; __syncthreads();
    for(int off=1; off<1024; off<<=1){
      int val = buf[cur][t];
      if(t>=off) val += buf[cur][t-off];
      buf[cur^1][t]=val; __syncthreads();
      cur^=1;
    }
    if(i<N) row[i] = carry + buf[cur][t] - v;
    int tot = buf[cur][1023];
    __syncthreads();
    if(t==0) carry += tot;
    __syncthreads();
  }
  if(t==0) row[N]=carry;
  for(int i=t;i<N;i+=1024) cursor[i]=0;
}

__global__ void k_fill(const int* __restrict__ edst, const int* __restrict__ row,
                       int* __restrict__ cursor, int* __restrict__ perm, int E){
  int e = blockIdx.x*256 + threadIdx.x;
  if(e<E){
    int d = edst[e];
    int p = atomicAdd(&cursor[d], 1);
    perm[row[d]+p] = e;
  }
}

// Pack W2 (scaled by 1/16) and W1 (scaled by sqrt(2)/sqrt(10)) into fp16 MFMA
// B-fragments with slot mapping k = g*4 + (s&3) + ((s>>2)<<4).
#define NB1 (17*8*64*8)
#define NB2 (2*8*64*8)
#define NW1 (16*64*8)
__global__ void k_prep(const float* __restrict__ W2a, const float* __restrict__ W2b,
                       const float* __restrict__ W1a, const float* __restrict__ W1b,
                       unsigned short* __restrict__ B1, unsigned short* __restrict__ B2,
                       unsigned short* __restrict__ W1p1, unsigned short* __restrict__ W1p2){
  int i = blockIdx.x*256 + threadIdx.x;
  if(i < NB1){
    int s = i&7, lane = (i>>3)&63, ks = (i>>9)&7, ct = i>>12;
    int g = lane>>4;
    int k = ks*32 + g*4 + (s&3) + ((s>>2)<<4);
    int c = ct*16 + (lane&15);
    B1[i] = f2h(W2a[k*272+c]*0.0625f);
  } else if(i < NB1+NB2){
    int j = i - NB1;
    int s = j&7, lane = (j>>3)&63, ks = (j>>9)&7, ct = j>>12;
    int g = lane>>4;
    int k = ks*32 + g*4 + (s&3) + ((s>>2)<<4);
    int c = ct*16 + (lane&15);
    B2[j] = f2h(W2b[k*32+c]*0.0625f);
  } else if(i < NB1+NB2+NW1){
    int j = i - NB1 - NB2;
    int s = j&7, lane = (j>>3)&63, ct = j>>9;
    int g = lane>>4;
    int k = g*4 + (s&3) + ((s>>2)<<4);
    int c = ct*16 + (lane&15);
    W1p1[j] = (k<10)? f2h(W1a[k*256+c]*0.4472135954999579f) : (unsigned short)0;
  } else if(i < NB1+NB2+2*NW1){
    int j = i - NB1 - NB2 - NW1;
    int s = j&7, lane = (j>>3)&63, ct = j>>9;
    int g = lane>>4;
    int k = g*4 + (s&3) + ((s>>2)<<4);
    int c = ct*16 + (lane&15);
    W1p2[j] = (k<10)? f2h(W1b[k*256+c]*0.4472135954999579f) : (unsigned short)0;
  }
}

// sorted edges: per-dst-run reduced scatter of sh into x
__global__ __launch_bounds__(256) void k_edge_pre(
    const float* __restrict__ pos, const int* __restrict__ esrc, const int* __restrict__ edst,
    const int* __restrict__ perm, float* __restrict__ x, int E){
  __shared__ float shs[256*17];
  __shared__ int dsts[256];
  int t = threadIdx.x;
  int idx = blockIdx.x*256 + t;
  int d = -1;
  if(idx<E){
    int e = perm[idx];
    int s = esrc[e]; d = edst[e];
    float ex=pos[3*d]-pos[3*s], ey=pos[3*d+1]-pos[3*s+1], ez=pos[3*d+2]-pos[3*s+2];
    float dd = sqrtf(ex*ex+ey*ey+ez*ez+1e-12f);
    sph16(ex/dd, ey/dd, ez/dd, &shs[t*17]);
  }
  dsts[t] = d;
  __syncthreads();
  bool leader = (d>=0) && (t==0 || dsts[t-1]!=d);
  if(leader){
    int len=1;
    while(t+len<256 && dsts[t+len]==d) len++;
    #pragma unroll
    for(int j=0;j<16;j++){
      float a=0.f;
      for(int k=0;k<len;k++) a += shs[(t+k)*17+j];
      atomicAdd(&x[(size_t)d*16+j], a);
    }
  }
}

// LDS layout (floats) for k_fc1_tp1 (512 threads):
//   sh_t @0 [32][17] | x1_t @544 [32][17] | emb_t @1088 [32][17]
//   Hbf @1632: us[32][268] = 4288 f  (S_l aliases: [32][48])
//   Wt_h @5920: us[32][276] = 4416 f
//   ef_h @10336: [32][65] = 2080 f
#define F1_H    1632
#define F1_WT   5920
#define F1_EF   10336
#define F1_TOT  12416

__global__ __launch_bounds__(512,6) void k_fc1_tp1(
    const float* __restrict__ pos, const int* __restrict__ esrc, const int* __restrict__ edst,
    const int* __restrict__ perm,
    const unsigned short* __restrict__ W1p, const unsigned short* __restrict__ B1,
    const float* __restrict__ xnode, float* __restrict__ ef1,
    const TPTables* __restrict__ T, int E, float inv_nn)
{
  __shared__ __align__(16) float sm[F1_TOT];
  __shared__ int src_t[TILE], dst_t[TILE];
  float* sh_t  = sm;
  float* x1_t  = sm + 544;
  float* emb_t = sm + 1088;
  unsigned short* Hbf  = (unsigned short*)(sm + F1_H);
  float* S_l   = sm + F1_H;
  unsigned short* Wt_h = (unsigned short*)(sm + F1_WT);
  float* ef_h  = sm + F1_EF;
  int t = threadIdx.x;
  int e0 = blockIdx.x*TILE;
  int nE = min(TILE, E-e0);

  // P1: per-edge geometry (threads 0..31)
  if(t<TILE){
    float embr[10];
    if(t<nE){
      int e = perm[e0+t];
      int s=esrc[e], d=edst[e];
      src_t[t]=s; dst_t[t]=d;
      float ex=pos[3*d]-pos[3*s], ey=pos[3*d+1]-pos[3*s+1], ez=pos[3*d+2]-pos[3*s+2];
      float dd=sqrtf(ex*ex+ey*ey+ez*ez+1e-12f);
      sph16(ex/dd,ey/dd,ez/dd, &sh_t[t*17]);
      radial10(dd, embr);
    } else {
      src_t[t]=0; dst_t[t]=-1;
      #pragma unroll
      for(int j=0;j<16;j++) sh_t[t*17+j]=0.f;
      #pragma unroll
      for(int b=0;b<10;b++) embr[b]=0.f;
    }
    #pragma unroll
    for(int b=0;b<10;b++) emb_t[t*17+b]=embr[b];
  }
  __syncthreads();
  // P2: x1 gather (1 elem/thread) + H-GEMM via MFMA (emb @ W1p)
  { int e=t>>4, j=t&15; x1_t[e*17+j] = xnode[(size_t)src_t[e]*16+j]*inv_nn; }
  {
    int w = t>>6, lane = t&63, g2 = lane>>4, lr = lane&15;
    float af0[8], af1[8];
    #pragma unroll
    for(int s=0;s<8;s++){
      int k = g2*4 + (s&3) + ((s>>2)<<4);
      af0[s] = (k<10)? emb_t[lr*17+k] : 0.f;
      af1[s] = (k<10)? emb_t[(16+lr)*17+k] : 0.f;
    }
    union { f16x8 v; uint32_t w4[4]; } a0, a1;
    #pragma unroll
    for(int i=0;i<4;i++){
      a0.w4[i] = (uint32_t)f2h(af0[2*i]) | ((uint32_t)f2h(af0[2*i+1])<<16);
      a1.w4[i] = (uint32_t)f2h(af1[2*i]) | ((uint32_t)f2h(af1[2*i+1])<<16);
    }
    #pragma unroll
    for(int q=0;q<2;q++){
      int ct = w*2+q;
      f16x8 b = *(const f16x8*)(W1p + ((size_t)(ct*64+lane))*8);
      f32x4 z = {0.f,0.f,0.f,0.f};
      f32x4 c0 = __builtin_amdgcn_mfma_f32_16x16x32_f16(a0.v, b, z, 0,0,0);
      f32x4 c1 = __builtin_amdgcn_mfma_f32_16x16x32_f16(a1.v, b, z, 0,0,0);
      #pragma unroll
      for(int r=0;r<4;r++){
        Hbf[(g2*4+r)*HSTRIDE + ct*16+lr]    = f2h(fmaxf(c0[r],0.f));
        Hbf[(16+g2*4+r)*HSTRIDE + ct*16+lr] = f2h(fmaxf(c1[r],0.f));
      }
    }
  }
  __syncthreads();
  // P3: W = H @ B1 (272 cols, 17 col-tiles over 8 waves)
  {
    int w = t>>6, lane = t&63, g2 = lane>>4, lr = lane&15;
    for(int ct = w; ct < 17; ct += 8){
      f32x4 acc0 = {0.f,0.f,0.f,0.f}, acc1 = {0.f,0.f,0.f,0.f};
      #pragma unroll
      for(int ks=0; ks<8; ks++){
        f16x8 b = *(const f16x8*)(B1 + ((size_t)(ct*8+ks)*64 + lane)*8);
        union { f16x8 v; uint32_t w4[4]; } a0, a1;
        const uint32_t* p0 = (const uint32_t*)(Hbf + lr*HSTRIDE + ks*32 + g2*4);
        const uint32_t* p1 = (const uint32_t*)(Hbf + (16+lr)*HSTRIDE + ks*32 + g2*4);
        a0.w4[0]=p0[0]; a0.w4[1]=p0[1]; a0.w4[2]=p0[8]; a0.w4[3]=p0[9];
        a1.w4[0]=p1[0]; a1.w4[1]=p1[1]; a1.w4[2]=p1[8]; a1.w4[3]=p1[9];
        acc0 = __builtin_amdgcn_mfma_f32_16x16x32_f16(a0.v, b, acc0, 0,0,0);
        acc1 = __builtin_amdgcn_mfma_f32_16x16x32_f16(a1.v, b, acc1, 0,0,0);
      }
      #pragma unroll
      for(int r=0;r<4;r++){
        Wt_h[(g2*4+r)*WSTRIDE + ct*16+lr]    = f2h(acc0[r]);
        Wt_h[(16+g2*4+r)*WSTRIDE + ct*16+lr] = f2h(acc1[r]);
      }
    }
  }
  __syncthreads();
  // P4: padded branch-free cg contraction, 16 threads/edge, 3 slot passes
  int e = t>>4, g = t&15;
  {
    const uint2* cgt = (const uint2*)T->cg1p;
    #pragma unroll
    for(int p=0;p<3;p++){
      int slot = p*16 + g;
      if(slot < 40){
        float acc = 0.f;
        #pragma unroll
        for(int q=0;q<16;q++){
          uint2 v = cgt[slot*16+q];
          int i = v.x & 0xff, j = (v.x>>8)&0xff;
          acc += __uint_as_float(v.y) * x1_t[e*17+i] * sh_t[e*17+j];
        }
        S_l[e*48+slot] = acc;
      }
    }
  }
  __syncthreads();
  // P5: two output halves (active idx 0..63 / 64..127), padded 6 entries each
  const uint2* ot = (const uint2*)T->out1p;
  #pragma unroll
  for(int h=0; h<2; h++){
    for(int i=t;i<TILE*65;i+=512) ef_h[i]=0.f;
    __syncthreads();
    if(e<nE){
      #pragma unroll
      for(int p=0;p<4;p++){
        int col = p*16 + g;           // 0..63
        int a = h*64 + col;
        float acc=0.f;
        #pragma unroll
        for(int q=0;q<6;q++){
          uint2 v = ot[a*6+q];
          int widx = v.x & 0xffff, s = v.x>>16;
          acc += __uint_as_float(v.y) * h2f(Wt_h[e*WSTRIDE+widx]) * S_l[e*48+s];
        }
        ef_h[e*65 + col] = acc;
      }
    }
    __syncthreads();
    if(t<64){
      int ropos = T->aop[h*64+t];
      float acc=0.f;
      for(int e2=0;e2<TILE;e2++){
        int d = dst_t[e2];
        if(d>=0) acc += ef_h[e2*65+t];
        bool bnd = (e2==TILE-1) || (dst_t[e2+1]!=d);
        if(bnd){
          if(d>=0 && acc!=0.f) atomicAdd(&ef1[(size_t)d*160 + ropos], acc);
          acc=0.f;
        }
      }
    }
    __syncthreads();
  }
}

__global__ void k_gate(const float* __restrict__ ef1, float* __restrict__ xg, int N, float inv_nn){
  int n = blockIdx.x*256+threadIdx.x;
  if(n>=N) return;
  const float* v = ef1 + (size_t)n*160;
  float* o = xg + (size_t)n*128;
  float g[32];
  #pragma unroll
  for(int i=0;i<16;i++) o[i] = fmaxf(v[i]*inv_nn, 0.f);
  #pragma unroll
  for(int i=0;i<16;i++) o[16+i] = tanhf(v[16+i]*inv_nn);
  #pragma unroll
  for(int i=0;i<8;i++) g[i]    = fmaxf(v[32+i]*inv_nn,0.f);
  #pragma unroll
  for(int i=0;i<8;i++) g[8+i]  = tanhf(v[40+i]*inv_nn);
  #pragma unroll
  for(int i=0;i<8;i++) g[16+i] = fmaxf(v[48+i]*inv_nn,0.f);
  #pragma unroll
  for(int i=0;i<8;i++) g[24+i] = tanhf(v[56+i]*inv_nn);
  #pragma unroll
  for(int u=0;u<32;u++){
    float gu = g[u];
    #pragma unroll
    for(int k=0;k<3;k++) o[32+u*3+k] = v[64+u*3+k]*inv_nn*gu;
  }
}

// LDS layout (floats) for k_fc2_tp2 (512 threads):
//   sh_t @0 [32][17] | xg_t @544 [32][65] | emb_t @2624 [32][17]
//   Hbf @3168: us[32][268] = 4288 f (S_l aliases [32][33])
//   Wt2 @7456: f32 [32][36] = 1152 | bins @8608 (16)
#define F2_H    3168
#define F2_WT   7456
#define F2_BINS 8608
#define F2_TOT  8624

__global__ __launch_bounds__(512,6) void k_fc2_tp2(
    const float* __restrict__ pos, const int* __restrict__ esrc, const int* __restrict__ edst,
    const int* __restrict__ batch,
    const unsigned short* __restrict__ W1p, const unsigned short* __restrict__ B2,
    const float* __restrict__ xg, float* __restrict__ out,
    const TPTables* __restrict__ T, int E, float out_scale, int G)
{
  __shared__ __align__(16) float sm[F2_TOT];
  __shared__ int src_t[TILE], dst_t[TILE], g_t[TILE];
  float* sh_t  = sm;
  float* xg_t  = sm + 544;
  float* emb_t = sm + 2624;
  unsigned short* Hbf = (unsigned short*)(sm + F2_H);
  float* S_l   = sm + F2_H;
  float* Wt    = sm + F2_WT;
  float* bins  = sm + F2_BINS;
  int t = threadIdx.x;
  int e0 = blockIdx.x*TILE;
  int nE = min(TILE, E-e0);

  if(t<TILE){
    float embr[10];
    if(t<nE){
      int s=esrc[e0+t], d=edst[e0+t];
      src_t[t]=s; dst_t[t]=d; g_t[t]=batch[d];
      float ex=pos[3*d]-pos[3*s], ey=pos[3*d+1]-pos[3*s+1], ez=pos[3*d+2]-pos[3*s+2];
      float dd=sqrtf(ex*ex+ey*ey+ez*ez+1e-12f);
      sph16(ex/dd,ey/dd,ez/dd, &sh_t[t*17]);
      radial10(dd, embr);
    } else {
      src_t[t]=0; dst_t[t]=-1; g_t[t]=0;
      #pragma unroll
      for(int j=0;j<16;j++) sh_t[t*17+j]=0.f;
      #pragma unroll
      for(int b=0;b<10;b++) embr[b]=0.f;
    }
    #pragma unroll
    for(int b=0;b<10;b++) emb_t[t*17+b]=embr[b];
  } else if(t<TILE+16){
    bins[t-TILE]=0.f;
  }
  __syncthreads();
  for(int i=t;i<TILE*64;i+=512){
    int e=i>>6, j=i&63;
    xg_t[e*65+j] = xg[(size_t)src_t[e]*128 + (j<16? j : j+16)];
  }
  {
    int w = t>>6, lane = t&63, g2 = lane>>4, lr = lane&15;
    float af0[8], af1[8];
    #pragma unroll
    for(int s=0;s<8;s++){
      int k = g2*4 + (s&3) + ((s>>2)<<4);
      af0[s] = (k<10)? emb_t[lr*17+k] : 0.f;
      af1[s] = (k<10)? emb_t[(16+lr)*17+k] : 0.f;
    }
    union { f16x8 v; uint32_t w4[4]; } a0, a1;
    #pragma unroll
    for(int i=0;i<4;i++){
      a0.w4[i] = (uint32_t)f2h(af0[2*i]) | ((uint32_t)f2h(af0[2*i+1])<<16);
      a1.w4[i] = (uint32_t)f2h(af1[2*i]) | ((uint32_t)f2h(af1[2*i+1])<<16);
    }
    #pragma unroll
    for(int q=0;q<2;q++){
      int ct = w*2+q;
      f16x8 b = *(const f16x8*)(W1p + ((size_t)(ct*64+lane))*8);
      f32x4 z = {0.f,0.f,0.f,0.f};
      f32x4 c0 = __builtin_amdgcn_mfma_f32_16x16x32_f16(a0.v, b, z, 0,0,0);
      f32x4 c1 = __builtin_amdgcn_mfma_f32_16x16x32_f16(a1.v, b, z, 0,0,0);
      #pragma unroll
      for(int r=0;r<4;r++){
        Hbf[(g2*4+r)*HSTRIDE + ct*16+lr]    = f2h(fmaxf(c0[r],0.f));
        Hbf[(16+g2*4+r)*HSTRIDE + ct*16+lr] = f2h(fmaxf(c1[r],0.f));
      }
    }
  }
  __syncthreads();
  {
    int w = t>>6, lane = t&63, g2 = lane>>4, lr = lane&15;
    if(w<2){
      int ct = w;
      f32x4 acc0 = {0.f,0.f,0.f,0.f}, acc1 = {0.f,0.f,0.f,0.f};
      #pragma unroll
      for(int ks=0; ks<8; ks++){
        f16x8 b = *(const f16x8*)(B2 + ((size_t)(ct*8+ks)*64 + lane)*8);
        union { f16x8 v; uint32_t w4[4]; } a0, a1;
        const uint32_t* p0 = (const uint32_t*)(Hbf + lr*HSTRIDE + ks*32 + g2*4);
        const uint32_t* p1 = (const uint32_t*)(Hbf + (16+lr)*HSTRIDE + ks*32 + g2*4);
        a0.w4[0]=p0[0]; a0.w4[1]=p0[1]; a0.w4[2]=p0[8]; a0.w4[3]=p0[9];
        a1.w4[0]=p1[0]; a1.w4[1]=p1[1]; a1.w4[2]=p1[8]; a1.w4[3]=p1[9];
        acc0 = __builtin_amdgcn_mfma_f32_16x16x32_f16(a0.v, b, acc0, 0,0,0);
        acc1 = __builtin_amdgcn_mfma_f32_16x16x32_f16(a1.v, b, acc1, 0,0,0);
      }
      #pragma unroll
      for(int r=0;r<4;r++){
        Wt[(g2*4+r)*36 + ct*16+lr]    = acc0[r];
        Wt[(16+g2*4+r)*36 + ct*16+lr] = acc1[r];
      }
    }
  }
  __syncthreads();
  int e = t>>4, g = t&15;
  {
    const uint2* cgt = (const uint2*)T->cg2p;
    #pragma unroll
    for(int p=0;p<2;p++){
      int slot = p*16 + g;
      float acc=0.f;
      #pragma unroll
      for(int q=0;q<4;q++){
        uint2 v = cgt[slot*4+q];
        acc += __uint_as_float(v.y) * xg_t[e*65+(v.x&0xff)] * sh_t[e*17+((v.x>>8)&0xff)];
      }
      S_l[e*33+slot]=acc;
    }
  }
  __syncthreads();
  {
    const uint2* ot = (const uint2*)T->out2p;
    uint2 u0 = ot[2*g], u1 = ot[2*g+1];
    float v = __uint_as_float(u0.y) * Wt[e*36+(u0.x&0xffff)] * S_l[e*33+(u0.x>>16)]
            + __uint_as_float(u1.y) * Wt[e*36+(u1.x&0xffff)] * S_l[e*33+(u1.x>>16)];
    #pragma unroll
    for(int m=1;m<16;m<<=1) v += __shfl_xor(v, m, 64);
    if(g==0 && e<nE) atomicAdd(&bins[g_t[e]], v);
  }
  __syncthreads();
  if(t<G) atomicAdd(&out[t], bins[t]*out_scale);
}

// ---------------- launch ----------------
extern "C" void kernel_launch(void* const* d_in, const int* in_sizes, int n_in,
                              void* d_out, int out_size, void* d_ws, size_t ws_size,
                              hipStream_t stream) {
  const float* pos  = (const float*)d_in[0];
  const float* w11  = (const float*)d_in[1];
  const float* w12  = (const float*)d_in[2];
  const float* w21  = (const float*)d_in[3];
  const float* w22  = (const float*)d_in[4];
  const int*   esrc = (const int*)d_in[5];
  const int*   edst = (const int*)d_in[6];
  const int*   batch= (const int*)d_in[7];
  int E = in_sizes[5];
  int N = in_sizes[0]/3;
  int G = out_size;

  double nn = std::sqrt((double)E/(double)N);
  float inv_nn    = (float)(1.0/nn);
  float out_scale = (float)(1.0/(nn*std::sqrt((double)N)));

  float* ws = (float*)d_ws;
  float* x   = ws;
  float* ef1 = x   + (size_t)N*16;
  float* xg  = ef1 + (size_t)N*160;
  TPTables* dT = (TPTables*)(xg + (size_t)N*128);
  unsigned short* B1   = (unsigned short*)(((char*)dT) + ((sizeof(TPTables)+255)&~(size_t)255));
  unsigned short* B2   = B1 + NB1;
  unsigned short* W1p1 = B2 + NB2;
  unsigned short* W1p2 = W1p1 + NW1;
  int* deg    = (int*)(W1p2 + NW1);
  int* row    = deg + N;
  int* cursor = row + (N+1);
  int* perm   = cursor + N;

  static TPTables hT;
  build_tables(hT);
  hipMemcpyAsync(dT, &hT, sizeof(TPTables), hipMemcpyHostToDevice, stream);

  size_t nz = (size_t)N*16 + (size_t)N*160 + G + N;
  int zgrid = (int)((nz+255)/256); if(zgrid>2048) zgrid=2048;
  k_zero<<<zgrid,256,0,stream>>>(x, (size_t)N*16, ef1, (size_t)N*160, (float*)d_out, (size_t)G, deg, (size_t)N);
  k_deg<<<(E+255)/256,256,0,stream>>>(edst, deg, E);
  k_scan<<<1,1024,0,stream>>>(deg, row, cursor, N);
  k_fill<<<(E+255)/256,256,0,stream>>>(edst, row, cursor, perm, E);
  k_prep<<<(NB1+NB2+2*NW1+255)/256,256,0,stream>>>(w12, w22, w11, w21, B1, B2, W1p1, W1p2);
  k_edge_pre<<<(E+255)/256,256,0,stream>>>(pos, esrc, edst, perm, x, E);
  k_fc1_tp1<<<(E+TILE-1)/TILE,512,0,stream>>>(pos, esrc, edst, perm, W1p1, B1, x, ef1, dT, E, inv_nn);
  k_gate<<<(N+255)/256,256,0,stream>>>(ef1, xg, N, inv_nn);
  k_fc2_tp2<<<(E+TILE-1)/TILE,512,0,stream>>>(pos, esrc, edst, batch, W1p2, B2, xg,
                                              (float*)d_out, dT, E, out_scale, G);
}

// Round 7
// 938.278 us; speedup vs baseline: 6.6391x; 1.3858x over previous
//
#include <hip/hip_runtime.h>
#include <cmath>
#include <cstdint>
#include <cstring>
#include <cstdlib>
#include <vector>
#include <algorithm>
#include <complex>

#define TILE 32

typedef __attribute__((ext_vector_type(8))) _Float16 f16x8;
typedef __attribute__((ext_vector_type(4))) float f32x4;

// ------------------------------------------------------------------
// TP tables: trimmed cg [39][10] + overflow list; structural path
// tables for the out phase (fan 4/6/3 per class); alphas folded into W2.
// ------------------------------------------------------------------
struct TPTables {
  uint32_t cg1p[40*10*2];   // [slot][10] uint2 {prodidx(i*16+j), coefbits}
  uint32_t ovf[64*2];       // overflow: {prodidx | slot<<8, coefbits}
  int novf;
  uint32_t tabA[12];        // [grp(i3=0,2,4)][4 paths] = w0 | sbase<<16
  uint32_t tabB[6];         // i3=6 paths
  uint32_t tabC[3];         // i3=7 paths
  uint32_t cg2p[32*4*2];    // uint2 {i | j<<8, coefbits}
  uint32_t out2p[32];       // widx | s<<16
  float alpha1[272];
  float alpha2[32];
};

static double factd(int n){ double r=1; for(int i=2;i<=n;i++) r*=(double)i; return r; }

static double cg_complex(int j1,int m1,int j2,int m2,int j3,int m3){
  if(m1+m2!=m3) return 0.0;
  double pref = std::sqrt((2*j3+1)*factd(j3+j1-j2)*factd(j3-j1+j2)*factd(j1+j2-j3)/factd(j1+j2+j3+1));
  pref *= std::sqrt(factd(j3+m3)*factd(j3-m3)*factd(j1-m1)*factd(j1+m1)*factd(j2-m2)*factd(j2+m2));
  double s=0.0;
  for(int k=0;k<=j1+j2-j3;k++){
    int dd[6] = {k, j1+j2-j3-k, j1-m1-k, j2+m2-k, j3-j2+m1+k, j3-j1-m2+k};
    bool ok=true; double prod=1.0;
    for(int t=0;t<6;t++){ if(dd[t]<0){ok=false;break;} prod*=factd(dd[t]); }
    if(!ok) continue;
    s += ((k&1)?-1.0:1.0)/prod;
  }
  return pref*s;
}

typedef std::complex<double> cd;
static void real_U(int l, cd* U){
  int n = 2*l+1;
  for(int i=0;i<n*n;i++) U[i]=cd(0,0);
  U[l*n+l] = cd(1,0);
  for(int m=1;m<=l;m++){
    double sgn = (m&1)? -1.0 : 1.0;
    double is2 = 1.0/std::sqrt(2.0);
    U[(l+m)*n + (l+m)] = cd(sgn*is2,0);
    U[(l+m)*n + (l-m)] = cd(is2,0);
    U[(l-m)*n + (l+m)] = cd(0,-sgn*is2);
    U[(l-m)*n + (l-m)] = cd(0,is2);
  }
}

static void real_cg_h(int l1,int l2,int l3, double* out){
  int n1=2*l1+1,n2=2*l2+1,n3=2*l3+1;
  std::vector<cd> C(n1*n2*n3);
  for(int a=-l1;a<=l1;a++)for(int b=-l2;b<=l2;b++)for(int c=-l3;c<=l3;c++)
    C[(size_t)((a+l1)*n2+(b+l2))*n3+(c+l3)] = cd(cg_complex(l1,a,l2,b,l3,c),0);
  std::vector<cd> U1(n1*n1),U2(n2*n2),U3(n3*n3);
  real_U(l1,U1.data()); real_U(l2,U2.data()); real_U(l3,U3.data());
  std::vector<cd> T((size_t)n1*n2*n3, cd(0,0));
  for(int i=0;i<n1;i++)for(int j=0;j<n2;j++)for(int k=0;k<n3;k++){
    cd acc(0,0);
    for(int a=0;a<n1;a++){ cd u1=U1[i*n1+a]; if(u1==cd(0,0)) continue;
      for(int b=0;b<n2;b++){ cd u2=U2[j*n2+b]; if(u2==cd(0,0)) continue;
        for(int c=0;c<n3;c++){ cd u3=std::conj(U3[k*n3+c]); if(u3==cd(0,0)) continue;
          acc += u1*u2*u3*C[(size_t)(a*n2+b)*n3+c];
        } } }
    T[(size_t)(i*n2+j)*n3+k]=acc;
  }
  double sr=0, si=0;
  for(auto&z:T){ sr += std::fabs(z.real()); si += std::fabs(z.imag()); }
  int tot=n1*n2*n3;
  std::vector<double> R(tot);
  for(int i=0;i<tot;i++) R[i] = (sr>=si)? T[i].real() : T[i].imag();
  double nrm=0; for(double v:R) nrm += v*v; nrm = std::sqrt(nrm);
  for(int i=0;i<tot;i++) out[i] = R[i]/nrm;
}

struct HIrr{int m,l,p;};
static int map_id(int i){return i;}
static int map_gate(int i){return (i<16)? i : i-16;}

static void build_one(const std::vector<HIrr>& ir1, const std::vector<HIrr>& ir2,
                      const std::vector<HIrr>& ir3, int (*map1)(int),
                      std::vector<uint32_t>& cg_pk, std::vector<float>& cg_c,
                      std::vector<uint32_t>& out_pk, std::vector<float>& out_c)
{
  int n1=(int)ir1.size(), n2=(int)ir2.size(), n3=(int)ir3.size();
  std::vector<int> s1(n1), s2(n2), s3(n3);
  { int o=0; for(int i=0;i<n1;i++){ s1[i]=o; o+=ir1[i].m*(2*ir1[i].l+1);} }
  { int o=0; for(int i=0;i<n2;i++){ s2[i]=o; o+=ir2[i].m*(2*ir2[i].l+1);} }
  { int o=0; for(int i=0;i<n3;i++){ s3[i]=o; o+=ir3[i].m*(2*ir3[i].l+1);} }
  struct Inst{int i1,i2,i3,w0;};
  std::vector<Inst> insts; int woff=0;
  for(int i1=0;i1<n1;i1++)for(int i2=0;i2<n2;i2++)for(int i3=0;i3<n3;i3++){
    const HIrr&A=ir1[i1];const HIrr&B=ir2[i2];const HIrr&C=ir3[i3];
    int dl = A.l-B.l; if(dl<0) dl=-dl;
    if(A.p*B.p==C.p && dl<=C.l && C.l<=A.l+B.l){
      insts.push_back({i1,i2,i3,woff}); woff += A.m*B.m*C.m;
    }
  }
  std::vector<int> fan(n3,0);
  for(auto&P:insts) fan[P.i3] += ir1[P.i1].m*ir2[P.i2].m;
  int sbase=0;
  for(auto&P:insts){
    const HIrr&A=ir1[P.i1];const HIrr&B=ir2[P.i2];const HIrr&C=ir3[P.i3];
    int d1=2*A.l+1,d2=2*B.l+1,d3=2*C.l+1;
    double cg[343];
    real_cg_h(A.l,B.l,C.l,cg);
    double alpha = std::sqrt((double)d3/(double)fan[P.i3]);
    for(int u=0;u<A.m;u++)for(int v=0;v<B.m;v++){
      for(int k=0;k<d3;k++)
        for(int i=0;i<d1;i++)for(int j=0;j<d2;j++){
          double c = cg[(i*d2+j)*d3+k];
          if(std::fabs(c)<1e-8) continue;
          int iabs = map1(s1[P.i1]+u*d1+i);
          int jabs = s2[P.i2]+v*d2+j;
          cg_pk.push_back((uint32_t)iabs | ((uint32_t)jabs<<8) | ((uint32_t)(sbase+k)<<16));
          cg_c.push_back((float)c);
        }
      for(int w=0;w<C.m;w++)for(int k=0;k<d3;k++){
        out_pk.push_back((uint32_t)(s3[P.i3]+w*d3+k) | ((uint32_t)(P.w0+(u*B.m+v)*C.m+w)<<8) | ((uint32_t)(sbase+k)<<20));
        out_c.push_back((float)alpha);
      }
      sbase += d3;
    }
  }
}

static uint32_t fbits(float f){ uint32_t u; memcpy(&u,&f,4); return u; }

static void build_tables(TPTables& T){
  std::vector<HIrr> IR_SH   ={{1,0,1},{1,1,-1},{1,2,1},{1,3,-1}};
  std::vector<HIrr> GATE_IN ={{16,0,1},{16,0,-1},{8,0,1},{8,0,-1},{8,0,1},{8,0,-1},{16,1,-1},{16,1,1}};
  std::vector<HIrr> GATE_OUT={{16,0,1},{16,0,-1},{16,1,-1},{16,1,1}};
  std::vector<HIrr> IR_OUT  ={{1,0,1}};
  std::vector<uint32_t> cg1,o1,cg2,o2; std::vector<float> cg1c,o1c,cg2c,o2c;
  build_one(IR_SH,IR_SH,GATE_IN,map_id,cg1,cg1c,o1,o1c);
  build_one(GATE_OUT,IR_SH,IR_OUT,map_gate,cg2,cg2c,o2,o2c);
  memset(&T,0,sizeof(T));
  {
    int cnt[40]; memset(cnt,0,sizeof(cnt));
    for(size_t idx=0; idx<cg1.size(); ++idx){
      int i = cg1[idx]&0xff, j=(cg1[idx]>>8)&0xff, s=(int)(cg1[idx]>>16);
      uint32_t pidx = (uint32_t)(i*16+j);
      if(s<40 && cnt[s]<10){
        T.cg1p[(s*10+cnt[s])*2]   = pidx;
        T.cg1p[(s*10+cnt[s])*2+1] = fbits(cg1c[idx]);
        cnt[s]++;
      } else if(T.novf<64){
        T.ovf[T.novf*2]   = pidx | ((uint32_t)s<<8);
        T.ovf[T.novf*2+1] = fbits(cg1c[idx]);
        T.novf++;
      }
    }
  }
  {
    int GIl[8]={0,0,0,0,0,0,1,1}, GIp[8]={1,-1,1,-1,1,-1,-1,1}, GIm[8]={16,16,8,8,8,8,16,16};
    int SHl[4]={0,1,2,3}, SHp[4]={1,-1,1,-1};
    int w0=0, sb=0, nA0=0,nA1=0,nA2=0,nB=0,nC=0;
    for(int i1=0;i1<4;i1++)for(int i2=0;i2<4;i2++)for(int i3=0;i3<8;i3++){
      int dl=SHl[i1]-SHl[i2]; if(dl<0) dl=-dl;
      if(SHp[i1]*SHp[i2]==GIp[i3] && dl<=GIl[i3] && GIl[i3]<=SHl[i1]+SHl[i2]){
        uint32_t ent = (uint32_t)w0 | ((uint32_t)sb<<16);
        if(i3==0 && nA0<4) T.tabA[nA0++] = ent;
        else if(i3==2 && nA1<4) T.tabA[4+nA1++] = ent;
        else if(i3==4 && nA2<4) T.tabA[8+nA2++] = ent;
        else if(i3==6 && nB<6) T.tabB[nB++] = ent;
        else if(i3==7 && nC<3) T.tabC[nC++] = ent;
        w0 += GIm[i3];
        sb += 2*GIl[i3]+1;
      }
    }
  }
  for(size_t idx=0; idx<o1.size(); ++idx){
    int widx = (o1[idx]>>8)&0xfff;
    if(widx<272) T.alpha1[widx] = o1c[idx];
  }
  {
    int cnt[32]; memset(cnt,0,sizeof(cnt));
    for(size_t idx=0; idx<cg2.size(); ++idx){
      int s = (int)(cg2[idx]>>16);
      if(s<32 && cnt[s]<4){
        T.cg2p[(s*4+cnt[s])*2]   = cg2[idx]&0xFFFF;
        T.cg2p[(s*4+cnt[s])*2+1] = fbits(cg2c[idx]);
        cnt[s]++;
      }
    }
  }
  for(size_t idx=0; idx<o2.size() && idx<32; ++idx){
    int widx = (o2[idx]>>8)&0xfff;
    int s    = (int)(o2[idx]>>20);
    T.out2p[idx] = (uint32_t)widx | ((uint32_t)s<<16);
    if(widx<32) T.alpha2[widx] = o2c[idx];
  }
}

// ---------------- device helpers ----------------
__device__ __forceinline__ unsigned short f2h(float f){
  _Float16 h = (_Float16)f;
  unsigned short u; __builtin_memcpy(&u, &h, 2); return u;
}
__device__ __forceinline__ float h2f(unsigned short u){
  _Float16 h; __builtin_memcpy(&h, &u, 2); return (float)h;
}

__device__ __forceinline__ void sph16(float x,float y,float z,float* sh){
  float x2=x*x, y2=y*y, z2=z*z;
  const float SQ3=1.7320508075688772f, SQ5=2.23606797749979f, SQ7=2.6457513110645907f;
  const float SQ15=3.872983346207417f, SQ42=6.48074069840786f, SQ70=8.366600265340756f, SQ105=10.246950765959598f;
  sh[0]=1.f;
  sh[1]=SQ3*y;  sh[2]=SQ3*z;  sh[3]=SQ3*x;
  sh[4]=SQ15*x*y; sh[5]=SQ15*y*z; sh[6]=0.5f*SQ5*(3.f*z2-1.f); sh[7]=SQ15*x*z; sh[8]=0.5f*SQ15*(x2-y2);
  sh[9]=0.25f*SQ70*y*(3.f*x2-y2); sh[10]=SQ105*x*y*z; sh[11]=0.25f*SQ42*y*(5.f*z2-1.f);
  sh[12]=0.5f*SQ7*z*(5.f*z2-3.f); sh[13]=0.25f*SQ42*x*(5.f*z2-1.f);
  sh[14]=0.5f*SQ105*z*(x2-y2);    sh[15]=0.25f*SQ70*x*(x2-3.f*y2);
}

__device__ __forceinline__ void radial10(float d, float* emb){
  const float step = 0.2909090909090909f;
  #pragma unroll
  for(int b=0;b<10;b++){
    float c = step*(float)(b+1);
    float u = (d-c)/step;
    float u2 = u*u;
    float f = 0.f;
    if(u2<1.f) f = 1.14136f*__expf(-u2/fmaxf(1.f-u2,1e-6f));
    emb[b] = f*3.1622776601683795f;
  }
}

// ---------------- kernels ----------------
__global__ void k_zero(float* a, size_t na, float* b, size_t nb, float* c, size_t nc,
                       int* d, size_t nd){
  size_t total = na+nb+nc+nd;
  for(size_t i = (size_t)blockIdx.x*blockDim.x+threadIdx.x; i<total; i += (size_t)gridDim.x*blockDim.x){
    if(i<na) a[i]=0.f;
    else if(i<na+nb) b[i-na]=0.f;
    else if(i<na+nb+nc) c[i-na-nb]=0.f;
    else d[i-na-nb-nc]=0;
  }
}

__global__ void k_deg(const int* __restrict__ edst, int* __restrict__ deg, int E){
  int e = blockIdx.x*256 + threadIdx.x;
  if(e<E) atomicAdd(&deg[edst[e]], 1);
}

__global__ __launch_bounds__(1024) void k_scan(const int* __restrict__ deg, int* __restrict__ row,
                                               int* __restrict__ cursor, int N){
  __shared__ int buf[2][1024];
  __shared__ int carry;
  int t = threadIdx.x;
  if(t==0) carry=0;
  __syncthreads();
  for(int base=0; base<N; base+=1024){
    int i = base+t;
    int v = (i<N)? deg[i] : 0;
    int cur=0;
    buf[0][t]=v; __syncthreads();
    for(int off=1; off<1024; off<<=1){
      int val = buf[cur][t];
      if(t>=off) val += buf[cur][t-off];
      buf[cur^1][t]=val; __syncthreads();
      cur^=1;
    }
    if(i<N) row[i] = carry + buf[cur][t] - v;
    int tot = buf[cur][1023];
    __syncthreads();
    if(t==0) carry += tot;
    __syncthreads();
  }
  if(t==0) row[N]=carry;
  for(int i=t;i<N;i+=1024) cursor[i]=0;
}

__global__ void k_fill(const int* __restrict__ edst, const int* __restrict__ row,
                       int* __restrict__ cursor, int* __restrict__ perm, int E){
  int e = blockIdx.x*256 + threadIdx.x;
  if(e<E){
    int d = edst[e];
    int p = atomicAdd(&cursor[d], 1);
    perm[row[d]+p] = e;
  }
}

#define NB1 (17*8*64*8)
#define NB2 (2*8*64*8)
#define NW1 (16*64*8)
__global__ void k_prep(const float* __restrict__ W2a, const float* __restrict__ W2b,
                       const float* __restrict__ W1a, const float* __restrict__ W1b,
                       unsigned short* __restrict__ B1, unsigned short* __restrict__ B2,
                       unsigned short* __restrict__ W1p1, unsigned short* __restrict__ W1p2,
                       const TPTables* __restrict__ T){
  int i = blockIdx.x*256 + threadIdx.x;
  if(i < NB1){
    int s = i&7, lane = (i>>3)&63, ks = (i>>9)&7, ct = i>>12;
    int g = lane>>4;
    int k = ks*32 + g*4 + (s&3) + ((s>>2)<<4);
    int c = ct*16 + (lane&15);
    B1[i] = f2h(W2a[k*272+c]*0.0625f*T->alpha1[c]);
  } else if(i < NB1+NB2){
    int j = i - NB1;
    int s = j&7, lane = (j>>3)&63, ks = (j>>9)&7, ct = j>>12;
    int g = lane>>4;
    int k = ks*32 + g*4 + (s&3) + ((s>>2)<<4);
    int c = ct*16 + (lane&15);
    B2[j] = f2h(W2b[k*32+c]*0.0625f*T->alpha2[c]);
  } else if(i < NB1+NB2+NW1){
    int j = i - NB1 - NB2;
    int s = j&7, lane = (j>>3)&63, ct = j>>9;
    int g = lane>>4;
    int k = g*4 + (s&3) + ((s>>2)<<4);
    int c = ct*16 + (lane&15);
    W1p1[j] = (k<10)? f2h(W1a[k*256+c]*0.4472135954999579f) : (unsigned short)0;
  } else if(i < NB1+NB2+2*NW1){
    int j = i - NB1 - NB2 - NW1;
    int s = j&7, lane = (j>>3)&63, ct = j>>9;
    int g = lane>>4;
    int k = g*4 + (s&3) + ((s>>2)<<4);
    int c = ct*16 + (lane&15);
    W1p2[j] = (k<10)? f2h(W1b[k*256+c]*0.4472135954999579f) : (unsigned short)0;
  }
}

__global__ __launch_bounds__(256) void k_edge_pre(
    const float* __restrict__ pos, const int* __restrict__ esrc, const int* __restrict__ edst,
    const int* __restrict__ perm, float* __restrict__ x, int E){
  __shared__ float shs[256*17];
  __shared__ int dsts[256];
  int t = threadIdx.x;
  int idx = blockIdx.x*256 + t;
  int d = -1;
  if(idx<E){
    int e = perm[idx];
    int s = esrc[e]; d = edst[e];
    float ex=pos[3*d]-pos[3*s], ey=pos[3*d+1]-pos[3*s+1], ez=pos[3*d+2]-pos[3*s+2];
    float dd = sqrtf(ex*ex+ey*ey+ez*ez+1e-12f);
    sph16(ex/dd, ey/dd, ez/dd, &shs[t*17]);
  }
  dsts[t] = d;
  __syncthreads();
  bool leader = (d>=0) && (t==0 || dsts[t-1]!=d);
  if(leader){
    int len=1;
    while(t+len<256 && dsts[t+len]==d) len++;
    #pragma unroll
    for(int j=0;j<16;j++){
      float a=0.f;
      for(int k=0;k<len;k++) a += shs[(t+k)*17+j];
      atomicAdd(&x[(size_t)d*16+j], a);
    }
  }
}

// LDS (floats) k_fc1_tp1 (512 threads):
//   sh_t @0 [32][17] | x1_t @544 | emb_t @1088 -> 1632
//   Wt_h @1632 us[32][272] (4352f) -> 5984
//   AFh @5984: H-frags us[2][8][64][8]=8192us; P us[32][264]=8448us (4224f) -> 10208
//   S16 @10208 us[32][40]=1280us (640f) -> 10848
//   ef @10848 [32][65]=2080f -> 12928
#define F1_WT 1632
#define F1_AF 5984
#define F1_S  10208
#define F1_EF 10848
#define F1_TOT 12928

__global__ __launch_bounds__(512,6) void k_fc1_tp1(
    const float* __restrict__ pos, const int* __restrict__ esrc, const int* __restrict__ edst,
    const int* __restrict__ perm,
    const unsigned short* __restrict__ W1p, const unsigned short* __restrict__ B1,
    const float* __restrict__ xnode, float* __restrict__ ef1,
    const TPTables* __restrict__ T, int E, float inv_nn)
{
  __shared__ __align__(16) float sm[F1_TOT];
  __shared__ int src_t[TILE], dst_t[TILE];
  float* sh_t  = sm;
  float* x1_t  = sm + 544;
  float* emb_t = sm + 1088;
  unsigned short* Wt_h = (unsigned short*)(sm + F1_WT);
  unsigned short* AFh  = (unsigned short*)(sm + F1_AF);
  unsigned short* S16h = (unsigned short*)(sm + F1_S);
  float* ef_h = sm + F1_EF;
  int t = threadIdx.x;
  int e0 = blockIdx.x*TILE;
  int nE = min(TILE, E-e0);
  int e = t>>4, g = t&15, w = t>>6, lane = t&63;
  int g2 = lane>>4, lr = lane&15;

  if(t<TILE){
    float embr[10];
    if(t<nE){
      int e2 = perm[e0+t];
      int s=esrc[e2], d=edst[e2];
      src_t[t]=s; dst_t[t]=d;
      float ex=pos[3*d]-pos[3*s], ey=pos[3*d+1]-pos[3*s+1], ez=pos[3*d+2]-pos[3*s+2];
      float dd=sqrtf(ex*ex+ey*ey+ez*ez+1e-12f);
      sph16(ex/dd,ey/dd,ez/dd, &sh_t[t*17]);
      radial10(dd, embr);
    } else {
      src_t[t]=0; dst_t[t]=-1;
      #pragma unroll
      for(int j=0;j<16;j++) sh_t[t*17+j]=0.f;
      #pragma unroll
      for(int b=0;b<10;b++) embr[b]=0.f;
    }
    #pragma unroll
    for(int b=0;b<10;b++) emb_t[t*17+b]=embr[b];
  }
  __syncthreads();
  x1_t[e*17+g] = xnode[(size_t)src_t[e]*16+g]*inv_nn;
  // ph1: H = relu(emb @ W1p) -> A-fragment-major LDS
  {
    float af0[8], af1[8];
    #pragma unroll
    for(int s=0;s<8;s++){
      int k = g2*4 + (s&3) + ((s>>2)<<4);
      af0[s] = (k<10)? emb_t[lr*17+k] : 0.f;
      af1[s] = (k<10)? emb_t[(16+lr)*17+k] : 0.f;
    }
    union { f16x8 v; uint32_t w4[4]; } a0u, a1u;
    #pragma unroll
    for(int i=0;i<4;i++){
      a0u.w4[i] = (uint32_t)f2h(af0[2*i]) | ((uint32_t)f2h(af0[2*i+1])<<16);
      a1u.w4[i] = (uint32_t)f2h(af1[2*i]) | ((uint32_t)f2h(af1[2*i+1])<<16);
    }
    #pragma unroll
    for(int q=0;q<2;q++){
      int ct = w*2+q;
      f16x8 b = *(const f16x8*)(W1p + ((size_t)(ct*64+lane))*8);
      f32x4 z = {0.f,0.f,0.f,0.f};
      f32x4 c0 = __builtin_amdgcn_mfma_f32_16x16x32_f16(a0u.v, b, z, 0,0,0);
      f32x4 c1 = __builtin_amdgcn_mfma_f32_16x16x32_f16(a1u.v, b, z, 0,0,0);
      int ks = ct>>1, sp = (lr&3)|((ct&1)<<2);
      #pragma unroll
      for(int r=0;r<4;r++){
        int lnp = ((lr>>2)<<4) + (g2<<2) + r;
        AFh[(ks*64+lnp)*8+sp]     = f2h(fmaxf(c0[r],0.f));
        AFh[((8+ks)*64+lnp)*8+sp] = f2h(fmaxf(c1[r],0.f));
      }
    }
  }
  __syncthreads();
  // ph2: W = H @ B1
  {
    for(int ct=w; ct<17; ct+=8){
      f32x4 acc0 = {0.f,0.f,0.f,0.f}, acc1 = {0.f,0.f,0.f,0.f};
      #pragma unroll
      for(int ks=0;ks<8;ks++){
        f16x8 b  = *(const f16x8*)(B1 + ((size_t)(ct*8+ks)*64 + lane)*8);
        f16x8 a0 = *(const f16x8*)(AFh + (ks*64+lane)*8);
        f16x8 a1 = *(const f16x8*)(AFh + ((8+ks)*64+lane)*8);
        acc0 = __builtin_amdgcn_mfma_f32_16x16x32_f16(a0, b, acc0, 0,0,0);
        acc1 = __builtin_amdgcn_mfma_f32_16x16x32_f16(a1, b, acc1, 0,0,0);
      }
      #pragma unroll
      for(int r=0;r<4;r++){
        Wt_h[(g2*4+r)*272 + ct*16+lr]    = f2h(acc0[r]);
        Wt_h[(16+g2*4+r)*272 + ct*16+lr] = f2h(acc1[r]);
      }
    }
  }
  __syncthreads();
  // ph3: outer products P[i][j] = x1[i]*sh[j]
  {
    float xv = x1_t[e*17+g];
    float shv[16];
    #pragma unroll
    for(int j=0;j<16;j++) shv[j]=sh_t[e*17+j];
    uint32_t* dst = (uint32_t*)AFh + e*132 + g*8;
    #pragma unroll
    for(int jp=0;jp<8;jp++)
      dst[jp] = (uint32_t)f2h(xv*shv[2*jp]) | ((uint32_t)f2h(xv*shv[2*jp+1])<<16);
  }
  __syncthreads();
  // ph4: cg contraction
  {
    const uint2* cgt = (const uint2*)T->cg1p;
    #pragma unroll
    for(int p=0;p<3;p++){
      int slot = p*16+g;
      if(slot<39){
        float acc=0.f;
        #pragma unroll
        for(int q=0;q<10;q++){
          uint2 v = cgt[slot*10+q];
          acc += __uint_as_float(v.y) * h2f(AFh[e*264 + (v.x&0xff)]);
        }
        S16h[e*40+slot] = f2h(acc);
      }
    }
  }
  __syncthreads();
  if(t<TILE){
    int n = T->novf;
    for(int o=0;o<n;o++){
      uint2 v = ((const uint2*)T->ovf)[o];
      int slot = (v.x>>8)&0xff;
      S16h[t*40+slot] = f2h(h2f(S16h[t*40+slot]) + __uint_as_float(v.y)*h2f(AFh[t*264+(v.x&0xff)]));
    }
  }
  __syncthreads();
  // ph5: out phase
  float a0=0.f, a1=0.f, accB[3]={0.f,0.f,0.f}, accC[3]={0.f,0.f,0.f};
  {
    int grp = (g>=8)+(g>=12);
    int base = (grp==0)?0:((grp==1)?16:24);
    int ol = g*2 - base;
    #pragma unroll
    for(int p=0;p<4;p++){
      uint32_t v = T->tabA[grp*4+p];
      int w0 = v&0xffff, sb = v>>16;
      float Sv = h2f(S16h[e*40+sb]);
      uint32_t wp = *(const uint32_t*)(Wt_h + e*272 + w0 + ol);
      a0 += h2f((unsigned short)(wp&0xffff))*Sv;
      a1 += h2f((unsigned short)(wp>>16))*Sv;
    }
    #pragma unroll
    for(int p=0;p<6;p++){
      uint32_t v = T->tabB[p];
      int w0 = v&0xffff, sb = v>>16;
      float Wv = h2f(Wt_h[e*272 + w0 + g]);
      accB[0] += Wv*h2f(S16h[e*40+sb]);
      accB[1] += Wv*h2f(S16h[e*40+sb+1]);
      accB[2] += Wv*h2f(S16h[e*40+sb+2]);
    }
    #pragma unroll
    for(int p=0;p<3;p++){
      uint32_t v = T->tabC[p];
      int w0 = v&0xffff, sb = v>>16;
      float Wv = h2f(Wt_h[e*272 + w0 + g]);
      accC[0] += Wv*h2f(S16h[e*40+sb]);
      accC[1] += Wv*h2f(S16h[e*40+sb+1]);
      accC[2] += Wv*h2f(S16h[e*40+sb+2]);
    }
  }
  #pragma unroll
  for(int h=0; h<2; h++){
    for(int i=t;i<TILE*65;i+=512) ef_h[i]=0.f;
    __syncthreads();
    if(h==0){
      ef_h[e*65 + g*2]   = a0;
      ef_h[e*65 + g*2+1] = a1;
      #pragma unroll
      for(int k=0;k<3;k++){
        int b = g*3+k;
        if(b<32) ef_h[e*65 + 32+b] = accB[k];
      }
    } else {
      #pragma unroll
      for(int k=0;k<3;k++){
        int b = g*3+k;
        if(b>=32) ef_h[e*65 + (b-32)] = accB[k];
      }
      #pragma unroll
      for(int k=0;k<3;k++)
        ef_h[e*65 + 16 + g*3+k] = accC[k];
    }
    __syncthreads();
    if(t<64){
      int rank = h*64+t;
      int opos = rank<16? rank : rank<24? rank+16 : rank<32? rank+24 : rank+32;
      float acc=0.f;
      for(int e2=0;e2<TILE;e2++){
        int d = dst_t[e2];
        if(d>=0) acc += ef_h[e2*65+t];
        bool bnd = (e2==TILE-1) || (dst_t[e2+1]!=d);
        if(bnd){
          if(d>=0 && acc!=0.f) atomicAdd(&ef1[(size_t)d*160 + opos], acc);
          acc=0.f;
        }
      }
    }
    __syncthreads();
  }
}

__global__ void k_gate(const float* __restrict__ ef1, float* __restrict__ xg, int N, float inv_nn){
  int n = blockIdx.x*256+threadIdx.x;
  if(n>=N) return;
  const float* v = ef1 + (size_t)n*160;
  float* o = xg + (size_t)n*128;
  float g[32];
  #pragma unroll
  for(int i=0;i<16;i++) o[i] = fmaxf(v[i]*inv_nn, 0.f);
  #pragma unroll
  for(int i=0;i<16;i++) o[16+i] = tanhf(v[16+i]*inv_nn);
  #pragma unroll
  for(int i=0;i<8;i++) g[i]    = fmaxf(v[32+i]*inv_nn,0.f);
  #pragma unroll
  for(int i=0;i<8;i++) g[8+i]  = tanhf(v[40+i]*inv_nn);
  #pragma unroll
  for(int i=0;i<8;i++) g[16+i] = fmaxf(v[48+i]*inv_nn,0.f);
  #pragma unroll
  for(int i=0;i<8;i++) g[24+i] = tanhf(v[56+i]*inv_nn);
  #pragma unroll
  for(int u=0;u<32;u++){
    float gu = g[u];
    #pragma unroll
    for(int k=0;k<3;k++) o[32+u*3+k] = v[64+u*3+k]*inv_nn*gu;
  }
}

// LDS (floats) k_fc2_tp2 (512 threads):
//   sh @0 544 | emb @544 -> 1088 | xg @1088 [32][65] 2080 -> 3168
//   Wt @3168 f32[32][36] 1152 -> 4320
//   AF @4320 4096f (S_l f32 [32][33]=1056 aliases) -> 8416 | bins @8416 16
#define F2_WT 3168
#define F2_AF 4320
#define F2_BINS 8416
#define F2_TOT 8432

__global__ __launch_bounds__(512,6) void k_fc2_tp2(
    const float* __restrict__ pos, const int* __restrict__ esrc, const int* __restrict__ edst,
    const int* __restrict__ perm, const int* __restrict__ batch,
    const unsigned short* __restrict__ W1p, const unsigned short* __restrict__ B2,
    const float* __restrict__ xg, float* __restrict__ out,
    const TPTables* __restrict__ T, int E, float out_scale, int G)
{
  __shared__ __align__(16) float sm[F2_TOT];
  __shared__ int src_t[TILE], dst_t[TILE], g_t[TILE];
  float* sh_t  = sm;
  float* emb_t = sm + 544;
  float* xg_t  = sm + 1088;
  float* Wt    = sm + F2_WT;
  unsigned short* AFh = (unsigned short*)(sm + F2_AF);
  float* S_l  = sm + F2_AF;
  float* bins = sm + F2_BINS;
  int t = threadIdx.x;
  int e0 = blockIdx.x*TILE;
  int nE = min(TILE, E-e0);
  int e = t>>4, g = t&15, w = t>>6, lane = t&63;
  int g2 = lane>>4, lr = lane&15;

  if(t<TILE){
    float embr[10];
    if(t<nE){
      int e2 = perm[e0+t];
      int s=esrc[e2], d=edst[e2];
      src_t[t]=s; dst_t[t]=d; g_t[t]=batch[d];
      float ex=pos[3*d]-pos[3*s], ey=pos[3*d+1]-pos[3*s+1], ez=pos[3*d+2]-pos[3*s+2];
      float dd=sqrtf(ex*ex+ey*ey+ez*ez+1e-12f);
      sph16(ex/dd,ey/dd,ez/dd, &sh_t[t*17]);
      radial10(dd, embr);
    } else {
      src_t[t]=0; dst_t[t]=-1; g_t[t]=0;
      #pragma unroll
      for(int j=0;j<16;j++) sh_t[t*17+j]=0.f;
      #pragma unroll
      for(int b=0;b<10;b++) embr[b]=0.f;
    }
    #pragma unroll
    for(int b=0;b<10;b++) emb_t[t*17+b]=embr[b];
  } else if(t<TILE+16){
    bins[t-TILE]=0.f;
  }
  __syncthreads();
  #pragma unroll
  for(int rep=0;rep<4;rep++){
    int j = g + rep*16;
    xg_t[e*65+j] = xg[(size_t)src_t[e]*128 + (j<16? j : j+16)];
  }
  {
    float af0[8], af1[8];
    #pragma unroll
    for(int s=0;s<8;s++){
      int k = g2*4 + (s&3) + ((s>>2)<<4);
      af0[s] = (k<10)? emb_t[lr*17+k] : 0.f;
      af1[s] = (k<10)? emb_t[(16+lr)*17+k] : 0.f;
    }
    union { f16x8 v; uint32_t w4[4]; } a0u, a1u;
    #pragma unroll
    for(int i=0;i<4;i++){
      a0u.w4[i] = (uint32_t)f2h(af0[2*i]) | ((uint32_t)f2h(af0[2*i+1])<<16);
      a1u.w4[i] = (uint32_t)f2h(af1[2*i]) | ((uint32_t)f2h(af1[2*i+1])<<16);
    }
    #pragma unroll
    for(int q=0;q<2;q++){
      int ct = w*2+q;
      f16x8 b = *(const f16x8*)(W1p + ((size_t)(ct*64+lane))*8);
      f32x4 z = {0.f,0.f,0.f,0.f};
      f32x4 c0 = __builtin_amdgcn_mfma_f32_16x16x32_f16(a0u.v, b, z, 0,0,0);
      f32x4 c1 = __builtin_amdgcn_mfma_f32_16x16x32_f16(a1u.v, b, z, 0,0,0);
      int ks = ct>>1, sp = (lr&3)|((ct&1)<<2);
      #pragma unroll
      for(int r=0;r<4;r++){
        int lnp = ((lr>>2)<<4) + (g2<<2) + r;
        AFh[(ks*64+lnp)*8+sp]     = f2h(fmaxf(c0[r],0.f));
        AFh[((8+ks)*64+lnp)*8+sp] = f2h(fmaxf(c1[r],0.f));
      }
    }
  }
  __syncthreads();
  {
    if(w<2){
      int ct = w;
      f32x4 acc0 = {0.f,0.f,0.f,0.f}, acc1 = {0.f,0.f,0.f,0.f};
      #pragma unroll
      for(int ks=0;ks<8;ks++){
        f16x8 b  = *(const f16x8*)(B2 + ((size_t)(ct*8+ks)*64 + lane)*8);
        f16x8 a0 = *(const f16x8*)(AFh + (ks*64+lane)*8);
        f16x8 a1 = *(const f16x8*)(AFh + ((8+ks)*64+lane)*8);
        acc0 = __builtin_amdgcn_mfma_f32_16x16x32_f16(a0, b, acc0, 0,0,0);
        acc1 = __builtin_amdgcn_mfma_f32_16x16x32_f16(a1, b, acc1, 0,0,0);
      }
      #pragma unroll
      for(int r=0;r<4;r++){
        Wt[(g2*4+r)*36 + ct*16+lr]    = acc0[r];
        Wt[(16+g2*4+r)*36 + ct*16+lr] = acc1[r];
      }
    }
  }
  __syncthreads();
  {
    const uint2* cgt = (const uint2*)T->cg2p;
    #pragma unroll
    for(int p=0;p<2;p++){
      int slot = p*16 + g;
      float acc=0.f;
      #pragma unroll
      for(int q=0;q<4;q++){
        uint2 v = cgt[slot*4+q];
        acc += __uint_as_float(v.y) * xg_t[e*65+(v.x&0xff)] * sh_t[e*17+((v.x>>8)&0xff)];
      }
      S_l[e*33+slot]=acc;
    }
  }
  __syncthreads();
  {
    uint32_t u0 = T->out2p[2*g], u1 = T->out2p[2*g+1];
    float v = Wt[e*36+(u0&0xffff)] * S_l[e*33+(u0>>16)]
            + Wt[e*36+(u1&0xffff)] * S_l[e*33+(u1>>16)];
    #pragma unroll
    for(int m=1;m<16;m<<=1) v += __shfl_xor(v, m, 64);
    if(g==0 && e<nE) atomicAdd(&bins[g_t[e]], v);
  }
  __syncthreads();
  if(t<G) atomicAdd(&out[t], bins[t]*out_scale);
}

// ---------------- launch ----------------
extern "C" void kernel_launch(void* const* d_in, const int* in_sizes, int n_in,
                              void* d_out, int out_size, void* d_ws, size_t ws_size,
                              hipStream_t stream) {
  const float* pos  = (const float*)d_in[0];
  const float* w11  = (const float*)d_in[1];
  const float* w12  = (const float*)d_in[2];
  const float* w21  = (const float*)d_in[3];
  const float* w22  = (const float*)d_in[4];
  const int*   esrc = (const int*)d_in[5];
  const int*   edst = (const int*)d_in[6];
  const int*   batch= (const int*)d_in[7];
  int E = in_sizes[5];
  int N = in_sizes[0]/3;
  int G = out_size;

  double nn = std::sqrt((double)E/(double)N);
  float inv_nn    = (float)(1.0/nn);
  float out_scale = (float)(1.0/(nn*std::sqrt((double)N)));

  float* ws = (float*)d_ws;
  float* x   = ws;
  float* ef1 = x   + (size_t)N*16;
  float* xg  = ef1 + (size_t)N*160;
  TPTables* dT = (TPTables*)(xg + (size_t)N*128);
  unsigned short* B1   = (unsigned short*)(((char*)dT) + ((sizeof(TPTables)+255)&~(size_t)255));
  unsigned short* B2   = B1 + NB1;
  unsigned short* W1p1 = B2 + NB2;
  unsigned short* W1p2 = W1p1 + NW1;
  int* deg    = (int*)(W1p2 + NW1);
  int* row    = deg + N;
  int* cursor = row + (N+1);
  int* perm   = cursor + N;

  static TPTables hT;
  build_tables(hT);
  hipMemcpyAsync(dT, &hT, sizeof(TPTables), hipMemcpyHostToDevice, stream);

  size_t nz = (size_t)N*16 + (size_t)N*160 + G + N;
  int zgrid = (int)((nz+255)/256); if(zgrid>2048) zgrid=2048;
  k_zero<<<zgrid,256,0,stream>>>(x, (size_t)N*16, ef1, (size_t)N*160, (float*)d_out, (size_t)G, deg, (size_t)N);
  k_deg<<<(E+255)/256,256,0,stream>>>(edst, deg, E);
  k_scan<<<1,1024,0,stream>>>(deg, row, cursor, N);
  k_fill<<<(E+255)/256,256,0,stream>>>(edst, row, cursor, perm, E);
  k_prep<<<(NB1+NB2+2*NW1+255)/256,256,0,stream>>>(w12, w22, w11, w21, B1, B2, W1p1, W1p2, dT);
  k_edge_pre<<<(E+255)/256,256,0,stream>>>(pos, esrc, edst, perm, x, E);
  k_fc1_tp1<<<(E+TILE-1)/TILE,512,0,stream>>>(pos, esrc, edst, perm, W1p1, B1, x, ef1, dT, E, inv_nn);
  k_gate<<<(N+255)/256,256,0,stream>>>(ef1, xg, N, inv_nn);
  k_fc2_tp2<<<(E+TILE-1)/TILE,512,0,stream>>>(pos, esrc, edst, perm, batch, W1p2, B2, xg,
                                              (float*)d_out, dT, E, out_scale, G);
}